// Round 6
// baseline (678.071 us; speedup 1.0000x reference)
//
#include <hip/hip_runtime.h>
#include <hip/hip_bf16.h>
#include <stdint.h>

#define N_NODES 16384
#define E_EDGES 131072
#define F_DIM 128
#define L_DIM 9
#define R_DIM 8
#define DOUT_DIM 1152
#define K_SEL 1024
#define HID_DIM 64
#define DA_DIM 64

typedef unsigned short u16;
typedef __attribute__((ext_vector_type(8))) short bf16x8;
typedef __attribute__((ext_vector_type(4))) float f32x4;

static __device__ inline u16 f2bs(float x) {
  union { __hip_bfloat16 b; u16 s; } u;
  u.b = __float2bfloat16(x);
  return u.s;
}

// async global->LDS, 16B per lane. LDS dest must be waveBase + lane*16.
#define GLDS16(gsrc, ldst) __builtin_amdgcn_global_load_lds( \
    (__attribute__((address_space(1))) void*)(void*)(gsrc),  \
    (__attribute__((address_space(3))) void*)(ldst), 16, 0, 0)

// ================= MFMA GEMM (fallback): C = A(f32->bf16) * B^T(bf16) [+Add]
__global__ __launch_bounds__(256) void gemm_mfma(
    const float* __restrict__ A, const u16* __restrict__ Bt,
    float* __restrict__ C, int ldc, int M, int Nc, int Kc,
    const float* __restrict__ Add, int ldadd, int addW)
{
  __shared__ float Af[128 * 32];   // [m][oct ^ (m&7)]
  __shared__ u16  Bs[128 * 32];    // [n][q ^ ((n>>1)&3)]
  const int tid = threadIdx.x;
  const int wave = tid >> 6, lane = tid & 63;
  const int wm = wave >> 1, wn = wave & 1;
  const int l15 = lane & 15, quad = lane >> 4;
  const int bm = blockIdx.y * 128, bn = blockIdx.x * 128;

  f32x4 acc[4][4];
#pragma unroll
  for (int i = 0; i < 4; i++)
#pragma unroll
    for (int j = 0; j < 4; j++) acc[i][j] = (f32x4)(0.f);

  for (int k0 = 0; k0 < Kc; k0 += 32) {
    __syncthreads();
#pragma unroll
    for (int it = 0; it < 4; it++) {
      int c = it * 256 + tid;
      int row = c >> 3, op = c & 7;
      int oct = op ^ (row & 7);
      const float* g = A + (size_t)(bm + row) * Kc + k0 + oct * 4;
      GLDS16(g, &Af[c * 4]);
    }
#pragma unroll
    for (int it = 0; it < 2; it++) {
      int c = it * 256 + tid;
      int row = c >> 2, qp = c & 3;
      int q = qp ^ ((row >> 1) & 3);
      const u16* g = Bt + (size_t)(bn + row) * Kc + k0 + q * 8;
      GLDS16(g, &Bs[c * 8]);
    }
    __syncthreads();

    bf16x8 af[4], bfg[4];
#pragma unroll
    for (int mi = 0; mi < 4; mi++) {
      int m = wm * 64 + mi * 16 + l15;
      int o0 = (quad * 2) ^ (m & 7), o1 = (quad * 2 + 1) ^ (m & 7);
      float4 lo = *(const float4*)&Af[m * 32 + o0 * 4];
      float4 hi = *(const float4*)&Af[m * 32 + o1 * 4];
      bf16x8 r;
      r[0] = (short)f2bs(lo.x); r[1] = (short)f2bs(lo.y);
      r[2] = (short)f2bs(lo.z); r[3] = (short)f2bs(lo.w);
      r[4] = (short)f2bs(hi.x); r[5] = (short)f2bs(hi.y);
      r[6] = (short)f2bs(hi.z); r[7] = (short)f2bs(hi.w);
      af[mi] = r;
    }
#pragma unroll
    for (int ni = 0; ni < 4; ni++) {
      int n = wn * 64 + ni * 16 + l15;
      int q2 = quad ^ ((n >> 1) & 3);
      bfg[ni] = *(const bf16x8*)&Bs[n * 32 + q2 * 8];
    }
#pragma unroll
    for (int mi = 0; mi < 4; mi++)
#pragma unroll
      for (int ni = 0; ni < 4; ni++)
        acc[mi][ni] = __builtin_amdgcn_mfma_f32_16x16x32_bf16(af[mi], bfg[ni], acc[mi][ni], 0, 0, 0);
  }
#pragma unroll
  for (int mi = 0; mi < 4; mi++)
#pragma unroll
    for (int ni = 0; ni < 4; ni++)
#pragma unroll
      for (int r = 0; r < 4; r++) {
        int row = bm + wm * 64 + mi * 16 + quad * 4 + r;
        int col = bn + wn * 64 + ni * 16 + l15;
        float v = acc[mi][ni][r];
        if (Add != nullptr && col < addW) v += Add[(size_t)row * ldadd + col];
        C[(size_t)row * ldc + col] = v;
      }
}

// ================= MFMA GEMM, bf16 A, double-buffered prefetch.
// 1D grid with XCD-chunked swizzle (nwg % 8 == 0).
__global__ __launch_bounds__(256) void gemm_mfma_b16(
    const u16* __restrict__ A, const u16* __restrict__ Bt,
    float* __restrict__ C, int ldc, int Kc, int nbx, int nwg,
    const float* __restrict__ Add, int ldadd, int addW)
{
  __shared__ u16 As[2][128 * 32];  // [buf][m][q ^ ((m>>1)&3)]
  __shared__ u16 Bs[2][128 * 32];  // [buf][n][q ^ ((n>>1)&3)]
  const int tid = threadIdx.x;
  const int wave = tid >> 6, lane = tid & 63;
  const int wm = wave >> 1, wn = wave & 1;
  const int l15 = lane & 15, quad = lane >> 4;
  const int lin = blockIdx.x;
  const int swz = (lin & 7) * (nwg >> 3) + (lin >> 3);  // XCD-chunked, bijective
  const int bm = (swz / nbx) * 128, bn = (swz % nbx) * 128;

  const int c0 = tid,      r0 = c0 >> 2, q0 = (c0 & 3) ^ ((r0 >> 1) & 3);
  const int c1 = 256 + tid, r1 = c1 >> 2, q1 = (c1 & 3) ^ ((r1 >> 1) & 3);
  const u16* gA0 = A + (size_t)(bm + r0) * Kc + q0 * 8;
  const u16* gA1 = A + (size_t)(bm + r1) * Kc + q1 * 8;
  const u16* gB0 = Bt + (size_t)(bn + r0) * Kc + q0 * 8;
  const u16* gB1 = Bt + (size_t)(bn + r1) * Kc + q1 * 8;

  f32x4 acc[4][4];
#pragma unroll
  for (int i = 0; i < 4; i++)
#pragma unroll
    for (int j = 0; j < 4; j++) acc[i][j] = (f32x4)(0.f);

#define STAGE_AB(s, k0) do {                      \
    GLDS16(gA0 + (k0), &As[s][c0 * 8]);           \
    GLDS16(gA1 + (k0), &As[s][c1 * 8]);           \
    GLDS16(gB0 + (k0), &Bs[s][c0 * 8]);           \
    GLDS16(gB1 + (k0), &Bs[s][c1 * 8]);           \
  } while (0)

  STAGE_AB(0, 0);
  __syncthreads();
  int cur = 0;
  const int nt = Kc / 32;
  for (int t = 0; t < nt; t++) {
    if (t + 1 < nt) STAGE_AB(cur ^ 1, (t + 1) * 32);
    bf16x8 af[4], bfg[4];
#pragma unroll
    for (int mi = 0; mi < 4; mi++) {
      int m = wm * 64 + mi * 16 + l15;
      af[mi] = *(const bf16x8*)&As[cur][m * 32 + (quad ^ ((m >> 1) & 3)) * 8];
    }
#pragma unroll
    for (int ni = 0; ni < 4; ni++) {
      int n = wn * 64 + ni * 16 + l15;
      bfg[ni] = *(const bf16x8*)&Bs[cur][n * 32 + (quad ^ ((n >> 1) & 3)) * 8];
    }
#pragma unroll
    for (int mi = 0; mi < 4; mi++)
#pragma unroll
      for (int ni = 0; ni < 4; ni++)
        acc[mi][ni] = __builtin_amdgcn_mfma_f32_16x16x32_bf16(af[mi], bfg[ni], acc[mi][ni], 0, 0, 0);
    __syncthreads();
    cur ^= 1;
  }
#undef STAGE_AB

#pragma unroll
  for (int mi = 0; mi < 4; mi++)
#pragma unroll
    for (int ni = 0; ni < 4; ni++)
#pragma unroll
      for (int r = 0; r < 4; r++) {
        int row = bm + wm * 64 + mi * 16 + quad * 4 + r;
        int col = bn + wn * 64 + ni * 16 + l15;
        float v = acc[mi][ni][r];
        if (Add != nullptr && col < addW) v += Add[(size_t)row * ldadd + col];
        C[(size_t)row * ldc + col] = v;
      }
}

// ================= transpose + bf16 cast
__global__ __launch_bounds__(256) void transpose_bf16(
    const float* __restrict__ W, u16* __restrict__ Bt, int K, int N)
{
  __shared__ float t[32][33];
  const int n0 = blockIdx.x * 32, k0 = blockIdx.y * 32;
  const int tx = threadIdx.x & 31, ty = threadIdx.x >> 5;
  for (int r = ty; r < 32; r += 8) t[r][tx] = W[(size_t)(k0 + r) * N + n0 + tx];
  __syncthreads();
  for (int r = ty; r < 32; r += 8) Bt[(size_t)(n0 + r) * K + k0 + tx] = f2bs(t[tx][r]);
}

// ================= hs GEMM: psum[z] = upd[:, z*288:(z+1)*288] @ W_prod_l[z-chunk, :128]
__global__ __launch_bounds__(256) void hs_gemm_kernel(
    const float* __restrict__ A,      // upd, lda = DOUT_DIM
    const float* __restrict__ B,      // W_prod_l, ldb = DOUT_DIM (cols 0..127)
    float* __restrict__ psum)         // [4][N_NODES][F_DIM]
{
  __shared__ float As[16][129];
  __shared__ float Bs[16][128];
  const int tid = threadIdx.x;
  const int tx = tid & 15, ty = tid >> 4;
  const int bm = blockIdx.x * 128;
  const int z = blockIdx.y;
  const int kb = z * (DOUT_DIM / 4);
  const int ke = kb + DOUT_DIM / 4;
  const int ac = tid & 15, ar0 = tid >> 4;
  const int bc = tid & 127, br0 = tid >> 7;
  float acc[8][8];
#pragma unroll
  for (int i = 0; i < 8; i++)
#pragma unroll
    for (int j = 0; j < 8; j++) acc[i][j] = 0.f;

  float ra[8], rb[8];
#define LOADREG(k0) do {                                                       \
    _Pragma("unroll")                                                          \
    for (int rr = 0; rr < 8; rr++)                                             \
      ra[rr] = A[(size_t)(bm + ar0 + rr * 16) * DOUT_DIM + (k0) + ac];         \
    _Pragma("unroll")                                                          \
    for (int rr = 0; rr < 8; rr++)                                             \
      rb[rr] = B[(size_t)((k0) + br0 + rr * 2) * DOUT_DIM + bc];               \
  } while (0)

  LOADREG(kb);
  for (int k0 = kb; k0 < ke; k0 += 16) {
#pragma unroll
    for (int rr = 0; rr < 8; rr++) As[ac][ar0 + rr * 16] = ra[rr];
#pragma unroll
    for (int rr = 0; rr < 8; rr++) Bs[br0 + rr * 2][bc] = rb[rr];
    __syncthreads();
    if (k0 + 16 < ke) LOADREG(k0 + 16);
#pragma unroll
    for (int kk = 0; kk < 16; kk++) {
      float a[8], b[8];
#pragma unroll
      for (int i = 0; i < 8; i++) a[i] = As[kk][ty * 8 + i];
#pragma unroll
      for (int j = 0; j < 8; j++) b[j] = Bs[kk][tx * 8 + j];
#pragma unroll
      for (int i = 0; i < 8; i++)
#pragma unroll
        for (int j = 0; j < 8; j++) acc[i][j] = fmaf(a[i], b[j], acc[i][j]);
    }
    __syncthreads();
  }
#undef LOADREG
#pragma unroll
  for (int i = 0; i < 8; i++) {
    size_t row = (size_t)z * N_NODES + bm + ty * 8 + i;
#pragma unroll
    for (int j = 0; j < 8; j++)
      psum[row * F_DIM + tx * 8 + j] = acc[i][j];
  }
}

// hs = psum[0]+psum[1]+psum[2]+psum[3] + h   (float4)
__global__ __launch_bounds__(256) void hs_reduce_kernel(
    const float* __restrict__ psum, const float* __restrict__ h, float* __restrict__ hs)
{
  size_t i4 = (size_t)blockIdx.x * 256 + threadIdx.x;
  const size_t stride = (size_t)N_NODES * F_DIM / 4;
  const float4* p = (const float4*)psum;
  float4 a = p[i4], b = p[i4 + stride], c = p[i4 + 2 * stride], d = p[i4 + 3 * stride];
  float4 hh = ((const float4*)h)[i4];
  float4 o;
  o.x = a.x + b.x + c.x + d.x + hh.x;
  o.y = a.y + b.y + c.y + d.y + hh.y;
  o.z = a.z + b.z + c.z + d.z + hh.z;
  o.w = a.w + b.w + c.w + d.w + hh.w;
  ((float4*)hs)[i4] = o;
}

// ================= fp32 GEMM 64x64, optional split-K
__global__ __launch_bounds__(256) void gemm64_f32(
    const float* __restrict__ A, int lda,
    const float* __restrict__ B, int ldb,
    float* __restrict__ C, int ldc,
    int M, int Nc, int Kc, int kPerSplit,
    const float* __restrict__ Add, int ldadd, int addW)
{
  __shared__ float As[16][65];
  __shared__ float Bs[16][64];
  const int tid = threadIdx.x;
  const int tx = tid & 15, ty = tid >> 4;
  const int bm = blockIdx.y * 64, bn = blockIdx.x * 64;
  const int kb = blockIdx.z * kPerSplit;
  const int ke = min(kb + kPerSplit, Kc);
  float acc[4][4];
#pragma unroll
  for (int i = 0; i < 4; i++)
#pragma unroll
    for (int j = 0; j < 4; j++) acc[i][j] = 0.f;
  for (int k0 = kb; k0 < ke; k0 += 16) {
    const int ac = tid & 15, ar = tid >> 4;
#pragma unroll
    for (int rr = 0; rr < 4; rr++) {
      int row = ar + rr * 16;
      As[ac][row] = A[(size_t)(bm + row) * lda + k0 + ac];
    }
    const int bc = tid & 63, br = tid >> 6;
#pragma unroll
    for (int rr = 0; rr < 4; rr++) {
      int kr = br + rr * 4;
      Bs[kr][bc] = B[(size_t)(k0 + kr) * ldb + bn + bc];
    }
    __syncthreads();
#pragma unroll
    for (int kk = 0; kk < 16; kk++) {
      float a[4], b[4];
#pragma unroll
      for (int i = 0; i < 4; i++) a[i] = As[kk][ty * 4 + i];
#pragma unroll
      for (int j = 0; j < 4; j++) b[j] = Bs[kk][tx * 4 + j];
#pragma unroll
      for (int i = 0; i < 4; i++)
#pragma unroll
        for (int j = 0; j < 4; j++) acc[i][j] = fmaf(a[i], b[j], acc[i][j]);
    }
    __syncthreads();
  }
#pragma unroll
  for (int i = 0; i < 4; i++) {
    int row = bm + ty * 4 + i;
#pragma unroll
    for (int j = 0; j < 4; j++) {
      int col = bn + tx * 4 + j;
      if (gridDim.z > 1) {
        atomicAdd(&C[(size_t)row * ldc + col], acc[i][j]);
      } else {
        float v = acc[i][j];
        if (Add != nullptr && col < addW) v += Add[(size_t)row * ldadd + col];
        C[(size_t)row * ldc + col] = v;
      }
    }
  }
}

// ================= CSR build: count / scan / fill
__global__ __launch_bounds__(256) void count_kernel(
    const int* __restrict__ ei, int* __restrict__ counts)
{
  int e = blockIdx.x * 256 + threadIdx.x;
  atomicAdd(&counts[ei[E_EDGES + e]], 1);
}

__global__ __launch_bounds__(1024) void scan_kernel(
    const int* __restrict__ counts, int* __restrict__ offsets, int* __restrict__ cursor)
{
  __shared__ int part[1024];
  const int t = threadIdx.x;
  const int base = t * 16;
  int loc[16];
  int s = 0;
#pragma unroll
  for (int k = 0; k < 16; k++) { loc[k] = counts[base + k]; s += loc[k]; }
  part[t] = s;
  __syncthreads();
  for (int d = 1; d < 1024; d <<= 1) {
    int v = (t >= d) ? part[t - d] : 0;
    __syncthreads();
    part[t] += v;
    __syncthreads();
  }
  int run = part[t] - s;  // exclusive prefix
#pragma unroll
  for (int k = 0; k < 16; k++) {
    offsets[base + k] = run;
    cursor[base + k] = run;
    run += loc[k];
  }
}

__global__ __launch_bounds__(256) void fill_kernel(
    const int* __restrict__ ei, int* __restrict__ cursor, int* __restrict__ elist)
{
  int e = blockIdx.x * 256 + threadIdx.x;
  int d = ei[E_EDGES + e];
  int p = atomicAdd(&cursor[d], 1);
  elist[p] = e;
}

// ================= atomic-free edge accumulation: block per dst node.
__global__ __launch_bounds__(128) void gather_accum_kernel(
    const float* __restrict__ hW, const float* __restrict__ edge_sh,
    const float* __restrict__ edge_feats, const float* __restrict__ W_rad_l,
    const int* __restrict__ ei, const int* __restrict__ offsets,
    const int* __restrict__ counts, const int* __restrict__ elist,
    float* __restrict__ upd, u16* __restrict__ updb)
{
  const int d = blockIdx.x, f = threadIdx.x;
  const float w0 = W_rad_l[0 * F_DIM + f], w1 = W_rad_l[1 * F_DIM + f];
  const float w2 = W_rad_l[2 * F_DIM + f], w3 = W_rad_l[3 * F_DIM + f];
  const float w4 = W_rad_l[4 * F_DIM + f], w5 = W_rad_l[5 * F_DIM + f];
  const float w6 = W_rad_l[6 * F_DIM + f], w7 = W_rad_l[7 * F_DIM + f];
  const int b = offsets[d], n = counts[d];
  float acc[L_DIM];
#pragma unroll
  for (int l = 0; l < L_DIM; l++) acc[l] = 0.f;
  for (int k = 0; k < n; k++) {
    const int e = elist[b + k];
    const int s = ei[e];
    const float4 ef0 = *(const float4*)&edge_feats[(size_t)e * R_DIM];
    const float4 ef1 = *(const float4*)&edge_feats[(size_t)e * R_DIM + 4];
    float rw = ef0.x * w0;
    rw = fmaf(ef0.y, w1, rw); rw = fmaf(ef0.z, w2, rw); rw = fmaf(ef0.w, w3, rw);
    rw = fmaf(ef1.x, w4, rw); rw = fmaf(ef1.y, w5, rw);
    rw = fmaf(ef1.z, w6, rw); rw = fmaf(ef1.w, w7, rw);
    const float tf = hW[(size_t)s * F_DIM + f] * rw;
#pragma unroll
    for (int l = 0; l < L_DIM; l++)
      acc[l] = fmaf(edge_sh[(size_t)e * L_DIM + l], tf, acc[l]);
  }
#pragma unroll
  for (int l = 0; l < L_DIM; l++)
    upd[(size_t)d * DOUT_DIM + l * F_DIM + f] = acc[l];
  if (updb != nullptr) {
#pragma unroll
    for (int l = 0; l < L_DIM; l++)
      updb[(size_t)d * DOUT_DIM + l * F_DIM + f] = f2bs(acc[l]);
  }
}

// ================= gating MLP on hs (fp32, ld=F_DIM) + fused 16-bit histogram
__global__ __launch_bounds__(256) void gate_kernel(
    const float* __restrict__ hs, const float* __restrict__ W1,
    const float* __restrict__ b1, const float* __restrict__ W2,
    const float* __restrict__ b2, float* __restrict__ m_ws, float* __restrict__ m_out,
    int* __restrict__ hist1)
{
  __shared__ float sW1[F_DIM * HID_DIM];
  __shared__ float srow[4][F_DIM];
  const int tid = threadIdx.x;
  for (int t = tid; t < F_DIM * HID_DIM; t += 256) sW1[t] = W1[t];
  const int wave = tid >> 6, lane = tid & 63;
  const int n = blockIdx.x * 4 + wave;
  srow[wave][lane] = hs[(size_t)n * F_DIM + lane];
  srow[wave][lane + 64] = hs[(size_t)n * F_DIM + lane + 64];
  __syncthreads();
  float hid = b1[lane];
#pragma unroll 8
  for (int c = 0; c < F_DIM; c++) hid = fmaf(srow[wave][c], sW1[c * HID_DIM + lane], hid);
  hid = fmaxf(hid, 0.f);
  float v = hid * W2[lane];
#pragma unroll
  for (int off = 32; off > 0; off >>= 1) v += __shfl_down(v, off);
  if (lane == 0) {
    float mm = 1.f / (1.f + expf(-(v + b2[0])));
    m_ws[n] = mm;
    m_out[n] = mm;
    unsigned mb = __float_as_uint(mm);
    atomicAdd(&hist1[mb >> 16], 1);
  }
}

// ================= radix top-K selection
__global__ __launch_bounds__(1024) void radix_sel_kernel(
    const int* __restrict__ hist, const int* __restrict__ kin, int kinIdx,
    int* __restrict__ outp, int outIdx)
{
  __shared__ int part[1024];
  const int t = threadIdx.x;
  const int Kv = kin ? kin[kinIdx] : K_SEL;
  const int base = t * 64;
  int s = 0;
  for (int k = 0; k < 64; k++) s += hist[base + k];
  part[t] = s;
  __syncthreads();
  for (int d = 1; d < 1024; d <<= 1) {
    int v = (t + d < 1024) ? part[t + d] : 0;
    __syncthreads();
    part[t] += v;
    __syncthreads();
  }
  int inc = part[t];
  if (inc >= Kv && inc - s < Kv) {
    int r = inc - s;
    for (int b = base + 63; b >= base; b--) {
      int hv = hist[b];
      if (r + hv >= Kv) { outp[outIdx] = b; outp[outIdx + 1] = Kv - r; break; }
      r += hv;
    }
  }
}

__global__ __launch_bounds__(256) void hist2_kernel(
    const float* __restrict__ m_ws, const int* __restrict__ selb, int* __restrict__ hist2)
{
  int i = blockIdx.x * 256 + threadIdx.x;
  unsigned mb = __float_as_uint(m_ws[i]);
  if ((int)(mb >> 16) == selb[0]) atomicAdd(&hist2[mb & 0xFFFFu], 1);
}

__global__ __launch_bounds__(256) void flag_kernel(
    const float* __restrict__ m_ws, int* __restrict__ selb,
    unsigned char* __restrict__ flags, int* __restrict__ cand)
{
  int i = blockIdx.x * 256 + threadIdx.x;
  unsigned mb = __float_as_uint(m_ws[i]);
  unsigned vb = ((unsigned)selb[0] << 16) | (unsigned)selb[2];
  unsigned char fl = 0;
  if (mb > vb) fl = 1;
  else if (mb == vb) { int p = atomicAdd(&selb[4], 1); cand[p] = i; }
  flags[i] = fl;
}

__global__ __launch_bounds__(1024) void cand_kernel(
    const int* __restrict__ selb, const int* __restrict__ cand, unsigned char* __restrict__ flags)
{
  const int nc = selb[4], need = selb[3];
  for (int c = threadIdx.x; c < nc; c += 1024) {
    const int idx = cand[c];
    int r = 0;
    for (int o = 0; o < nc; o++) r += (cand[o] < idx) ? 1 : 0;
    if (r < need) flags[idx] = 1;
  }
}

__global__ __launch_bounds__(1024) void compact_kernel(
    const unsigned char* __restrict__ flags, int* __restrict__ midx,
    int* __restrict__ rank, float* __restrict__ mi_out)
{
  __shared__ int part[1024];
  const int t = threadIdx.x;
  const int base = t * 16;
  int loc[16];
  int s = 0;
#pragma unroll
  for (int k = 0; k < 16; k++) { loc[k] = flags[base + k]; s += loc[k]; }
  part[t] = s;
  __syncthreads();
  for (int d = 1; d < 1024; d <<= 1) {
    int v = (t >= d) ? part[t - d] : 0;
    __syncthreads();
    part[t] += v;
    __syncthreads();
  }
  int run = part[t] - s;
#pragma unroll
  for (int k = 0; k < 16; k++) {
    int i = base + k;
    if (loc[k]) {
      midx[run] = i;
      mi_out[run] = (float)i;
      rank[i] = run;
      run++;
    } else {
      rank[i] = K_SEL;
    }
  }
}

// ================= induced adjacency (+ transposed copy for coalesced listbuild)
__global__ __launch_bounds__(256) void adj_kernel(
    const int* __restrict__ ei, const int* __restrict__ rank,
    unsigned char* __restrict__ adjm, unsigned char* __restrict__ adjT)
{
  int e = blockIdx.x * 256 + threadIdx.x;
  int rs = rank[ei[e]];
  int rd = rank[ei[E_EDGES + e]];
  if (rs < K_SEL && rd < K_SEL) {
    adjm[(size_t)rs * K_SEL + rd] = 1;
    adjT[(size_t)rd * K_SEL + rs] = 1;
  }
}

// ================= gather master rows + positions (float4)
__global__ __launch_bounds__(128) void gather_kernel(
    const float* __restrict__ hl, const float* __restrict__ pos,
    const int* __restrict__ midx, float* __restrict__ h_m, float* __restrict__ pos_m)
{
  const int rI = blockIdx.x, t = threadIdx.x;
  const int mi = midx[rI];
  const float4* src = (const float4*)(hl + (size_t)mi * DOUT_DIM);
  float4* dst = (float4*)(h_m + (size_t)rI * DOUT_DIM);
  for (int c = t; c < DOUT_DIM / 4; c += 128) dst[c] = src[c];
  if (t < 3) pos_m[rI * 3 + t] = pos[mi * 3 + t];
}

// ================= q/k projections from hs at master rows
__global__ __launch_bounds__(128) void qk_kernel(
    const float* __restrict__ hs, const int* __restrict__ midx,
    const float* __restrict__ Wq, const float* __restrict__ Wk,
    float* __restrict__ q, float* __restrict__ kk)
{
  __shared__ float row[F_DIM];
  const int i = blockIdx.x, t = threadIdx.x;
  const int mi = midx[i];
  row[t] = hs[(size_t)mi * F_DIM + t];
  __syncthreads();
  const int d = t & 63;
  const float* W = (t < 64) ? Wq : Wk;
  float acc = 0.f;
#pragma unroll 8
  for (int c = 0; c < F_DIM; c++) acc = fmaf(row[c], W[c * DA_DIM + d], acc);
  float* dst = (t < 64) ? q : kk;
  dst[(size_t)i * DA_DIM + d] = acc;
}

// ================= attention (padded LDS; also emits transposed mask)
__global__ __launch_bounds__(256) void attn_kernel(
    const float* __restrict__ q, const float* __restrict__ kk,
    unsigned char* __restrict__ maskA, unsigned char* __restrict__ maskAT,
    float* __restrict__ Av)
{
  __shared__ float qs[16][DA_DIM + 1], ks[16][DA_DIM + 1];
  const int tx = threadIdx.x, ty = threadIdx.y;
  const int tid = ty * 16 + tx;
  const int i0 = blockIdx.y * 16, j0 = blockIdx.x * 16;
  for (int t = tid; t < 16 * DA_DIM; t += 256) {
    int rr = t >> 6, cc = t & 63;
    qs[rr][cc] = q[(size_t)(i0 + rr) * DA_DIM + cc];
    ks[rr][cc] = kk[(size_t)(j0 + rr) * DA_DIM + cc];
  }
  __syncthreads();
  float acc = 0.f;
#pragma unroll
  for (int d2 = 0; d2 < DA_DIM; d2++) acc = fmaf(qs[ty][d2], ks[tx][d2], acc);
  float sgl = 1.f / (1.f + expf(-acc * 0.125f));
  size_t o = (size_t)(i0 + ty) * K_SEL + (j0 + tx);
  bool big = sgl > 0.5f;
  unsigned char bb = big ? 1 : 0;
  maskA[o] = bb;
  maskAT[(size_t)(j0 + tx) * K_SEL + (i0 + ty)] = bb;
  Av[o] = big ? sgl : 0.f;
}

// ================= per-i active-j list (coalesced row reads + wave-ballot)
__global__ __launch_bounds__(256) void listbuild_kernel(
    const unsigned char* __restrict__ adjT, const unsigned char* __restrict__ maskAT,
    const unsigned char* __restrict__ maskA, u16* __restrict__ list, int* __restrict__ nj)
{
  __shared__ int cnt;
  const int i = blockIdx.x, tid = threadIdx.x;
  const int lane = tid & 63;
  if (tid == 0) cnt = 0;
  __syncthreads();
  const int j0 = tid * 4;
  uchar4 a  = *(const uchar4*)&adjT  [(size_t)i * K_SEL + j0];
  uchar4 mt = *(const uchar4*)&maskAT[(size_t)i * K_SEL + j0];
  uchar4 ma = *(const uchar4*)&maskA [(size_t)i * K_SEL + j0];
  unsigned char av[4];
  av[0] = a.x | mt.x | ma.x; av[1] = a.y | mt.y | ma.y;
  av[2] = a.z | mt.z | ma.z; av[3] = a.w | mt.w | ma.w;
#pragma unroll
  for (int r = 0; r < 4; r++) {
    int j = j0 + r;
    bool e = (j != i) && av[r];
    unsigned long long m = __ballot(e);
    int nset = __popcll(m);
    int base = 0;
    if (lane == 0 && nset) base = atomicAdd(&cnt, nset);
    base = __shfl(base, 0);
    if (e) {
      int p = base + __popcll(m & ((1ull << lane) - 1ull));
      list[(size_t)i * K_SEL + p] = (u16)j;
    }
  }
  __syncthreads();
  if (tid == 0) nj[i] = cnt;
}

// ================= hier v4: half-split blocks (2048x256) for occupancy refill,
// unroll-2 j-loop, partials to psum2[half][i][:] (exclusive, no atomics).
__global__ __launch_bounds__(256) void hier2_kernel(
    const float* __restrict__ hWn, const float* __restrict__ pos_m,
    const float* __restrict__ W_rad_h, const u16* __restrict__ list,
    const int* __restrict__ nj, float* __restrict__ psum2)
{
  __shared__ float gsm[128][20];   // [pair][rd0..7, sh0..8, jbits, pad, pad]
  __shared__ float red[L_DIM][F_DIM];
  const int tid = threadIdx.x;
  const int i = blockIdx.x >> 1, half = blockIdx.x & 1;
  const int f = tid & 127, jsub = tid >> 7;   // 2 j-subgroups x 128 f
  const float sw0 = W_rad_h[0 * F_DIM + f], sw1 = W_rad_h[1 * F_DIM + f];
  const float sw2 = W_rad_h[2 * F_DIM + f], sw3 = W_rad_h[3 * F_DIM + f];
  const float sw4 = W_rad_h[4 * F_DIM + f], sw5 = W_rad_h[5 * F_DIM + f];
  const float sw6 = W_rad_h[6 * F_DIM + f], sw7 = W_rad_h[7 * F_DIM + f];
  const float* hWf = hWn + f;
  const float pix = pos_m[i * 3 + 0], piy = pos_m[i * 3 + 1], piz = pos_m[i * 3 + 2];
  float acc[L_DIM];
#pragma unroll
  for (int l = 0; l < L_DIM; l++) acc[l] = 0.f;
  const int n = nj[i];

#define HBODY(tt)                                                        \
  { float2 s2 = *(const float2*)&gsm[tt][16];                            \
    const int jj = __float_as_int(s2.y);                                 \
    const float hw = hWf[(size_t)jj * F_DIM];                            \
    float4 r0 = *(const float4*)&gsm[tt][0];                             \
    float4 r1 = *(const float4*)&gsm[tt][4];                             \
    float4 s0 = *(const float4*)&gsm[tt][8];                             \
    float4 s1g = *(const float4*)&gsm[tt][12];                           \
    float rw = r0.x * sw0;                                               \
    rw = fmaf(r0.y, sw1, rw); rw = fmaf(r0.z, sw2, rw);                  \
    rw = fmaf(r0.w, sw3, rw); rw = fmaf(r1.x, sw4, rw);                  \
    rw = fmaf(r1.y, sw5, rw); rw = fmaf(r1.z, sw6, rw);                  \
    rw = fmaf(r1.w, sw7, rw);                                            \
    const float tm = hw * rw;                                            \
    acc[0] = fmaf(s0.x, tm, acc[0]); acc[1] = fmaf(s0.y, tm, acc[1]);    \
    acc[2] = fmaf(s0.z, tm, acc[2]); acc[3] = fmaf(s0.w, tm, acc[3]);    \
    acc[4] = fmaf(s1g.x, tm, acc[4]); acc[5] = fmaf(s1g.y, tm, acc[5]);  \
    acc[6] = fmaf(s1g.z, tm, acc[6]); acc[7] = fmaf(s1g.w, tm, acc[7]);  \
    acc[8] = fmaf(s2.x, tm, acc[8]); }

  for (int c0 = half * 128; c0 < n; c0 += 256) {
    const int cnt = min(128, n - c0);
    __syncthreads();
    if (tid < cnt) {
      const int j = list[(size_t)i * K_SEL + c0 + tid];
      float vx = pos_m[j * 3 + 0] - pix;
      float vy = pos_m[j * 3 + 1] - piy;
      float vz = pos_m[j * 3 + 2] - piz;
      float r = sqrtf(vx * vx + vy * vy + vz * vz);
      float rm = fmaxf(r, 1e-9f);
      float inv = 1.f / rm;
      float ux = vx * inv, uy = vy * inv, uz = vz * inv;
      float theta = 0.62831853071795864769f * r;  // pi/R_CUT
      float s1 = sinf(theta), c1 = cosf(theta);
      float coef = 0.632455532033675866f * inv;   // sqrt(2/R_CUT)/max(r,eps)
      float snm2 = 0.f, snm1 = s1;
      gsm[tid][0] = s1 * coef;
#pragma unroll
      for (int nn = 2; nn <= R_DIM; nn++) {
        float sn = 2.f * c1 * snm1 - snm2;
        gsm[tid][nn - 1] = sn * coef;
        snm2 = snm1; snm1 = sn;
      }
      gsm[tid][8] = 1.f; gsm[tid][9] = ux; gsm[tid][10] = uy; gsm[tid][11] = uz;
      gsm[tid][12] = ux * uy; gsm[tid][13] = uy * uz;
      gsm[tid][14] = 3.f * uz * uz - 1.f;
      gsm[tid][15] = ux * uz; gsm[tid][16] = ux * ux - uy * uy;
      gsm[tid][17] = __int_as_float(j);
    }
    __syncthreads();
    int t = jsub;
    for (; t + 2 < cnt; t += 4) { HBODY(t); HBODY(t + 2); }
    for (; t < cnt; t += 2) { HBODY(t); }
  }
#undef HBODY
  __syncthreads();
  if (jsub == 1) {
#pragma unroll
    for (int l = 0; l < L_DIM; l++) red[l][f] = acc[l];
  }
  __syncthreads();
  if (jsub == 0) {
#pragma unroll
    for (int l = 0; l < L_DIM; l++)
      psum2[((size_t)half * K_SEL + i) * DOUT_DIM + l * F_DIM + f] = acc[l] + red[l][f];
  }
}

// updbm = bf16(psum2[0] + psum2[1])
__global__ __launch_bounds__(256) void hier_fin_kernel(
    const float* __restrict__ psum2, u16* __restrict__ updbm)
{
  size_t idx = (size_t)blockIdx.x * 256 + threadIdx.x;
  updbm[idx] = f2bs(psum2[idx] + psum2[idx + (size_t)K_SEL * DOUT_DIM]);
}

// ================= final blend (float4; 1152 % 4 == 0, vector never spans rows)
__global__ __launch_bounds__(256) void combine_kernel(
    float* __restrict__ out0, const float* __restrict__ h_hier,
    const float* __restrict__ m_ws, const int* __restrict__ rank)
{
  size_t i4 = (size_t)blockIdx.x * 256 + threadIdx.x;
  int n = (int)(i4 / (DOUT_DIM / 4));
  int g4 = (int)(i4 % (DOUT_DIM / 4));
  float mv = m_ws[n];
  int r = rank[n];
  float4 hl = ((const float4*)out0)[i4];
  float4 he = make_float4(0.f, 0.f, 0.f, 0.f);
  if (r < K_SEL) he = ((const float4*)h_hier)[(size_t)r * (DOUT_DIM / 4) + g4];
  float4 o;
  o.x = (1.f - mv) * hl.x + mv * he.x;
  o.y = (1.f - mv) * hl.y + mv * he.y;
  o.z = (1.f - mv) * hl.z + mv * he.z;
  o.w = (1.f - mv) * hl.w + mv * he.w;
  ((float4*)out0)[i4] = o;
}

extern "C" void kernel_launch(void* const* d_in, const int* in_sizes, int n_in,
                              void* d_out, int out_size, void* d_ws, size_t ws_size,
                              hipStream_t stream)
{
  const float* h         = (const float*)d_in[0];
  const float* pos       = (const float*)d_in[1];
  const float* edge_sh   = (const float*)d_in[2];
  const float* edge_feats= (const float*)d_in[3];
  const float* W_node_l  = (const float*)d_in[4];
  const float* W_rad_l   = (const float*)d_in[5];
  const float* W_prod_l  = (const float*)d_in[6];
  const float* ms_W1     = (const float*)d_in[7];
  const float* ms_b1     = (const float*)d_in[8];
  const float* ms_W2     = (const float*)d_in[9];
  const float* ms_b2     = (const float*)d_in[10];
  const float* vg_Wq     = (const float*)d_in[11];
  const float* vg_Wk     = (const float*)d_in[12];
  const float* W_node_h  = (const float*)d_in[13];
  const float* W_rad_h   = (const float*)d_in[14];
  const float* W_prod_h  = (const float*)d_in[15];
  const int*   eidx      = (const int*)d_in[16];

  float* out    = (float*)d_out;
  float* out_hf = out;
  float* out_Av = out + (size_t)N_NODES * DOUT_DIM;
  float* out_m  = out_Av + (size_t)K_SEL * K_SEL;
  float* out_mi = out_m + N_NODES;

  char* ws = (char*)d_ws;
  // Phase 1: upd [0, 75.5MB); hW/hs [75.5, 83.9MB); optional updb [83.9, 121.6MB).
  float* upd = (float*)ws;
  float* hW  = (float*)(ws + (size_t)N_NODES * DOUT_DIM * 4);
  float* hs  = hW;  // hW dead after gather_accum; hs written after
  const size_t updbOff = (size_t)N_NODES * DOUT_DIM * 4 + (size_t)N_NODES * F_DIM * 4;
  const size_t updbNeed = updbOff + (size_t)N_NODES * DOUT_DIM * 2;
  const bool useB16 = (ws_size >= updbNeed);
  u16* updb = (u16*)(ws + updbOff);
  // hs split-K partials borrow out_hf (75.5MB, dead until gemm_mfma_b16 writes it).
  float* psum = out_hf;   // 4 * 16384 * 128 * 4B = 33.6 MB < 75.5 MB
  // Btl + CSR borrow the A_virtual out region (4MB, dead until attn writes it).
  u16* Btl = (u16*)out_Av;                                       // 2.65 MB
  char* csr = (char*)out_Av + (((size_t)DOUT_DIM * DOUT_DIM * 2 + 255) & ~(size_t)255);
  int* counts  = (int*)csr;                                      // 64 KB
  int* offsets = counts + N_NODES;                               // 64 KB
  int* cursor  = offsets + N_NODES;                              // 64 KB
  int* elist   = cursor + N_NODES;                               // 512 KB  (total 3.4MB < 4MB)
  // Phase 2 small pool aliases dead upd.
  size_t off = 0;
  auto alloc = [&](size_t bytes) -> void* {
    void* p = ws + off;
    off += (bytes + 255) & ~(size_t)255;
    return p;
  };
  float* m_ws  = (float*)alloc((size_t)N_NODES * 4);
  int*   rank  = (int*)alloc((size_t)N_NODES * 4);
  int*   midx  = (int*)alloc((size_t)K_SEL * 4);
  int*   hist1 = (int*)alloc((size_t)65536 * 4);
  int*   hist2 = (int*)alloc((size_t)65536 * 4);
  int*   selb  = (int*)alloc((size_t)64 * 4);   // [0]=b1 [1]=need1 [2]=b2 [3]=need2 [4]=ncand
  int*   cand  = (int*)alloc((size_t)N_NODES * 4);
  unsigned char* flags = (unsigned char*)alloc((size_t)N_NODES);
  unsigned char* adjm  = (unsigned char*)alloc((size_t)K_SEL * K_SEL);
  unsigned char* adjT  = (unsigned char*)alloc((size_t)K_SEL * K_SEL);  // contiguous after adjm
  unsigned char* maskA = (unsigned char*)alloc((size_t)K_SEL * K_SEL);
  unsigned char* maskAT= (unsigned char*)alloc((size_t)K_SEL * K_SEL);
  float* qbuf  = (float*)alloc((size_t)K_SEL * DA_DIM * 4);
  float* kbuf  = (float*)alloc((size_t)K_SEL * DA_DIM * 4);
  float* h_m   = (float*)alloc((size_t)K_SEL * DOUT_DIM * 4);
  float* pos_m = (float*)alloc((size_t)K_SEL * 3 * 4);
  float* hWn   = (float*)alloc((size_t)K_SEL * F_DIM * 4);
  float* psum2 = (float*)alloc((size_t)2 * K_SEL * DOUT_DIM * 4);
  float* h_hier= (float*)alloc((size_t)K_SEL * DOUT_DIM * 4);
  u16*   Bth   = (u16*)alloc((size_t)DOUT_DIM * DOUT_DIM * 2);
  u16*   jlist = (u16*)alloc((size_t)K_SEL * K_SEL * 2);
  int*   njbuf = (int*)alloc((size_t)K_SEL * 4);
  u16*   updbm = (u16*)alloc((size_t)K_SEL * DOUT_DIM * 2);

  // ---- Phase 1: message passing (CSR, atomic-free)
  hipMemsetAsync(counts, 0, (size_t)N_NODES * 4, stream);
  transpose_bf16<<<dim3(DOUT_DIM / 32, DOUT_DIM / 32), 256, 0, stream>>>(
      W_prod_l, Btl, DOUT_DIM, DOUT_DIM);
  gemm64_f32<<<dim3(F_DIM / 64, N_NODES / 64, 1), 256, 0, stream>>>(
      h, F_DIM, W_node_l, F_DIM, hW, F_DIM, N_NODES, F_DIM, F_DIM, F_DIM, nullptr, 0, 0);
  count_kernel<<<E_EDGES / 256, 256, 0, stream>>>(eidx, counts);
  scan_kernel<<<1, 1024, 0, stream>>>(counts, offsets, cursor);
  fill_kernel<<<E_EDGES / 256, 256, 0, stream>>>(eidx, cursor, elist);
  gather_accum_kernel<<<N_NODES, 128, 0, stream>>>(
      hW, edge_sh, edge_feats, W_rad_l, eidx, offsets, counts, elist, upd,
      useB16 ? updb : nullptr);
  // hs (fp32-exact gate input) = upd @ W_prod_l[:, :128] + h, split-K=4 via psum
  hs_gemm_kernel<<<dim3(N_NODES / 128, 4), 256, 0, stream>>>(upd, W_prod_l, psum);
  hs_reduce_kernel<<<(N_NODES * F_DIM / 4) / 256, 256, 0, stream>>>(psum, h, hs);
  // h_local (MFMA bf16) into d_out region 0 (overwrites psum region)
  if (useB16) {
    gemm_mfma_b16<<<(DOUT_DIM / 128) * (N_NODES / 128), 256, 0, stream>>>(
        updb, Btl, out_hf, DOUT_DIM, DOUT_DIM, DOUT_DIM / 128,
        (DOUT_DIM / 128) * (N_NODES / 128), h, F_DIM, F_DIM);
  } else {
    gemm_mfma<<<dim3(DOUT_DIM / 128, N_NODES / 128), 256, 0, stream>>>(
        upd, Btl, out_hf, DOUT_DIM, N_NODES, DOUT_DIM, DOUT_DIM, h, F_DIM, F_DIM);
  }

  // ---- Phase 2
  hipMemsetAsync(adjm, 0, (size_t)2 * K_SEL * K_SEL, stream);     // adjm + adjT
  hipMemsetAsync(hist1, 0, (size_t)65536 * 4 * 2 + 256, stream);  // hist1+hist2+selb
  transpose_bf16<<<dim3(DOUT_DIM / 32, DOUT_DIM / 32), 256, 0, stream>>>(
      W_prod_h, Bth, DOUT_DIM, DOUT_DIM);
  gate_kernel<<<N_NODES / 4, 256, 0, stream>>>(hs, ms_W1, ms_b1, ms_W2, ms_b2,
                                               m_ws, out_m, hist1);
  // radix top-K selection (exact; ties broken by smaller index, matching top_k)
  radix_sel_kernel<<<1, 1024, 0, stream>>>(hist1, nullptr, 0, selb, 0);
  hist2_kernel<<<N_NODES / 256, 256, 0, stream>>>(m_ws, selb, hist2);
  radix_sel_kernel<<<1, 1024, 0, stream>>>(hist2, selb, 1, selb, 2);
  flag_kernel<<<N_NODES / 256, 256, 0, stream>>>(m_ws, selb, flags, cand);
  cand_kernel<<<1, 1024, 0, stream>>>(selb, cand, flags);
  compact_kernel<<<1, 1024, 0, stream>>>(flags, midx, rank, out_mi);
  adj_kernel<<<E_EDGES / 256, 256, 0, stream>>>(eidx, rank, adjm, adjT);
  gather_kernel<<<K_SEL, 128, 0, stream>>>(out_hf, pos, midx, h_m, pos_m);
  qk_kernel<<<K_SEL, 128, 0, stream>>>(hs, midx, vg_Wq, vg_Wk, qbuf, kbuf);
  attn_kernel<<<dim3(K_SEL / 16, K_SEL / 16), dim3(16, 16), 0, stream>>>(
      qbuf, kbuf, maskA, maskAT, out_Av);
  listbuild_kernel<<<K_SEL, 256, 0, stream>>>(adjT, maskAT, maskA, jlist, njbuf);
  hipMemsetAsync(hWn, 0, (size_t)K_SEL * F_DIM * 4, stream);
  gemm64_f32<<<dim3(F_DIM / 64, K_SEL / 64, 4), 256, 0, stream>>>(
      h_m, DOUT_DIM, W_node_h, F_DIM, hWn, F_DIM,
      K_SEL, F_DIM, DOUT_DIM, DOUT_DIM / 4, nullptr, 0, 0);
  hier2_kernel<<<K_SEL * 2, 256, 0, stream>>>(hWn, pos_m, W_rad_h, jlist, njbuf, psum2);
  hier_fin_kernel<<<(K_SEL * DOUT_DIM) / 256, 256, 0, stream>>>(psum2, updbm);
  gemm_mfma_b16<<<(DOUT_DIM / 128) * (K_SEL / 128), 256, 0, stream>>>(
      updbm, Bth, h_hier, DOUT_DIM, DOUT_DIM, DOUT_DIM / 128,
      (DOUT_DIM / 128) * (K_SEL / 128), h_m, DOUT_DIM, DOUT_DIM);
  combine_kernel<<<(N_NODES * DOUT_DIM / 4) / 256, 256, 0, stream>>>(out_hf, h_hier, m_ws, rank);
}

// Round 7
// 676.709 us; speedup vs baseline: 1.0020x; 1.0020x over previous
//
#include <hip/hip_runtime.h>
#include <hip/hip_bf16.h>
#include <stdint.h>

#define N_NODES 16384
#define E_EDGES 131072
#define F_DIM 128
#define L_DIM 9
#define R_DIM 8
#define DOUT_DIM 1152
#define K_SEL 1024
#define HID_DIM 64
#define DA_DIM 64

typedef unsigned short u16;
typedef __attribute__((ext_vector_type(8))) short bf16x8;
typedef __attribute__((ext_vector_type(4))) float f32x4;

static __device__ inline u16 f2bs(float x) {
  union { __hip_bfloat16 b; u16 s; } u;
  u.b = __float2bfloat16(x);
  return u.s;
}

// async global->LDS, 16B per lane. LDS dest must be waveBase + lane*16.
#define GLDS16(gsrc, ldst) __builtin_amdgcn_global_load_lds( \
    (__attribute__((address_space(1))) void*)(void*)(gsrc),  \
    (__attribute__((address_space(3))) void*)(ldst), 16, 0, 0)

// ================= MFMA GEMM (fallback): C = A(f32->bf16) * B^T(bf16) [+Add]
__global__ __launch_bounds__(256) void gemm_mfma(
    const float* __restrict__ A, const u16* __restrict__ Bt,
    float* __restrict__ C, int ldc, int M, int Nc, int Kc,
    const float* __restrict__ Add, int ldadd, int addW)
{
  __shared__ float Af[128 * 32];   // [m][oct ^ (m&7)]
  __shared__ u16  Bs[128 * 32];    // [n][q ^ ((n>>1)&3)]
  const int tid = threadIdx.x;
  const int wave = tid >> 6, lane = tid & 63;
  const int wm = wave >> 1, wn = wave & 1;
  const int l15 = lane & 15, quad = lane >> 4;
  const int bm = blockIdx.y * 128, bn = blockIdx.x * 128;

  f32x4 acc[4][4];
#pragma unroll
  for (int i = 0; i < 4; i++)
#pragma unroll
    for (int j = 0; j < 4; j++) acc[i][j] = (f32x4)(0.f);

  for (int k0 = 0; k0 < Kc; k0 += 32) {
    __syncthreads();
#pragma unroll
    for (int it = 0; it < 4; it++) {
      int c = it * 256 + tid;
      int row = c >> 3, op = c & 7;
      int oct = op ^ (row & 7);
      const float* g = A + (size_t)(bm + row) * Kc + k0 + oct * 4;
      GLDS16(g, &Af[c * 4]);
    }
#pragma unroll
    for (int it = 0; it < 2; it++) {
      int c = it * 256 + tid;
      int row = c >> 2, qp = c & 3;
      int q = qp ^ ((row >> 1) & 3);
      const u16* g = Bt + (size_t)(bn + row) * Kc + k0 + q * 8;
      GLDS16(g, &Bs[c * 8]);
    }
    __syncthreads();

    bf16x8 af[4], bfg[4];
#pragma unroll
    for (int mi = 0; mi < 4; mi++) {
      int m = wm * 64 + mi * 16 + l15;
      int o0 = (quad * 2) ^ (m & 7), o1 = (quad * 2 + 1) ^ (m & 7);
      float4 lo = *(const float4*)&Af[m * 32 + o0 * 4];
      float4 hi = *(const float4*)&Af[m * 32 + o1 * 4];
      bf16x8 r;
      r[0] = (short)f2bs(lo.x); r[1] = (short)f2bs(lo.y);
      r[2] = (short)f2bs(lo.z); r[3] = (short)f2bs(lo.w);
      r[4] = (short)f2bs(hi.x); r[5] = (short)f2bs(hi.y);
      r[6] = (short)f2bs(hi.z); r[7] = (short)f2bs(hi.w);
      af[mi] = r;
    }
#pragma unroll
    for (int ni = 0; ni < 4; ni++) {
      int n = wn * 64 + ni * 16 + l15;
      int q2 = quad ^ ((n >> 1) & 3);
      bfg[ni] = *(const bf16x8*)&Bs[n * 32 + q2 * 8];
    }
#pragma unroll
    for (int mi = 0; mi < 4; mi++)
#pragma unroll
      for (int ni = 0; ni < 4; ni++)
        acc[mi][ni] = __builtin_amdgcn_mfma_f32_16x16x32_bf16(af[mi], bfg[ni], acc[mi][ni], 0, 0, 0);
  }
#pragma unroll
  for (int mi = 0; mi < 4; mi++)
#pragma unroll
    for (int ni = 0; ni < 4; ni++)
#pragma unroll
      for (int r = 0; r < 4; r++) {
        int row = bm + wm * 64 + mi * 16 + quad * 4 + r;
        int col = bn + wn * 64 + ni * 16 + l15;
        float v = acc[mi][ni][r];
        if (Add != nullptr && col < addW) v += Add[(size_t)row * ldadd + col];
        C[(size_t)row * ldc + col] = v;
      }
}

// ================= MFMA GEMM, bf16 A, double-buffered prefetch.
// 1D grid with XCD-chunked swizzle (nwg % 8 == 0).
__global__ __launch_bounds__(256) void gemm_mfma_b16(
    const u16* __restrict__ A, const u16* __restrict__ Bt,
    float* __restrict__ C, int ldc, int Kc, int nbx, int nwg,
    const float* __restrict__ Add, int ldadd, int addW)
{
  __shared__ u16 As[2][128 * 32];  // [buf][m][q ^ ((m>>1)&3)]
  __shared__ u16 Bs[2][128 * 32];  // [buf][n][q ^ ((n>>1)&3)]
  const int tid = threadIdx.x;
  const int wave = tid >> 6, lane = tid & 63;
  const int wm = wave >> 1, wn = wave & 1;
  const int l15 = lane & 15, quad = lane >> 4;
  const int lin = blockIdx.x;
  const int swz = (lin & 7) * (nwg >> 3) + (lin >> 3);  // XCD-chunked, bijective
  const int bm = (swz / nbx) * 128, bn = (swz % nbx) * 128;

  const int c0 = tid,      r0 = c0 >> 2, q0 = (c0 & 3) ^ ((r0 >> 1) & 3);
  const int c1 = 256 + tid, r1 = c1 >> 2, q1 = (c1 & 3) ^ ((r1 >> 1) & 3);
  const u16* gA0 = A + (size_t)(bm + r0) * Kc + q0 * 8;
  const u16* gA1 = A + (size_t)(bm + r1) * Kc + q1 * 8;
  const u16* gB0 = Bt + (size_t)(bn + r0) * Kc + q0 * 8;
  const u16* gB1 = Bt + (size_t)(bn + r1) * Kc + q1 * 8;

  f32x4 acc[4][4];
#pragma unroll
  for (int i = 0; i < 4; i++)
#pragma unroll
    for (int j = 0; j < 4; j++) acc[i][j] = (f32x4)(0.f);

#define STAGE_AB(s, k0) do {                      \
    GLDS16(gA0 + (k0), &As[s][c0 * 8]);           \
    GLDS16(gA1 + (k0), &As[s][c1 * 8]);           \
    GLDS16(gB0 + (k0), &Bs[s][c0 * 8]);           \
    GLDS16(gB1 + (k0), &Bs[s][c1 * 8]);           \
  } while (0)

  STAGE_AB(0, 0);
  __syncthreads();
  int cur = 0;
  const int nt = Kc / 32;
  for (int t = 0; t < nt; t++) {
    if (t + 1 < nt) STAGE_AB(cur ^ 1, (t + 1) * 32);
    bf16x8 af[4], bfg[4];
#pragma unroll
    for (int mi = 0; mi < 4; mi++) {
      int m = wm * 64 + mi * 16 + l15;
      af[mi] = *(const bf16x8*)&As[cur][m * 32 + (quad ^ ((m >> 1) & 3)) * 8];
    }
#pragma unroll
    for (int ni = 0; ni < 4; ni++) {
      int n = wn * 64 + ni * 16 + l15;
      bfg[ni] = *(const bf16x8*)&Bs[cur][n * 32 + (quad ^ ((n >> 1) & 3)) * 8];
    }
#pragma unroll
    for (int mi = 0; mi < 4; mi++)
#pragma unroll
      for (int ni = 0; ni < 4; ni++)
        acc[mi][ni] = __builtin_amdgcn_mfma_f32_16x16x32_bf16(af[mi], bfg[ni], acc[mi][ni], 0, 0, 0);
    __syncthreads();
    cur ^= 1;
  }
#undef STAGE_AB

#pragma unroll
  for (int mi = 0; mi < 4; mi++)
#pragma unroll
    for (int ni = 0; ni < 4; ni++)
#pragma unroll
      for (int r = 0; r < 4; r++) {
        int row = bm + wm * 64 + mi * 16 + quad * 4 + r;
        int col = bn + wn * 64 + ni * 16 + l15;
        float v = acc[mi][ni][r];
        if (Add != nullptr && col < addW) v += Add[(size_t)row * ldadd + col];
        C[(size_t)row * ldc + col] = v;
      }
}

// ================= transpose + bf16 cast
__global__ __launch_bounds__(256) void transpose_bf16(
    const float* __restrict__ W, u16* __restrict__ Bt, int K, int N)
{
  __shared__ float t[32][33];
  const int n0 = blockIdx.x * 32, k0 = blockIdx.y * 32;
  const int tx = threadIdx.x & 31, ty = threadIdx.x >> 5;
  for (int r = ty; r < 32; r += 8) t[r][tx] = W[(size_t)(k0 + r) * N + n0 + tx];
  __syncthreads();
  for (int r = ty; r < 32; r += 8) Bt[(size_t)(n0 + r) * K + k0 + tx] = f2bs(t[tx][r]);
}

// ================= hs GEMM: psum[z] = upd[:, z*288:(z+1)*288] @ W_prod_l[z-chunk, :128]
__global__ __launch_bounds__(256) void hs_gemm_kernel(
    const float* __restrict__ A,      // upd, lda = DOUT_DIM
    const float* __restrict__ B,      // W_prod_l, ldb = DOUT_DIM (cols 0..127)
    float* __restrict__ psum)         // [4][N_NODES][F_DIM]
{
  __shared__ float As[16][129];
  __shared__ float Bs[16][128];
  const int tid = threadIdx.x;
  const int tx = tid & 15, ty = tid >> 4;
  const int bm = blockIdx.x * 128;
  const int z = blockIdx.y;
  const int kb = z * (DOUT_DIM / 4);
  const int ke = kb + DOUT_DIM / 4;
  const int ac = tid & 15, ar0 = tid >> 4;
  const int bc = tid & 127, br0 = tid >> 7;
  float acc[8][8];
#pragma unroll
  for (int i = 0; i < 8; i++)
#pragma unroll
    for (int j = 0; j < 8; j++) acc[i][j] = 0.f;

  float ra[8], rb[8];
#define LOADREG(k0) do {                                                       \
    _Pragma("unroll")                                                          \
    for (int rr = 0; rr < 8; rr++)                                             \
      ra[rr] = A[(size_t)(bm + ar0 + rr * 16) * DOUT_DIM + (k0) + ac];         \
    _Pragma("unroll")                                                          \
    for (int rr = 0; rr < 8; rr++)                                             \
      rb[rr] = B[(size_t)((k0) + br0 + rr * 2) * DOUT_DIM + bc];               \
  } while (0)

  LOADREG(kb);
  for (int k0 = kb; k0 < ke; k0 += 16) {
#pragma unroll
    for (int rr = 0; rr < 8; rr++) As[ac][ar0 + rr * 16] = ra[rr];
#pragma unroll
    for (int rr = 0; rr < 8; rr++) Bs[br0 + rr * 2][bc] = rb[rr];
    __syncthreads();
    if (k0 + 16 < ke) LOADREG(k0 + 16);
#pragma unroll
    for (int kk = 0; kk < 16; kk++) {
      float a[8], b[8];
#pragma unroll
      for (int i = 0; i < 8; i++) a[i] = As[kk][ty * 8 + i];
#pragma unroll
      for (int j = 0; j < 8; j++) b[j] = Bs[kk][tx * 8 + j];
#pragma unroll
      for (int i = 0; i < 8; i++)
#pragma unroll
        for (int j = 0; j < 8; j++) acc[i][j] = fmaf(a[i], b[j], acc[i][j]);
    }
    __syncthreads();
  }
#undef LOADREG
#pragma unroll
  for (int i = 0; i < 8; i++) {
    size_t row = (size_t)z * N_NODES + bm + ty * 8 + i;
#pragma unroll
    for (int j = 0; j < 8; j++)
      psum[row * F_DIM + tx * 8 + j] = acc[i][j];
  }
}

// hs = psum[0]+psum[1]+psum[2]+psum[3] + h   (float4)
__global__ __launch_bounds__(256) void hs_reduce_kernel(
    const float* __restrict__ psum, const float* __restrict__ h, float* __restrict__ hs)
{
  size_t i4 = (size_t)blockIdx.x * 256 + threadIdx.x;
  const size_t stride = (size_t)N_NODES * F_DIM / 4;
  const float4* p = (const float4*)psum;
  float4 a = p[i4], b = p[i4 + stride], c = p[i4 + 2 * stride], d = p[i4 + 3 * stride];
  float4 hh = ((const float4*)h)[i4];
  float4 o;
  o.x = a.x + b.x + c.x + d.x + hh.x;
  o.y = a.y + b.y + c.y + d.y + hh.y;
  o.z = a.z + b.z + c.z + d.z + hh.z;
  o.w = a.w + b.w + c.w + d.w + hh.w;
  ((float4*)hs)[i4] = o;
}

// ================= fp32 GEMM 64x64, optional split-K
__global__ __launch_bounds__(256) void gemm64_f32(
    const float* __restrict__ A, int lda,
    const float* __restrict__ B, int ldb,
    float* __restrict__ C, int ldc,
    int M, int Nc, int Kc, int kPerSplit,
    const float* __restrict__ Add, int ldadd, int addW)
{
  __shared__ float As[16][65];
  __shared__ float Bs[16][64];
  const int tid = threadIdx.x;
  const int tx = tid & 15, ty = tid >> 4;
  const int bm = blockIdx.y * 64, bn = blockIdx.x * 64;
  const int kb = blockIdx.z * kPerSplit;
  const int ke = min(kb + kPerSplit, Kc);
  float acc[4][4];
#pragma unroll
  for (int i = 0; i < 4; i++)
#pragma unroll
    for (int j = 0; j < 4; j++) acc[i][j] = 0.f;
  for (int k0 = kb; k0 < ke; k0 += 16) {
    const int ac = tid & 15, ar = tid >> 4;
#pragma unroll
    for (int rr = 0; rr < 4; rr++) {
      int row = ar + rr * 16;
      As[ac][row] = A[(size_t)(bm + row) * lda + k0 + ac];
    }
    const int bc = tid & 63, br = tid >> 6;
#pragma unroll
    for (int rr = 0; rr < 4; rr++) {
      int kr = br + rr * 4;
      Bs[kr][bc] = B[(size_t)(k0 + kr) * ldb + bn + bc];
    }
    __syncthreads();
#pragma unroll
    for (int kk = 0; kk < 16; kk++) {
      float a[4], b[4];
#pragma unroll
      for (int i = 0; i < 4; i++) a[i] = As[kk][ty * 4 + i];
#pragma unroll
      for (int j = 0; j < 4; j++) b[j] = Bs[kk][tx * 4 + j];
#pragma unroll
      for (int i = 0; i < 4; i++)
#pragma unroll
        for (int j = 0; j < 4; j++) acc[i][j] = fmaf(a[i], b[j], acc[i][j]);
    }
    __syncthreads();
  }
#pragma unroll
  for (int i = 0; i < 4; i++) {
    int row = bm + ty * 4 + i;
#pragma unroll
    for (int j = 0; j < 4; j++) {
      int col = bn + tx * 4 + j;
      if (gridDim.z > 1) {
        atomicAdd(&C[(size_t)row * ldc + col], acc[i][j]);
      } else {
        float v = acc[i][j];
        if (Add != nullptr && col < addW) v += Add[(size_t)row * ldadd + col];
        C[(size_t)row * ldc + col] = v;
      }
    }
  }
}

// ================= CSR build: count / scan / fill
__global__ __launch_bounds__(256) void count_kernel(
    const int* __restrict__ ei, int* __restrict__ counts)
{
  int e = blockIdx.x * 256 + threadIdx.x;
  atomicAdd(&counts[ei[E_EDGES + e]], 1);
}

__global__ __launch_bounds__(1024) void scan_kernel(
    const int* __restrict__ counts, int* __restrict__ offsets, int* __restrict__ cursor)
{
  __shared__ int part[1024];
  const int t = threadIdx.x;
  const int base = t * 16;
  int loc[16];
  int s = 0;
#pragma unroll
  for (int k = 0; k < 16; k++) { loc[k] = counts[base + k]; s += loc[k]; }
  part[t] = s;
  __syncthreads();
  for (int d = 1; d < 1024; d <<= 1) {
    int v = (t >= d) ? part[t - d] : 0;
    __syncthreads();
    part[t] += v;
    __syncthreads();
  }
  int run = part[t] - s;  // exclusive prefix
#pragma unroll
  for (int k = 0; k < 16; k++) {
    offsets[base + k] = run;
    cursor[base + k] = run;
    run += loc[k];
  }
}

__global__ __launch_bounds__(256) void fill_kernel(
    const int* __restrict__ ei, int* __restrict__ cursor, int* __restrict__ elist)
{
  int e = blockIdx.x * 256 + threadIdx.x;
  int d = ei[E_EDGES + e];
  int p = atomicAdd(&cursor[d], 1);
  elist[p] = e;
}

// ================= atomic-free edge accumulation: block per dst node.
__global__ __launch_bounds__(128) void gather_accum_kernel(
    const float* __restrict__ hW, const float* __restrict__ edge_sh,
    const float* __restrict__ edge_feats, const float* __restrict__ W_rad_l,
    const int* __restrict__ ei, const int* __restrict__ offsets,
    const int* __restrict__ counts, const int* __restrict__ elist,
    float* __restrict__ upd, u16* __restrict__ updb)
{
  const int d = blockIdx.x, f = threadIdx.x;
  const float w0 = W_rad_l[0 * F_DIM + f], w1 = W_rad_l[1 * F_DIM + f];
  const float w2 = W_rad_l[2 * F_DIM + f], w3 = W_rad_l[3 * F_DIM + f];
  const float w4 = W_rad_l[4 * F_DIM + f], w5 = W_rad_l[5 * F_DIM + f];
  const float w6 = W_rad_l[6 * F_DIM + f], w7 = W_rad_l[7 * F_DIM + f];
  const int b = offsets[d], n = counts[d];
  float acc[L_DIM];
#pragma unroll
  for (int l = 0; l < L_DIM; l++) acc[l] = 0.f;
  for (int k = 0; k < n; k++) {
    const int e = elist[b + k];
    const int s = ei[e];
    const float4 ef0 = *(const float4*)&edge_feats[(size_t)e * R_DIM];
    const float4 ef1 = *(const float4*)&edge_feats[(size_t)e * R_DIM + 4];
    float rw = ef0.x * w0;
    rw = fmaf(ef0.y, w1, rw); rw = fmaf(ef0.z, w2, rw); rw = fmaf(ef0.w, w3, rw);
    rw = fmaf(ef1.x, w4, rw); rw = fmaf(ef1.y, w5, rw);
    rw = fmaf(ef1.z, w6, rw); rw = fmaf(ef1.w, w7, rw);
    const float tf = hW[(size_t)s * F_DIM + f] * rw;
#pragma unroll
    for (int l = 0; l < L_DIM; l++)
      acc[l] = fmaf(edge_sh[(size_t)e * L_DIM + l], tf, acc[l]);
  }
#pragma unroll
  for (int l = 0; l < L_DIM; l++)
    upd[(size_t)d * DOUT_DIM + l * F_DIM + f] = acc[l];
  if (updb != nullptr) {
#pragma unroll
    for (int l = 0; l < L_DIM; l++)
      updb[(size_t)d * DOUT_DIM + l * F_DIM + f] = f2bs(acc[l]);
  }
}

// ================= gating MLP on hs (fp32, ld=F_DIM) + fused 16-bit histogram
__global__ __launch_bounds__(256) void gate_kernel(
    const float* __restrict__ hs, const float* __restrict__ W1,
    const float* __restrict__ b1, const float* __restrict__ W2,
    const float* __restrict__ b2, float* __restrict__ m_ws, float* __restrict__ m_out,
    int* __restrict__ hist1)
{
  __shared__ float sW1[F_DIM * HID_DIM];
  __shared__ float srow[4][F_DIM];
  const int tid = threadIdx.x;
  for (int t = tid; t < F_DIM * HID_DIM; t += 256) sW1[t] = W1[t];
  const int wave = tid >> 6, lane = tid & 63;
  const int n = blockIdx.x * 4 + wave;
  srow[wave][lane] = hs[(size_t)n * F_DIM + lane];
  srow[wave][lane + 64] = hs[(size_t)n * F_DIM + lane + 64];
  __syncthreads();
  float hid = b1[lane];
#pragma unroll 8
  for (int c = 0; c < F_DIM; c++) hid = fmaf(srow[wave][c], sW1[c * HID_DIM + lane], hid);
  hid = fmaxf(hid, 0.f);
  float v = hid * W2[lane];
#pragma unroll
  for (int off = 32; off > 0; off >>= 1) v += __shfl_down(v, off);
  if (lane == 0) {
    float mm = 1.f / (1.f + expf(-(v + b2[0])));
    m_ws[n] = mm;
    m_out[n] = mm;
    unsigned mb = __float_as_uint(mm);
    atomicAdd(&hist1[mb >> 16], 1);
  }
}

// ================= radix top-K selection
__global__ __launch_bounds__(1024) void radix_sel_kernel(
    const int* __restrict__ hist, const int* __restrict__ kin, int kinIdx,
    int* __restrict__ outp, int outIdx)
{
  __shared__ int part[1024];
  const int t = threadIdx.x;
  const int Kv = kin ? kin[kinIdx] : K_SEL;
  const int base = t * 64;
  int s = 0;
  for (int k = 0; k < 64; k++) s += hist[base + k];
  part[t] = s;
  __syncthreads();
  for (int d = 1; d < 1024; d <<= 1) {
    int v = (t + d < 1024) ? part[t + d] : 0;
    __syncthreads();
    part[t] += v;
    __syncthreads();
  }
  int inc = part[t];
  if (inc >= Kv && inc - s < Kv) {
    int r = inc - s;
    for (int b = base + 63; b >= base; b--) {
      int hv = hist[b];
      if (r + hv >= Kv) { outp[outIdx] = b; outp[outIdx + 1] = Kv - r; break; }
      r += hv;
    }
  }
}

__global__ __launch_bounds__(256) void hist2_kernel(
    const float* __restrict__ m_ws, const int* __restrict__ selb, int* __restrict__ hist2)
{
  int i = blockIdx.x * 256 + threadIdx.x;
  unsigned mb = __float_as_uint(m_ws[i]);
  if ((int)(mb >> 16) == selb[0]) atomicAdd(&hist2[mb & 0xFFFFu], 1);
}

__global__ __launch_bounds__(256) void flag_kernel(
    const float* __restrict__ m_ws, int* __restrict__ selb,
    unsigned char* __restrict__ flags, int* __restrict__ cand)
{
  int i = blockIdx.x * 256 + threadIdx.x;
  unsigned mb = __float_as_uint(m_ws[i]);
  unsigned vb = ((unsigned)selb[0] << 16) | (unsigned)selb[2];
  unsigned char fl = 0;
  if (mb > vb) fl = 1;
  else if (mb == vb) { int p = atomicAdd(&selb[4], 1); cand[p] = i; }
  flags[i] = fl;
}

__global__ __launch_bounds__(1024) void cand_kernel(
    const int* __restrict__ selb, const int* __restrict__ cand, unsigned char* __restrict__ flags)
{
  const int nc = selb[4], need = selb[3];
  for (int c = threadIdx.x; c < nc; c += 1024) {
    const int idx = cand[c];
    int r = 0;
    for (int o = 0; o < nc; o++) r += (cand[o] < idx) ? 1 : 0;
    if (r < need) flags[idx] = 1;
  }
}

__global__ __launch_bounds__(1024) void compact_kernel(
    const unsigned char* __restrict__ flags, int* __restrict__ midx,
    int* __restrict__ rank, float* __restrict__ mi_out)
{
  __shared__ int part[1024];
  const int t = threadIdx.x;
  const int base = t * 16;
  int loc[16];
  int s = 0;
#pragma unroll
  for (int k = 0; k < 16; k++) { loc[k] = flags[base + k]; s += loc[k]; }
  part[t] = s;
  __syncthreads();
  for (int d = 1; d < 1024; d <<= 1) {
    int v = (t >= d) ? part[t - d] : 0;
    __syncthreads();
    part[t] += v;
    __syncthreads();
  }
  int run = part[t] - s;
#pragma unroll
  for (int k = 0; k < 16; k++) {
    int i = base + k;
    if (loc[k]) {
      midx[run] = i;
      mi_out[run] = (float)i;
      rank[i] = run;
      run++;
    } else {
      rank[i] = K_SEL;
    }
  }
}

// ================= induced adjacency (+ transposed copy for coalesced listbuild)
__global__ __launch_bounds__(256) void adj_kernel(
    const int* __restrict__ ei, const int* __restrict__ rank,
    unsigned char* __restrict__ adjm, unsigned char* __restrict__ adjT)
{
  int e = blockIdx.x * 256 + threadIdx.x;
  int rs = rank[ei[e]];
  int rd = rank[ei[E_EDGES + e]];
  if (rs < K_SEL && rd < K_SEL) {
    adjm[(size_t)rs * K_SEL + rd] = 1;
    adjT[(size_t)rd * K_SEL + rs] = 1;
  }
}

// ================= gather master rows + positions (float4)
__global__ __launch_bounds__(128) void gather_kernel(
    const float* __restrict__ hl, const float* __restrict__ pos,
    const int* __restrict__ midx, float* __restrict__ h_m, float* __restrict__ pos_m)
{
  const int rI = blockIdx.x, t = threadIdx.x;
  const int mi = midx[rI];
  const float4* src = (const float4*)(hl + (size_t)mi * DOUT_DIM);
  float4* dst = (float4*)(h_m + (size_t)rI * DOUT_DIM);
  for (int c = t; c < DOUT_DIM / 4; c += 128) dst[c] = src[c];
  if (t < 3) pos_m[rI * 3 + t] = pos[mi * 3 + t];
}

// ================= q/k projections from hs at master rows
__global__ __launch_bounds__(128) void qk_kernel(
    const float* __restrict__ hs, const int* __restrict__ midx,
    const float* __restrict__ Wq, const float* __restrict__ Wk,
    float* __restrict__ q, float* __restrict__ kk)
{
  __shared__ float row[F_DIM];
  const int i = blockIdx.x, t = threadIdx.x;
  const int mi = midx[i];
  row[t] = hs[(size_t)mi * F_DIM + t];
  __syncthreads();
  const int d = t & 63;
  const float* W = (t < 64) ? Wq : Wk;
  float acc = 0.f;
#pragma unroll 8
  for (int c = 0; c < F_DIM; c++) acc = fmaf(row[c], W[c * DA_DIM + d], acc);
  float* dst = (t < 64) ? q : kk;
  dst[(size_t)i * DA_DIM + d] = acc;
}

// ================= attention (padded LDS; also emits transposed mask)
__global__ __launch_bounds__(256) void attn_kernel(
    const float* __restrict__ q, const float* __restrict__ kk,
    unsigned char* __restrict__ maskA, unsigned char* __restrict__ maskAT,
    float* __restrict__ Av)
{
  __shared__ float qs[16][DA_DIM + 1], ks[16][DA_DIM + 1];
  const int tx = threadIdx.x, ty = threadIdx.y;
  const int tid = ty * 16 + tx;
  const int i0 = blockIdx.y * 16, j0 = blockIdx.x * 16;
  for (int t = tid; t < 16 * DA_DIM; t += 256) {
    int rr = t >> 6, cc = t & 63;
    qs[rr][cc] = q[(size_t)(i0 + rr) * DA_DIM + cc];
    ks[rr][cc] = kk[(size_t)(j0 + rr) * DA_DIM + cc];
  }
  __syncthreads();
  float acc = 0.f;
#pragma unroll
  for (int d2 = 0; d2 < DA_DIM; d2++) acc = fmaf(qs[ty][d2], ks[tx][d2], acc);
  float sgl = 1.f / (1.f + expf(-acc * 0.125f));
  size_t o = (size_t)(i0 + ty) * K_SEL + (j0 + tx);
  bool big = sgl > 0.5f;
  unsigned char bb = big ? 1 : 0;
  maskA[o] = bb;
  maskAT[(size_t)(j0 + tx) * K_SEL + (i0 + ty)] = bb;
  Av[o] = big ? sgl : 0.f;
}

// ================= per-i active-j list (coalesced row reads + wave-ballot)
__global__ __launch_bounds__(256) void listbuild_kernel(
    const unsigned char* __restrict__ adjT, const unsigned char* __restrict__ maskAT,
    const unsigned char* __restrict__ maskA, u16* __restrict__ list, int* __restrict__ nj)
{
  __shared__ int cnt;
  const int i = blockIdx.x, tid = threadIdx.x;
  const int lane = tid & 63;
  if (tid == 0) cnt = 0;
  __syncthreads();
  const int j0 = tid * 4;
  uchar4 a  = *(const uchar4*)&adjT  [(size_t)i * K_SEL + j0];
  uchar4 mt = *(const uchar4*)&maskAT[(size_t)i * K_SEL + j0];
  uchar4 ma = *(const uchar4*)&maskA [(size_t)i * K_SEL + j0];
  unsigned char av[4];
  av[0] = a.x | mt.x | ma.x; av[1] = a.y | mt.y | ma.y;
  av[2] = a.z | mt.z | ma.z; av[3] = a.w | mt.w | ma.w;
#pragma unroll
  for (int r = 0; r < 4; r++) {
    int j = j0 + r;
    bool e = (j != i) && av[r];
    unsigned long long m = __ballot(e);
    int nset = __popcll(m);
    int base = 0;
    if (lane == 0 && nset) base = atomicAdd(&cnt, nset);
    base = __shfl(base, 0);
    if (e) {
      int p = base + __popcll(m & ((1ull << lane) - 1ull));
      list[(size_t)i * K_SEL + p] = (u16)j;
    }
  }
  __syncthreads();
  if (tid == 0) nj[i] = cnt;
}

// ================= hier v5: uniform work quanta — one block = one (i, 128-pair chunk).
// Grid K_SEL*8 of 128 threads (2 waves); >2x oversubscription -> scheduler refills,
// tail imbalance gone. Partials accumulated with fp32 atomicAdd into zeroed upd_m.
__global__ __launch_bounds__(128) void hier3_kernel(
    const float* __restrict__ hWn, const float* __restrict__ pos_m,
    const float* __restrict__ W_rad_h, const u16* __restrict__ list,
    const int* __restrict__ nj, float* __restrict__ upd_m)
{
  __shared__ float gsm[128][20];   // [pair][rd0..7, sh0..8, jbits, pad, pad]
  const int bid = blockIdx.x;
  const int i = bid >> 3, ch = bid & 7;
  const int n = nj[i];
  const int c0 = ch * 128;
  if (c0 >= n) return;             // block-uniform: no work for this chunk
  const int cnt = min(128, n - c0);
  const int f = threadIdx.x;
  const float sw0 = W_rad_h[0 * F_DIM + f], sw1 = W_rad_h[1 * F_DIM + f];
  const float sw2 = W_rad_h[2 * F_DIM + f], sw3 = W_rad_h[3 * F_DIM + f];
  const float sw4 = W_rad_h[4 * F_DIM + f], sw5 = W_rad_h[5 * F_DIM + f];
  const float sw6 = W_rad_h[6 * F_DIM + f], sw7 = W_rad_h[7 * F_DIM + f];
  const float* hWf = hWn + f;
  const float pix = pos_m[i * 3 + 0], piy = pos_m[i * 3 + 1], piz = pos_m[i * 3 + 2];

  if (f < cnt) {
    const int j = list[(size_t)i * K_SEL + c0 + f];
    float vx = pos_m[j * 3 + 0] - pix;
    float vy = pos_m[j * 3 + 1] - piy;
    float vz = pos_m[j * 3 + 2] - piz;
    float r = sqrtf(vx * vx + vy * vy + vz * vz);
    float rm = fmaxf(r, 1e-9f);
    float inv = 1.f / rm;
    float ux = vx * inv, uy = vy * inv, uz = vz * inv;
    float theta = 0.62831853071795864769f * r;  // pi/R_CUT
    float s1 = sinf(theta), c1 = cosf(theta);
    float coef = 0.632455532033675866f * inv;   // sqrt(2/R_CUT)/max(r,eps)
    float snm2 = 0.f, snm1 = s1;
    gsm[f][0] = s1 * coef;
#pragma unroll
    for (int nn = 2; nn <= R_DIM; nn++) {
      float sn = 2.f * c1 * snm1 - snm2;
      gsm[f][nn - 1] = sn * coef;
      snm2 = snm1; snm1 = sn;
    }
    gsm[f][8] = 1.f; gsm[f][9] = ux; gsm[f][10] = uy; gsm[f][11] = uz;
    gsm[f][12] = ux * uy; gsm[f][13] = uy * uz;
    gsm[f][14] = 3.f * uz * uz - 1.f;
    gsm[f][15] = ux * uz; gsm[f][16] = ux * ux - uy * uy;
    gsm[f][17] = __int_as_float(j);
  }
  __syncthreads();

  float acc[L_DIM];
#pragma unroll
  for (int l = 0; l < L_DIM; l++) acc[l] = 0.f;

#define HBODY(tt)                                                        \
  { float2 s2 = *(const float2*)&gsm[tt][16];                            \
    const int jj = __float_as_int(s2.y);                                 \
    const float hw = hWf[(size_t)jj * F_DIM];                            \
    float4 r0 = *(const float4*)&gsm[tt][0];                             \
    float4 r1 = *(const float4*)&gsm[tt][4];                             \
    float4 s0 = *(const float4*)&gsm[tt][8];                             \
    float4 s1g = *(const float4*)&gsm[tt][12];                           \
    float rw = r0.x * sw0;                                               \
    rw = fmaf(r0.y, sw1, rw); rw = fmaf(r0.z, sw2, rw);                  \
    rw = fmaf(r0.w, sw3, rw); rw = fmaf(r1.x, sw4, rw);                  \
    rw = fmaf(r1.y, sw5, rw); rw = fmaf(r1.z, sw6, rw);                  \
    rw = fmaf(r1.w, sw7, rw);                                            \
    const float tm = hw * rw;                                            \
    acc[0] = fmaf(s0.x, tm, acc[0]); acc[1] = fmaf(s0.y, tm, acc[1]);    \
    acc[2] = fmaf(s0.z, tm, acc[2]); acc[3] = fmaf(s0.w, tm, acc[3]);    \
    acc[4] = fmaf(s1g.x, tm, acc[4]); acc[5] = fmaf(s1g.y, tm, acc[5]);  \
    acc[6] = fmaf(s1g.z, tm, acc[6]); acc[7] = fmaf(s1g.w, tm, acc[7]);  \
    acc[8] = fmaf(s2.x, tm, acc[8]); }

  int t = 0;
  for (; t + 1 < cnt; t += 2) { HBODY(t); HBODY(t + 1); }
  for (; t < cnt; t++) { HBODY(t); }
#undef HBODY

#pragma unroll
  for (int l = 0; l < L_DIM; l++)
    atomicAdd(&upd_m[(size_t)i * DOUT_DIM + l * F_DIM + f], acc[l]);
}

// updbm = bf16(upd_m)
__global__ __launch_bounds__(256) void cast_bf16_kernel(
    const float* __restrict__ x, u16* __restrict__ y)
{
  size_t idx = (size_t)blockIdx.x * 256 + threadIdx.x;
  y[idx] = f2bs(x[idx]);
}

// ================= final blend (float4; 1152 % 4 == 0, vector never spans rows)
__global__ __launch_bounds__(256) void combine_kernel(
    float* __restrict__ out0, const float* __restrict__ h_hier,
    const float* __restrict__ m_ws, const int* __restrict__ rank)
{
  size_t i4 = (size_t)blockIdx.x * 256 + threadIdx.x;
  int n = (int)(i4 / (DOUT_DIM / 4));
  int g4 = (int)(i4 % (DOUT_DIM / 4));
  float mv = m_ws[n];
  int r = rank[n];
  float4 hl = ((const float4*)out0)[i4];
  float4 he = make_float4(0.f, 0.f, 0.f, 0.f);
  if (r < K_SEL) he = ((const float4*)h_hier)[(size_t)r * (DOUT_DIM / 4) + g4];
  float4 o;
  o.x = (1.f - mv) * hl.x + mv * he.x;
  o.y = (1.f - mv) * hl.y + mv * he.y;
  o.z = (1.f - mv) * hl.z + mv * he.z;
  o.w = (1.f - mv) * hl.w + mv * he.w;
  ((float4*)out0)[i4] = o;
}

extern "C" void kernel_launch(void* const* d_in, const int* in_sizes, int n_in,
                              void* d_out, int out_size, void* d_ws, size_t ws_size,
                              hipStream_t stream)
{
  const float* h         = (const float*)d_in[0];
  const float* pos       = (const float*)d_in[1];
  const float* edge_sh   = (const float*)d_in[2];
  const float* edge_feats= (const float*)d_in[3];
  const float* W_node_l  = (const float*)d_in[4];
  const float* W_rad_l   = (const float*)d_in[5];
  const float* W_prod_l  = (const float*)d_in[6];
  const float* ms_W1     = (const float*)d_in[7];
  const float* ms_b1     = (const float*)d_in[8];
  const float* ms_W2     = (const float*)d_in[9];
  const float* ms_b2     = (const float*)d_in[10];
  const float* vg_Wq     = (const float*)d_in[11];
  const float* vg_Wk     = (const float*)d_in[12];
  const float* W_node_h  = (const float*)d_in[13];
  const float* W_rad_h   = (const float*)d_in[14];
  const float* W_prod_h  = (const float*)d_in[15];
  const int*   eidx      = (const int*)d_in[16];

  float* out    = (float*)d_out;
  float* out_hf = out;
  float* out_Av = out + (size_t)N_NODES * DOUT_DIM;
  float* out_m  = out_Av + (size_t)K_SEL * K_SEL;
  float* out_mi = out_m + N_NODES;

  char* ws = (char*)d_ws;
  // Phase 1: upd [0, 75.5MB); hW/hs [75.5, 83.9MB); optional updb [83.9, 121.6MB).
  float* upd = (float*)ws;
  float* hW  = (float*)(ws + (size_t)N_NODES * DOUT_DIM * 4);
  float* hs  = hW;  // hW dead after gather_accum; hs written after
  const size_t updbOff = (size_t)N_NODES * DOUT_DIM * 4 + (size_t)N_NODES * F_DIM * 4;
  const size_t updbNeed = updbOff + (size_t)N_NODES * DOUT_DIM * 2;
  const bool useB16 = (ws_size >= updbNeed);
  u16* updb = (u16*)(ws + updbOff);
  // hs split-K partials borrow out_hf (75.5MB, dead until gemm_mfma_b16 writes it).
  float* psum = out_hf;   // 4 * 16384 * 128 * 4B = 33.6 MB < 75.5 MB
  // Btl + CSR borrow the A_virtual out region (4MB, dead until attn writes it).
  u16* Btl = (u16*)out_Av;                                       // 2.65 MB
  char* csr = (char*)out_Av + (((size_t)DOUT_DIM * DOUT_DIM * 2 + 255) & ~(size_t)255);
  int* counts  = (int*)csr;                                      // 64 KB
  int* offsets = counts + N_NODES;                               // 64 KB
  int* cursor  = offsets + N_NODES;                              // 64 KB
  int* elist   = cursor + N_NODES;                               // 512 KB  (total 3.4MB < 4MB)
  // Phase 2 small pool aliases dead upd.
  size_t off = 0;
  auto alloc = [&](size_t bytes) -> void* {
    void* p = ws + off;
    off += (bytes + 255) & ~(size_t)255;
    return p;
  };
  float* m_ws  = (float*)alloc((size_t)N_NODES * 4);
  int*   rank  = (int*)alloc((size_t)N_NODES * 4);
  int*   midx  = (int*)alloc((size_t)K_SEL * 4);
  int*   hist1 = (int*)alloc((size_t)65536 * 4);
  int*   hist2 = (int*)alloc((size_t)65536 * 4);
  int*   selb  = (int*)alloc((size_t)64 * 4);   // [0]=b1 [1]=need1 [2]=b2 [3]=need2 [4]=ncand
  int*   cand  = (int*)alloc((size_t)N_NODES * 4);
  unsigned char* flags = (unsigned char*)alloc((size_t)N_NODES);
  unsigned char* adjm  = (unsigned char*)alloc((size_t)K_SEL * K_SEL);
  unsigned char* adjT  = (unsigned char*)alloc((size_t)K_SEL * K_SEL);  // contiguous after adjm
  unsigned char* maskA = (unsigned char*)alloc((size_t)K_SEL * K_SEL);
  unsigned char* maskAT= (unsigned char*)alloc((size_t)K_SEL * K_SEL);
  float* qbuf  = (float*)alloc((size_t)K_SEL * DA_DIM * 4);
  float* kbuf  = (float*)alloc((size_t)K_SEL * DA_DIM * 4);
  float* h_m   = (float*)alloc((size_t)K_SEL * DOUT_DIM * 4);
  float* pos_m = (float*)alloc((size_t)K_SEL * 3 * 4);
  float* hWn   = (float*)alloc((size_t)K_SEL * F_DIM * 4);
  float* upd_m = (float*)alloc((size_t)K_SEL * DOUT_DIM * 4);
  float* h_hier= (float*)alloc((size_t)K_SEL * DOUT_DIM * 4);
  u16*   Bth   = (u16*)alloc((size_t)DOUT_DIM * DOUT_DIM * 2);
  u16*   jlist = (u16*)alloc((size_t)K_SEL * K_SEL * 2);
  int*   njbuf = (int*)alloc((size_t)K_SEL * 4);
  u16*   updbm = (u16*)alloc((size_t)K_SEL * DOUT_DIM * 2);

  // ---- Phase 1: message passing (CSR, atomic-free)
  hipMemsetAsync(counts, 0, (size_t)N_NODES * 4, stream);
  transpose_bf16<<<dim3(DOUT_DIM / 32, DOUT_DIM / 32), 256, 0, stream>>>(
      W_prod_l, Btl, DOUT_DIM, DOUT_DIM);
  gemm64_f32<<<dim3(F_DIM / 64, N_NODES / 64, 1), 256, 0, stream>>>(
      h, F_DIM, W_node_l, F_DIM, hW, F_DIM, N_NODES, F_DIM, F_DIM, F_DIM, nullptr, 0, 0);
  count_kernel<<<E_EDGES / 256, 256, 0, stream>>>(eidx, counts);
  scan_kernel<<<1, 1024, 0, stream>>>(counts, offsets, cursor);
  fill_kernel<<<E_EDGES / 256, 256, 0, stream>>>(eidx, cursor, elist);
  gather_accum_kernel<<<N_NODES, 128, 0, stream>>>(
      hW, edge_sh, edge_feats, W_rad_l, eidx, offsets, counts, elist, upd,
      useB16 ? updb : nullptr);
  // hs (fp32-exact gate input) = upd @ W_prod_l[:, :128] + h, split-K=4 via psum
  hs_gemm_kernel<<<dim3(N_NODES / 128, 4), 256, 0, stream>>>(upd, W_prod_l, psum);
  hs_reduce_kernel<<<(N_NODES * F_DIM / 4) / 256, 256, 0, stream>>>(psum, h, hs);
  // h_local (MFMA bf16) into d_out region 0 (overwrites psum region)
  if (useB16) {
    gemm_mfma_b16<<<(DOUT_DIM / 128) * (N_NODES / 128), 256, 0, stream>>>(
        updb, Btl, out_hf, DOUT_DIM, DOUT_DIM, DOUT_DIM / 128,
        (DOUT_DIM / 128) * (N_NODES / 128), h, F_DIM, F_DIM);
  } else {
    gemm_mfma<<<dim3(DOUT_DIM / 128, N_NODES / 128), 256, 0, stream>>>(
        upd, Btl, out_hf, DOUT_DIM, N_NODES, DOUT_DIM, DOUT_DIM, h, F_DIM, F_DIM);
  }

  // ---- Phase 2
  hipMemsetAsync(adjm, 0, (size_t)2 * K_SEL * K_SEL, stream);     // adjm + adjT
  hipMemsetAsync(hist1, 0, (size_t)65536 * 4 * 2 + 256, stream);  // hist1+hist2+selb
  hipMemsetAsync(upd_m, 0, (size_t)K_SEL * DOUT_DIM * 4, stream); // hier3 accum target
  transpose_bf16<<<dim3(DOUT_DIM / 32, DOUT_DIM / 32), 256, 0, stream>>>(
      W_prod_h, Bth, DOUT_DIM, DOUT_DIM);
  gate_kernel<<<N_NODES / 4, 256, 0, stream>>>(hs, ms_W1, ms_b1, ms_W2, ms_b2,
                                               m_ws, out_m, hist1);
  // radix top-K selection (exact; ties broken by smaller index, matching top_k)
  radix_sel_kernel<<<1, 1024, 0, stream>>>(hist1, nullptr, 0, selb, 0);
  hist2_kernel<<<N_NODES / 256, 256, 0, stream>>>(m_ws, selb, hist2);
  radix_sel_kernel<<<1, 1024, 0, stream>>>(hist2, selb, 1, selb, 2);
  flag_kernel<<<N_NODES / 256, 256, 0, stream>>>(m_ws, selb, flags, cand);
  cand_kernel<<<1, 1024, 0, stream>>>(selb, cand, flags);
  compact_kernel<<<1, 1024, 0, stream>>>(flags, midx, rank, out_mi);
  adj_kernel<<<E_EDGES / 256, 256, 0, stream>>>(eidx, rank, adjm, adjT);
  gather_kernel<<<K_SEL, 128, 0, stream>>>(out_hf, pos, midx, h_m, pos_m);
  qk_kernel<<<K_SEL, 128, 0, stream>>>(hs, midx, vg_Wq, vg_Wk, qbuf, kbuf);
  attn_kernel<<<dim3(K_SEL / 16, K_SEL / 16), dim3(16, 16), 0, stream>>>(
      qbuf, kbuf, maskA, maskAT, out_Av);
  listbuild_kernel<<<K_SEL, 256, 0, stream>>>(adjT, maskAT, maskA, jlist, njbuf);
  hipMemsetAsync(hWn, 0, (size_t)K_SEL * F_DIM * 4, stream);
  gemm64_f32<<<dim3(F_DIM / 64, K_SEL / 64, 4), 256, 0, stream>>>(
      h_m, DOUT_DIM, W_node_h, F_DIM, hWn, F_DIM,
      K_SEL, F_DIM, DOUT_DIM, DOUT_DIM / 4, nullptr, 0, 0);
  hier3_kernel<<<K_SEL * 8, 128, 0, stream>>>(hWn, pos_m, W_rad_h, jlist, njbuf, upd_m);
  cast_bf16_kernel<<<(K_SEL * DOUT_DIM) / 256, 256, 0, stream>>>(upd_m, updbm);
  gemm_mfma_b16<<<(DOUT_DIM / 128) * (K_SEL / 128), 256, 0, stream>>>(
      updbm, Bth, h_hier, DOUT_DIM, DOUT_DIM, DOUT_DIM / 128,
      (DOUT_DIM / 128) * (K_SEL / 128), h_m, DOUT_DIM, DOUT_DIM);
  combine_kernel<<<(N_NODES * DOUT_DIM / 4) / 256, 256, 0, stream>>>(out_hf, h_hier, m_ws, rank);
}

// Round 8
// 667.826 us; speedup vs baseline: 1.0153x; 1.0133x over previous
//
#include <hip/hip_runtime.h>
#include <hip/hip_bf16.h>
#include <stdint.h>

#define N_NODES 16384
#define E_EDGES 131072
#define F_DIM 128
#define L_DIM 9
#define R_DIM 8
#define DOUT_DIM 1152
#define K_SEL 1024
#define HID_DIM 64
#define DA_DIM 64

typedef unsigned short u16;
typedef __attribute__((ext_vector_type(8))) short bf16x8;
typedef __attribute__((ext_vector_type(4))) float f32x4;

static __device__ inline u16 f2bs(float x) {
  union { __hip_bfloat16 b; u16 s; } u;
  u.b = __float2bfloat16(x);
  return u.s;
}

// async global->LDS, 16B per lane. LDS dest must be waveBase + lane*16.
#define GLDS16(gsrc, ldst) __builtin_amdgcn_global_load_lds( \
    (__attribute__((address_space(1))) void*)(void*)(gsrc),  \
    (__attribute__((address_space(3))) void*)(ldst), 16, 0, 0)

// ================= MFMA GEMM (fallback): C = A(f32->bf16) * B^T(bf16) [+Add]
__global__ __launch_bounds__(256) void gemm_mfma(
    const float* __restrict__ A, const u16* __restrict__ Bt,
    float* __restrict__ C, int ldc, int M, int Nc, int Kc,
    const float* __restrict__ Add, int ldadd, int addW)
{
  __shared__ float Af[128 * 32];   // [m][oct ^ (m&7)]
  __shared__ u16  Bs[128 * 32];    // [n][q ^ ((n>>1)&3)]
  const int tid = threadIdx.x;
  const int wave = tid >> 6, lane = tid & 63;
  const int wm = wave >> 1, wn = wave & 1;
  const int l15 = lane & 15, quad = lane >> 4;
  const int bm = blockIdx.y * 128, bn = blockIdx.x * 128;

  f32x4 acc[4][4];
#pragma unroll
  for (int i = 0; i < 4; i++)
#pragma unroll
    for (int j = 0; j < 4; j++) acc[i][j] = (f32x4)(0.f);

  for (int k0 = 0; k0 < Kc; k0 += 32) {
    __syncthreads();
#pragma unroll
    for (int it = 0; it < 4; it++) {
      int c = it * 256 + tid;
      int row = c >> 3, op = c & 7;
      int oct = op ^ (row & 7);
      const float* g = A + (size_t)(bm + row) * Kc + k0 + oct * 4;
      GLDS16(g, &Af[c * 4]);
    }
#pragma unroll
    for (int it = 0; it < 2; it++) {
      int c = it * 256 + tid;
      int row = c >> 2, qp = c & 3;
      int q = qp ^ ((row >> 1) & 3);
      const u16* g = Bt + (size_t)(bn + row) * Kc + k0 + q * 8;
      GLDS16(g, &Bs[c * 8]);
    }
    __syncthreads();

    bf16x8 af[4], bfg[4];
#pragma unroll
    for (int mi = 0; mi < 4; mi++) {
      int m = wm * 64 + mi * 16 + l15;
      int o0 = (quad * 2) ^ (m & 7), o1 = (quad * 2 + 1) ^ (m & 7);
      float4 lo = *(const float4*)&Af[m * 32 + o0 * 4];
      float4 hi = *(const float4*)&Af[m * 32 + o1 * 4];
      bf16x8 r;
      r[0] = (short)f2bs(lo.x); r[1] = (short)f2bs(lo.y);
      r[2] = (short)f2bs(lo.z); r[3] = (short)f2bs(lo.w);
      r[4] = (short)f2bs(hi.x); r[5] = (short)f2bs(hi.y);
      r[6] = (short)f2bs(hi.z); r[7] = (short)f2bs(hi.w);
      af[mi] = r;
    }
#pragma unroll
    for (int ni = 0; ni < 4; ni++) {
      int n = wn * 64 + ni * 16 + l15;
      int q2 = quad ^ ((n >> 1) & 3);
      bfg[ni] = *(const bf16x8*)&Bs[n * 32 + q2 * 8];
    }
#pragma unroll
    for (int mi = 0; mi < 4; mi++)
#pragma unroll
      for (int ni = 0; ni < 4; ni++)
        acc[mi][ni] = __builtin_amdgcn_mfma_f32_16x16x32_bf16(af[mi], bfg[ni], acc[mi][ni], 0, 0, 0);
  }
#pragma unroll
  for (int mi = 0; mi < 4; mi++)
#pragma unroll
    for (int ni = 0; ni < 4; ni++)
#pragma unroll
      for (int r = 0; r < 4; r++) {
        int row = bm + wm * 64 + mi * 16 + quad * 4 + r;
        int col = bn + wn * 64 + ni * 16 + l15;
        float v = acc[mi][ni][r];
        if (Add != nullptr && col < addW) v += Add[(size_t)row * ldadd + col];
        C[(size_t)row * ldc + col] = v;
      }
}

// ================= MFMA GEMM, bf16 A, double-buffered with COUNTED vmcnt (T4):
// raw s_barrier + s_waitcnt vmcnt(4) keeps the prefetch in flight across barriers;
// only the current tile's 4 loads are forced complete each iteration.
// 1D grid with XCD-chunked swizzle (nwg % 8 == 0).
__global__ __launch_bounds__(256) void gemm_mfma_b16(
    const u16* __restrict__ A, const u16* __restrict__ Bt,
    float* __restrict__ C, int ldc, int Kc, int nbx, int nwg,
    const float* __restrict__ Add, int ldadd, int addW)
{
  __shared__ u16 As[2][128 * 32];  // [buf][m][q ^ ((m>>1)&3)]
  __shared__ u16 Bs[2][128 * 32];  // [buf][n][q ^ ((n>>1)&3)]
  const int tid = threadIdx.x;
  const int wave = tid >> 6, lane = tid & 63;
  const int wm = wave >> 1, wn = wave & 1;
  const int l15 = lane & 15, quad = lane >> 4;
  const int lin = blockIdx.x;
  const int swz = (lin & 7) * (nwg >> 3) + (lin >> 3);  // XCD-chunked, bijective
  const int bm = (swz / nbx) * 128, bn = (swz % nbx) * 128;

  const int c0 = tid,      r0 = c0 >> 2, q0 = (c0 & 3) ^ ((r0 >> 1) & 3);
  const int c1 = 256 + tid, r1 = c1 >> 2, q1 = (c1 & 3) ^ ((r1 >> 1) & 3);
  const u16* gA0 = A + (size_t)(bm + r0) * Kc + q0 * 8;
  const u16* gA1 = A + (size_t)(bm + r1) * Kc + q1 * 8;
  const u16* gB0 = Bt + (size_t)(bn + r0) * Kc + q0 * 8;
  const u16* gB1 = Bt + (size_t)(bn + r1) * Kc + q1 * 8;

  f32x4 acc[4][4];
#pragma unroll
  for (int i = 0; i < 4; i++)
#pragma unroll
    for (int j = 0; j < 4; j++) acc[i][j] = (f32x4)(0.f);

#define STAGE_AB(s, k0) do {                      \
    GLDS16(gA0 + (k0), &As[s][c0 * 8]);           \
    GLDS16(gA1 + (k0), &As[s][c1 * 8]);           \
    GLDS16(gB0 + (k0), &Bs[s][c0 * 8]);           \
    GLDS16(gB1 + (k0), &Bs[s][c1 * 8]);           \
  } while (0)
#define RAWBAR() do { __builtin_amdgcn_s_barrier(); \
    __builtin_amdgcn_sched_barrier(0); } while (0)

  STAGE_AB(0, 0);
  asm volatile("s_waitcnt vmcnt(0)" ::: "memory");
  RAWBAR();
  int cur = 0;
  const int nt = Kc / 32;
  for (int t = 0; t < nt; t++) {
    if (t + 1 < nt) {
      STAGE_AB(cur ^ 1, (t + 1) * 32);              // 4 loads, stay in flight
      asm volatile("s_waitcnt vmcnt(4)" ::: "memory");  // tile-t loads landed
    } else {
      asm volatile("s_waitcnt vmcnt(0)" ::: "memory");
    }
    RAWBAR();                                        // buf[cur] staged for all waves
    bf16x8 af[4], bfg[4];
#pragma unroll
    for (int mi = 0; mi < 4; mi++) {
      int m = wm * 64 + mi * 16 + l15;
      af[mi] = *(const bf16x8*)&As[cur][m * 32 + (quad ^ ((m >> 1) & 3)) * 8];
    }
#pragma unroll
    for (int ni = 0; ni < 4; ni++) {
      int n = wn * 64 + ni * 16 + l15;
      bfg[ni] = *(const bf16x8*)&Bs[cur][n * 32 + (quad ^ ((n >> 1) & 3)) * 8];
    }
#pragma unroll
    for (int mi = 0; mi < 4; mi++)
#pragma unroll
      for (int ni = 0; ni < 4; ni++)
        acc[mi][ni] = __builtin_amdgcn_mfma_f32_16x16x32_bf16(af[mi], bfg[ni], acc[mi][ni], 0, 0, 0);
    RAWBAR();                                        // all waves done reading buf[cur]
    cur ^= 1;
  }
#undef STAGE_AB
#undef RAWBAR

#pragma unroll
  for (int mi = 0; mi < 4; mi++)
#pragma unroll
    for (int ni = 0; ni < 4; ni++)
#pragma unroll
      for (int r = 0; r < 4; r++) {
        int row = bm + wm * 64 + mi * 16 + quad * 4 + r;
        int col = bn + wn * 64 + ni * 16 + l15;
        float v = acc[mi][ni][r];
        if (Add != nullptr && col < addW) v += Add[(size_t)row * ldadd + col];
        C[(size_t)row * ldc + col] = v;
      }
}

// ================= transpose + bf16 cast
__global__ __launch_bounds__(256) void transpose_bf16(
    const float* __restrict__ W, u16* __restrict__ Bt, int K, int N)
{
  __shared__ float t[32][33];
  const int n0 = blockIdx.x * 32, k0 = blockIdx.y * 32;
  const int tx = threadIdx.x & 31, ty = threadIdx.x >> 5;
  for (int r = ty; r < 32; r += 8) t[r][tx] = W[(size_t)(k0 + r) * N + n0 + tx];
  __syncthreads();
  for (int r = ty; r < 32; r += 8) Bt[(size_t)(n0 + r) * K + k0 + tx] = f2bs(t[tx][r]);
}

// ================= hs GEMM: psum[z] = upd[:, z*288:(z+1)*288] @ W_prod_l[z-chunk, :128]
__global__ __launch_bounds__(256) void hs_gemm_kernel(
    const float* __restrict__ A,      // upd, lda = DOUT_DIM
    const float* __restrict__ B,      // W_prod_l, ldb = DOUT_DIM (cols 0..127)
    float* __restrict__ psum)         // [4][N_NODES][F_DIM]
{
  __shared__ float As[16][129];
  __shared__ float Bs[16][128];
  const int tid = threadIdx.x;
  const int tx = tid & 15, ty = tid >> 4;
  const int bm = blockIdx.x * 128;
  const int z = blockIdx.y;
  const int kb = z * (DOUT_DIM / 4);
  const int ke = kb + DOUT_DIM / 4;
  const int ac = tid & 15, ar0 = tid >> 4;
  const int bc = tid & 127, br0 = tid >> 7;
  float acc[8][8];
#pragma unroll
  for (int i = 0; i < 8; i++)
#pragma unroll
    for (int j = 0; j < 8; j++) acc[i][j] = 0.f;

  float ra[8], rb[8];
#define LOADREG(k0) do {                                                       \
    _Pragma("unroll")                                                          \
    for (int rr = 0; rr < 8; rr++)                                             \
      ra[rr] = A[(size_t)(bm + ar0 + rr * 16) * DOUT_DIM + (k0) + ac];         \
    _Pragma("unroll")                                                          \
    for (int rr = 0; rr < 8; rr++)                                             \
      rb[rr] = B[(size_t)((k0) + br0 + rr * 2) * DOUT_DIM + bc];               \
  } while (0)

  LOADREG(kb);
  for (int k0 = kb; k0 < ke; k0 += 16) {
#pragma unroll
    for (int rr = 0; rr < 8; rr++) As[ac][ar0 + rr * 16] = ra[rr];
#pragma unroll
    for (int rr = 0; rr < 8; rr++) Bs[br0 + rr * 2][bc] = rb[rr];
    __syncthreads();
    if (k0 + 16 < ke) LOADREG(k0 + 16);
#pragma unroll
    for (int kk = 0; kk < 16; kk++) {
      float a[8], b[8];
#pragma unroll
      for (int i = 0; i < 8; i++) a[i] = As[kk][ty * 8 + i];
#pragma unroll
      for (int j = 0; j < 8; j++) b[j] = Bs[kk][tx * 8 + j];
#pragma unroll
      for (int i = 0; i < 8; i++)
#pragma unroll
        for (int j = 0; j < 8; j++) acc[i][j] = fmaf(a[i], b[j], acc[i][j]);
    }
    __syncthreads();
  }
#undef LOADREG
#pragma unroll
  for (int i = 0; i < 8; i++) {
    size_t row = (size_t)z * N_NODES + bm + ty * 8 + i;
#pragma unroll
    for (int j = 0; j < 8; j++)
      psum[row * F_DIM + tx * 8 + j] = acc[i][j];
  }
}

// hs = psum[0]+psum[1]+psum[2]+psum[3] + h   (float4)
__global__ __launch_bounds__(256) void hs_reduce_kernel(
    const float* __restrict__ psum, const float* __restrict__ h, float* __restrict__ hs)
{
  size_t i4 = (size_t)blockIdx.x * 256 + threadIdx.x;
  const size_t stride = (size_t)N_NODES * F_DIM / 4;
  const float4* p = (const float4*)psum;
  float4 a = p[i4], b = p[i4 + stride], c = p[i4 + 2 * stride], d = p[i4 + 3 * stride];
  float4 hh = ((const float4*)h)[i4];
  float4 o;
  o.x = a.x + b.x + c.x + d.x + hh.x;
  o.y = a.y + b.y + c.y + d.y + hh.y;
  o.z = a.z + b.z + c.z + d.z + hh.z;
  o.w = a.w + b.w + c.w + d.w + hh.w;
  ((float4*)hs)[i4] = o;
}

// ================= fp32 GEMM 64x64, optional split-K
__global__ __launch_bounds__(256) void gemm64_f32(
    const float* __restrict__ A, int lda,
    const float* __restrict__ B, int ldb,
    float* __restrict__ C, int ldc,
    int M, int Nc, int Kc, int kPerSplit,
    const float* __restrict__ Add, int ldadd, int addW)
{
  __shared__ float As[16][65];
  __shared__ float Bs[16][64];
  const int tid = threadIdx.x;
  const int tx = tid & 15, ty = tid >> 4;
  const int bm = blockIdx.y * 64, bn = blockIdx.x * 64;
  const int kb = blockIdx.z * kPerSplit;
  const int ke = min(kb + kPerSplit, Kc);
  float acc[4][4];
#pragma unroll
  for (int i = 0; i < 4; i++)
#pragma unroll
    for (int j = 0; j < 4; j++) acc[i][j] = 0.f;
  for (int k0 = kb; k0 < ke; k0 += 16) {
    const int ac = tid & 15, ar = tid >> 4;
#pragma unroll
    for (int rr = 0; rr < 4; rr++) {
      int row = ar + rr * 16;
      As[ac][row] = A[(size_t)(bm + row) * lda + k0 + ac];
    }
    const int bc = tid & 63, br = tid >> 6;
#pragma unroll
    for (int rr = 0; rr < 4; rr++) {
      int kr = br + rr * 4;
      Bs[kr][bc] = B[(size_t)(k0 + kr) * ldb + bn + bc];
    }
    __syncthreads();
#pragma unroll
    for (int kk = 0; kk < 16; kk++) {
      float a[4], b[4];
#pragma unroll
      for (int i = 0; i < 4; i++) a[i] = As[kk][ty * 4 + i];
#pragma unroll
      for (int j = 0; j < 4; j++) b[j] = Bs[kk][tx * 4 + j];
#pragma unroll
      for (int i = 0; i < 4; i++)
#pragma unroll
        for (int j = 0; j < 4; j++) acc[i][j] = fmaf(a[i], b[j], acc[i][j]);
    }
    __syncthreads();
  }
#pragma unroll
  for (int i = 0; i < 4; i++) {
    int row = bm + ty * 4 + i;
#pragma unroll
    for (int j = 0; j < 4; j++) {
      int col = bn + tx * 4 + j;
      if (gridDim.z > 1) {
        atomicAdd(&C[(size_t)row * ldc + col], acc[i][j]);
      } else {
        float v = acc[i][j];
        if (Add != nullptr && col < addW) v += Add[(size_t)row * ldadd + col];
        C[(size_t)row * ldc + col] = v;
      }
    }
  }
}

// ================= CSR build: count / scan / fill
__global__ __launch_bounds__(256) void count_kernel(
    const int* __restrict__ ei, int* __restrict__ counts)
{
  int e = blockIdx.x * 256 + threadIdx.x;
  atomicAdd(&counts[ei[E_EDGES + e]], 1);
}

__global__ __launch_bounds__(1024) void scan_kernel(
    const int* __restrict__ counts, int* __restrict__ offsets, int* __restrict__ cursor)
{
  __shared__ int part[1024];
  const int t = threadIdx.x;
  const int base = t * 16;
  int loc[16];
  int s = 0;
#pragma unroll
  for (int k = 0; k < 16; k++) { loc[k] = counts[base + k]; s += loc[k]; }
  part[t] = s;
  __syncthreads();
  for (int d = 1; d < 1024; d <<= 1) {
    int v = (t >= d) ? part[t - d] : 0;
    __syncthreads();
    part[t] += v;
    __syncthreads();
  }
  int run = part[t] - s;  // exclusive prefix
#pragma unroll
  for (int k = 0; k < 16; k++) {
    offsets[base + k] = run;
    cursor[base + k] = run;
    run += loc[k];
  }
}

__global__ __launch_bounds__(256) void fill_kernel(
    const int* __restrict__ ei, int* __restrict__ cursor, int* __restrict__ elist)
{
  int e = blockIdx.x * 256 + threadIdx.x;
  int d = ei[E_EDGES + e];
  int p = atomicAdd(&cursor[d], 1);
  elist[p] = e;
}

// ================= atomic-free edge accumulation: block per dst node.
__global__ __launch_bounds__(128) void gather_accum_kernel(
    const float* __restrict__ hW, const float* __restrict__ edge_sh,
    const float* __restrict__ edge_feats, const float* __restrict__ W_rad_l,
    const int* __restrict__ ei, const int* __restrict__ offsets,
    const int* __restrict__ counts, const int* __restrict__ elist,
    float* __restrict__ upd, u16* __restrict__ updb)
{
  const int d = blockIdx.x, f = threadIdx.x;
  const float w0 = W_rad_l[0 * F_DIM + f], w1 = W_rad_l[1 * F_DIM + f];
  const float w2 = W_rad_l[2 * F_DIM + f], w3 = W_rad_l[3 * F_DIM + f];
  const float w4 = W_rad_l[4 * F_DIM + f], w5 = W_rad_l[5 * F_DIM + f];
  const float w6 = W_rad_l[6 * F_DIM + f], w7 = W_rad_l[7 * F_DIM + f];
  const int b = offsets[d], n = counts[d];
  float acc[L_DIM];
#pragma unroll
  for (int l = 0; l < L_DIM; l++) acc[l] = 0.f;
  for (int k = 0; k < n; k++) {
    const int e = elist[b + k];
    const int s = ei[e];
    const float4 ef0 = *(const float4*)&edge_feats[(size_t)e * R_DIM];
    const float4 ef1 = *(const float4*)&edge_feats[(size_t)e * R_DIM + 4];
    float rw = ef0.x * w0;
    rw = fmaf(ef0.y, w1, rw); rw = fmaf(ef0.z, w2, rw); rw = fmaf(ef0.w, w3, rw);
    rw = fmaf(ef1.x, w4, rw); rw = fmaf(ef1.y, w5, rw);
    rw = fmaf(ef1.z, w6, rw); rw = fmaf(ef1.w, w7, rw);
    const float tf = hW[(size_t)s * F_DIM + f] * rw;
#pragma unroll
    for (int l = 0; l < L_DIM; l++)
      acc[l] = fmaf(edge_sh[(size_t)e * L_DIM + l], tf, acc[l]);
  }
#pragma unroll
  for (int l = 0; l < L_DIM; l++)
    upd[(size_t)d * DOUT_DIM + l * F_DIM + f] = acc[l];
  if (updb != nullptr) {
#pragma unroll
    for (int l = 0; l < L_DIM; l++)
      updb[(size_t)d * DOUT_DIM + l * F_DIM + f] = f2bs(acc[l]);
  }
}

// ================= gating MLP on hs (fp32, ld=F_DIM) + fused 16-bit histogram
__global__ __launch_bounds__(256) void gate_kernel(
    const float* __restrict__ hs, const float* __restrict__ W1,
    const float* __restrict__ b1, const float* __restrict__ W2,
    const float* __restrict__ b2, float* __restrict__ m_ws, float* __restrict__ m_out,
    int* __restrict__ hist1)
{
  __shared__ float sW1[F_DIM * HID_DIM];
  __shared__ float srow[4][F_DIM];
  const int tid = threadIdx.x;
  for (int t = tid; t < F_DIM * HID_DIM; t += 256) sW1[t] = W1[t];
  const int wave = tid >> 6, lane = tid & 63;
  const int n = blockIdx.x * 4 + wave;
  srow[wave][lane] = hs[(size_t)n * F_DIM + lane];
  srow[wave][lane + 64] = hs[(size_t)n * F_DIM + lane + 64];
  __syncthreads();
  float hid = b1[lane];
#pragma unroll 8
  for (int c = 0; c < F_DIM; c++) hid = fmaf(srow[wave][c], sW1[c * HID_DIM + lane], hid);
  hid = fmaxf(hid, 0.f);
  float v = hid * W2[lane];
#pragma unroll
  for (int off = 32; off > 0; off >>= 1) v += __shfl_down(v, off);
  if (lane == 0) {
    float mm = 1.f / (1.f + expf(-(v + b2[0])));
    m_ws[n] = mm;
    m_out[n] = mm;
    unsigned mb = __float_as_uint(mm);
    atomicAdd(&hist1[mb >> 16], 1);
  }
}

// ================= radix top-K selection
__global__ __launch_bounds__(1024) void radix_sel_kernel(
    const int* __restrict__ hist, const int* __restrict__ kin, int kinIdx,
    int* __restrict__ outp, int outIdx)
{
  __shared__ int part[1024];
  const int t = threadIdx.x;
  const int Kv = kin ? kin[kinIdx] : K_SEL;
  const int base = t * 64;
  int s = 0;
  for (int k = 0; k < 64; k++) s += hist[base + k];
  part[t] = s;
  __syncthreads();
  for (int d = 1; d < 1024; d <<= 1) {
    int v = (t + d < 1024) ? part[t + d] : 0;
    __syncthreads();
    part[t] += v;
    __syncthreads();
  }
  int inc = part[t];
  if (inc >= Kv && inc - s < Kv) {
    int r = inc - s;
    for (int b = base + 63; b >= base; b--) {
      int hv = hist[b];
      if (r + hv >= Kv) { outp[outIdx] = b; outp[outIdx + 1] = Kv - r; break; }
      r += hv;
    }
  }
}

__global__ __launch_bounds__(256) void hist2_kernel(
    const float* __restrict__ m_ws, const int* __restrict__ selb, int* __restrict__ hist2)
{
  int i = blockIdx.x * 256 + threadIdx.x;
  unsigned mb = __float_as_uint(m_ws[i]);
  if ((int)(mb >> 16) == selb[0]) atomicAdd(&hist2[mb & 0xFFFFu], 1);
}

__global__ __launch_bounds__(256) void flag_kernel(
    const float* __restrict__ m_ws, int* __restrict__ selb,
    unsigned char* __restrict__ flags, int* __restrict__ cand)
{
  int i = blockIdx.x * 256 + threadIdx.x;
  unsigned mb = __float_as_uint(m_ws[i]);
  unsigned vb = ((unsigned)selb[0] << 16) | (unsigned)selb[2];
  unsigned char fl = 0;
  if (mb > vb) fl = 1;
  else if (mb == vb) { int p = atomicAdd(&selb[4], 1); cand[p] = i; }
  flags[i] = fl;
}

__global__ __launch_bounds__(1024) void cand_kernel(
    const int* __restrict__ selb, const int* __restrict__ cand, unsigned char* __restrict__ flags)
{
  const int nc = selb[4], need = selb[3];
  for (int c = threadIdx.x; c < nc; c += 1024) {
    const int idx = cand[c];
    int r = 0;
    for (int o = 0; o < nc; o++) r += (cand[o] < idx) ? 1 : 0;
    if (r < need) flags[idx] = 1;
  }
}

__global__ __launch_bounds__(1024) void compact_kernel(
    const unsigned char* __restrict__ flags, int* __restrict__ midx,
    int* __restrict__ rank, float* __restrict__ mi_out)
{
  __shared__ int part[1024];
  const int t = threadIdx.x;
  const int base = t * 16;
  int loc[16];
  int s = 0;
#pragma unroll
  for (int k = 0; k < 16; k++) { loc[k] = flags[base + k]; s += loc[k]; }
  part[t] = s;
  __syncthreads();
  for (int d = 1; d < 1024; d <<= 1) {
    int v = (t >= d) ? part[t - d] : 0;
    __syncthreads();
    part[t] += v;
    __syncthreads();
  }
  int run = part[t] - s;
#pragma unroll
  for (int k = 0; k < 16; k++) {
    int i = base + k;
    if (loc[k]) {
      midx[run] = i;
      mi_out[run] = (float)i;
      rank[i] = run;
      run++;
    } else {
      rank[i] = K_SEL;
    }
  }
}

// ================= induced adjacency (+ transposed copy for coalesced listbuild)
__global__ __launch_bounds__(256) void adj_kernel(
    const int* __restrict__ ei, const int* __restrict__ rank,
    unsigned char* __restrict__ adjm, unsigned char* __restrict__ adjT)
{
  int e = blockIdx.x * 256 + threadIdx.x;
  int rs = rank[ei[e]];
  int rd = rank[ei[E_EDGES + e]];
  if (rs < K_SEL && rd < K_SEL) {
    adjm[(size_t)rs * K_SEL + rd] = 1;
    adjT[(size_t)rd * K_SEL + rs] = 1;
  }
}

// ================= gather master rows + positions (float4)
__global__ __launch_bounds__(128) void gather_kernel(
    const float* __restrict__ hl, const float* __restrict__ pos,
    const int* __restrict__ midx, float* __restrict__ h_m, float* __restrict__ pos_m)
{
  const int rI = blockIdx.x, t = threadIdx.x;
  const int mi = midx[rI];
  const float4* src = (const float4*)(hl + (size_t)mi * DOUT_DIM);
  float4* dst = (float4*)(h_m + (size_t)rI * DOUT_DIM);
  for (int c = t; c < DOUT_DIM / 4; c += 128) dst[c] = src[c];
  if (t < 3) pos_m[rI * 3 + t] = pos[mi * 3 + t];
}

// ================= q/k projections from hs at master rows
__global__ __launch_bounds__(128) void qk_kernel(
    const float* __restrict__ hs, const int* __restrict__ midx,
    const float* __restrict__ Wq, const float* __restrict__ Wk,
    float* __restrict__ q, float* __restrict__ kk)
{
  __shared__ float row[F_DIM];
  const int i = blockIdx.x, t = threadIdx.x;
  const int mi = midx[i];
  row[t] = hs[(size_t)mi * F_DIM + t];
  __syncthreads();
  const int d = t & 63;
  const float* W = (t < 64) ? Wq : Wk;
  float acc = 0.f;
#pragma unroll 8
  for (int c = 0; c < F_DIM; c++) acc = fmaf(row[c], W[c * DA_DIM + d], acc);
  float* dst = (t < 64) ? q : kk;
  dst[(size_t)i * DA_DIM + d] = acc;
}

// ================= attention (padded LDS; also emits transposed mask)
__global__ __launch_bounds__(256) void attn_kernel(
    const float* __restrict__ q, const float* __restrict__ kk,
    unsigned char* __restrict__ maskA, unsigned char* __restrict__ maskAT,
    float* __restrict__ Av)
{
  __shared__ float qs[16][DA_DIM + 1], ks[16][DA_DIM + 1];
  const int tx = threadIdx.x, ty = threadIdx.y;
  const int tid = ty * 16 + tx;
  const int i0 = blockIdx.y * 16, j0 = blockIdx.x * 16;
  for (int t = tid; t < 16 * DA_DIM; t += 256) {
    int rr = t >> 6, cc = t & 63;
    qs[rr][cc] = q[(size_t)(i0 + rr) * DA_DIM + cc];
    ks[rr][cc] = kk[(size_t)(j0 + rr) * DA_DIM + cc];
  }
  __syncthreads();
  float acc = 0.f;
#pragma unroll
  for (int d2 = 0; d2 < DA_DIM; d2++) acc = fmaf(qs[ty][d2], ks[tx][d2], acc);
  float sgl = 1.f / (1.f + expf(-acc * 0.125f));
  size_t o = (size_t)(i0 + ty) * K_SEL + (j0 + tx);
  bool big = sgl > 0.5f;
  unsigned char bb = big ? 1 : 0;
  maskA[o] = bb;
  maskAT[(size_t)(j0 + tx) * K_SEL + (i0 + ty)] = bb;
  Av[o] = big ? sgl : 0.f;
}

// ================= per-i active-j list (coalesced row reads + wave-ballot)
__global__ __launch_bounds__(256) void listbuild_kernel(
    const unsigned char* __restrict__ adjT, const unsigned char* __restrict__ maskAT,
    const unsigned char* __restrict__ maskA, u16* __restrict__ list, int* __restrict__ nj)
{
  __shared__ int cnt;
  const int i = blockIdx.x, tid = threadIdx.x;
  const int lane = tid & 63;
  if (tid == 0) cnt = 0;
  __syncthreads();
  const int j0 = tid * 4;
  uchar4 a  = *(const uchar4*)&adjT  [(size_t)i * K_SEL + j0];
  uchar4 mt = *(const uchar4*)&maskAT[(size_t)i * K_SEL + j0];
  uchar4 ma = *(const uchar4*)&maskA [(size_t)i * K_SEL + j0];
  unsigned char av[4];
  av[0] = a.x | mt.x | ma.x; av[1] = a.y | mt.y | ma.y;
  av[2] = a.z | mt.z | ma.z; av[3] = a.w | mt.w | ma.w;
#pragma unroll
  for (int r = 0; r < 4; r++) {
    int j = j0 + r;
    bool e = (j != i) && av[r];
    unsigned long long m = __ballot(e);
    int nset = __popcll(m);
    int base = 0;
    if (lane == 0 && nset) base = atomicAdd(&cnt, nset);
    base = __shfl(base, 0);
    if (e) {
      int p = base + __popcll(m & ((1ull << lane) - 1ull));
      list[(size_t)i * K_SEL + p] = (u16)j;
    }
  }
  __syncthreads();
  if (tid == 0) nj[i] = cnt;
}

// ================= hier v3 (measured best: 87 us): sW in registers, j packed
// into gsm, 5 LDS reads/iter; 512 threads = 4 j-subgroups x 128 f.
__global__ __launch_bounds__(512) void hier2_kernel(
    const float* __restrict__ hWn, const float* __restrict__ pos_m,
    const float* __restrict__ W_rad_h, const u16* __restrict__ list,
    const int* __restrict__ nj, float* __restrict__ upd_m, u16* __restrict__ updb_m)
{
  __shared__ float gsm[128][20];   // [pair][rd0..7, sh0..8, jbits, pad, pad]
  __shared__ float red[3][L_DIM][F_DIM];
  const int tid = threadIdx.x;
  const int i = blockIdx.x;
  const int f = tid & 127, jsub = tid >> 7;
  const float sw0 = W_rad_h[0 * F_DIM + f], sw1 = W_rad_h[1 * F_DIM + f];
  const float sw2 = W_rad_h[2 * F_DIM + f], sw3 = W_rad_h[3 * F_DIM + f];
  const float sw4 = W_rad_h[4 * F_DIM + f], sw5 = W_rad_h[5 * F_DIM + f];
  const float sw6 = W_rad_h[6 * F_DIM + f], sw7 = W_rad_h[7 * F_DIM + f];
  const float pix = pos_m[i * 3 + 0], piy = pos_m[i * 3 + 1], piz = pos_m[i * 3 + 2];
  float acc[L_DIM];
#pragma unroll
  for (int l = 0; l < L_DIM; l++) acc[l] = 0.f;
  const int n = nj[i];
  for (int c0 = 0; c0 < n; c0 += 128) {
    const int cnt = min(128, n - c0);
    __syncthreads();
    if (tid < cnt) {
      const int j = list[(size_t)i * K_SEL + c0 + tid];
      float vx = pos_m[j * 3 + 0] - pix;
      float vy = pos_m[j * 3 + 1] - piy;
      float vz = pos_m[j * 3 + 2] - piz;
      float r = sqrtf(vx * vx + vy * vy + vz * vz);
      float rm = fmaxf(r, 1e-9f);
      float inv = 1.f / rm;
      float ux = vx * inv, uy = vy * inv, uz = vz * inv;
      float theta = 0.62831853071795864769f * r;  // pi/R_CUT
      float s1 = sinf(theta), c1 = cosf(theta);
      float coef = 0.632455532033675866f * inv;   // sqrt(2/R_CUT)/max(r,eps)
      float snm2 = 0.f, snm1 = s1;
      gsm[tid][0] = s1 * coef;
#pragma unroll
      for (int nn = 2; nn <= R_DIM; nn++) {
        float sn = 2.f * c1 * snm1 - snm2;
        gsm[tid][nn - 1] = sn * coef;
        snm2 = snm1; snm1 = sn;
      }
      gsm[tid][8] = 1.f; gsm[tid][9] = ux; gsm[tid][10] = uy; gsm[tid][11] = uz;
      gsm[tid][12] = ux * uy; gsm[tid][13] = uy * uz;
      gsm[tid][14] = 3.f * uz * uz - 1.f;
      gsm[tid][15] = ux * uz; gsm[tid][16] = ux * ux - uy * uy;
      gsm[tid][17] = __int_as_float(j);
      gsm[tid][18] = 0.f; gsm[tid][19] = 0.f;
    }
    __syncthreads();
    for (int t = jsub; t < cnt; t += 4) {
      float2 s2 = *(const float2*)&gsm[t][16];   // sh8, jbits
      const int j = __float_as_int(s2.y);
      const float hw = hWn[(size_t)j * F_DIM + f];
      float4 r0 = *(const float4*)&gsm[t][0];    // rd0..3
      float4 r1 = *(const float4*)&gsm[t][4];    // rd4..7
      float4 s0 = *(const float4*)&gsm[t][8];    // sh0..3
      float4 s1g = *(const float4*)&gsm[t][12];  // sh4..7
      float rw = r0.x * sw0;
      rw = fmaf(r0.y, sw1, rw); rw = fmaf(r0.z, sw2, rw); rw = fmaf(r0.w, sw3, rw);
      rw = fmaf(r1.x, sw4, rw); rw = fmaf(r1.y, sw5, rw);
      rw = fmaf(r1.z, sw6, rw); rw = fmaf(r1.w, sw7, rw);
      const float tm = hw * rw;
      acc[0] = fmaf(s0.x, tm, acc[0]); acc[1] = fmaf(s0.y, tm, acc[1]);
      acc[2] = fmaf(s0.z, tm, acc[2]); acc[3] = fmaf(s0.w, tm, acc[3]);
      acc[4] = fmaf(s1g.x, tm, acc[4]); acc[5] = fmaf(s1g.y, tm, acc[5]);
      acc[6] = fmaf(s1g.z, tm, acc[6]); acc[7] = fmaf(s1g.w, tm, acc[7]);
      acc[8] = fmaf(s2.x, tm, acc[8]);
    }
  }
  __syncthreads();
  if (jsub > 0) {
#pragma unroll
    for (int l = 0; l < L_DIM; l++) red[jsub - 1][l][f] = acc[l];
  }
  __syncthreads();
  if (jsub == 0) {
#pragma unroll
    for (int l = 0; l < L_DIM; l++) {
      float v = acc[l] + red[0][l][f] + red[1][l][f] + red[2][l][f];
      upd_m[(size_t)i * DOUT_DIM + l * F_DIM + f] = v;
      updb_m[(size_t)i * DOUT_DIM + l * F_DIM + f] = f2bs(v);
    }
  }
}

// ================= final blend (float4; 1152 % 4 == 0, vector never spans rows)
__global__ __launch_bounds__(256) void combine_kernel(
    float* __restrict__ out0, const float* __restrict__ h_hier,
    const float* __restrict__ m_ws, const int* __restrict__ rank)
{
  size_t i4 = (size_t)blockIdx.x * 256 + threadIdx.x;
  int n = (int)(i4 / (DOUT_DIM / 4));
  int g4 = (int)(i4 % (DOUT_DIM / 4));
  float mv = m_ws[n];
  int r = rank[n];
  float4 hl = ((const float4*)out0)[i4];
  float4 he = make_float4(0.f, 0.f, 0.f, 0.f);
  if (r < K_SEL) he = ((const float4*)h_hier)[(size_t)r * (DOUT_DIM / 4) + g4];
  float4 o;
  o.x = (1.f - mv) * hl.x + mv * he.x;
  o.y = (1.f - mv) * hl.y + mv * he.y;
  o.z = (1.f - mv) * hl.z + mv * he.z;
  o.w = (1.f - mv) * hl.w + mv * he.w;
  ((float4*)out0)[i4] = o;
}

extern "C" void kernel_launch(void* const* d_in, const int* in_sizes, int n_in,
                              void* d_out, int out_size, void* d_ws, size_t ws_size,
                              hipStream_t stream)
{
  const float* h         = (const float*)d_in[0];
  const float* pos       = (const float*)d_in[1];
  const float* edge_sh   = (const float*)d_in[2];
  const float* edge_feats= (const float*)d_in[3];
  const float* W_node_l  = (const float*)d_in[4];
  const float* W_rad_l   = (const float*)d_in[5];
  const float* W_prod_l  = (const float*)d_in[6];
  const float* ms_W1     = (const float*)d_in[7];
  const float* ms_b1     = (const float*)d_in[8];
  const float* ms_W2     = (const float*)d_in[9];
  const float* ms_b2     = (const float*)d_in[10];
  const float* vg_Wq     = (const float*)d_in[11];
  const float* vg_Wk     = (const float*)d_in[12];
  const float* W_node_h  = (const float*)d_in[13];
  const float* W_rad_h   = (const float*)d_in[14];
  const float* W_prod_h  = (const float*)d_in[15];
  const int*   eidx      = (const int*)d_in[16];

  float* out    = (float*)d_out;
  float* out_hf = out;
  float* out_Av = out + (size_t)N_NODES * DOUT_DIM;
  float* out_m  = out_Av + (size_t)K_SEL * K_SEL;
  float* out_mi = out_m + N_NODES;

  char* ws = (char*)d_ws;
  // Phase 1: upd [0, 75.5MB); hW/hs [75.5, 83.9MB); optional updb [83.9, 121.6MB).
  float* upd = (float*)ws;
  float* hW  = (float*)(ws + (size_t)N_NODES * DOUT_DIM * 4);
  float* hs  = hW;  // hW dead after gather_accum; hs written after
  const size_t updbOff = (size_t)N_NODES * DOUT_DIM * 4 + (size_t)N_NODES * F_DIM * 4;
  const size_t updbNeed = updbOff + (size_t)N_NODES * DOUT_DIM * 2;
  const bool useB16 = (ws_size >= updbNeed);
  u16* updb = (u16*)(ws + updbOff);
  // hs split-K partials borrow out_hf (75.5MB, dead until gemm_mfma_b16 writes it).
  float* psum = out_hf;   // 4 * 16384 * 128 * 4B = 33.6 MB < 75.5 MB
  // Btl + CSR borrow the A_virtual out region (4MB, dead until attn writes it).
  u16* Btl = (u16*)out_Av;                                       // 2.65 MB
  char* csr = (char*)out_Av + (((size_t)DOUT_DIM * DOUT_DIM * 2 + 255) & ~(size_t)255);
  int* counts  = (int*)csr;                                      // 64 KB
  int* offsets = counts + N_NODES;                               // 64 KB
  int* cursor  = offsets + N_NODES;                              // 64 KB
  int* elist   = cursor + N_NODES;                               // 512 KB  (total 3.4MB < 4MB)
  // Phase 2 small pool aliases dead upd.
  size_t off = 0;
  auto alloc = [&](size_t bytes) -> void* {
    void* p = ws + off;
    off += (bytes + 255) & ~(size_t)255;
    return p;
  };
  float* m_ws  = (float*)alloc((size_t)N_NODES * 4);
  int*   rank  = (int*)alloc((size_t)N_NODES * 4);
  int*   midx  = (int*)alloc((size_t)K_SEL * 4);
  int*   hist1 = (int*)alloc((size_t)65536 * 4);
  int*   hist2 = (int*)alloc((size_t)65536 * 4);
  int*   selb  = (int*)alloc((size_t)64 * 4);   // [0]=b1 [1]=need1 [2]=b2 [3]=need2 [4]=ncand
  int*   cand  = (int*)alloc((size_t)N_NODES * 4);
  unsigned char* flags = (unsigned char*)alloc((size_t)N_NODES);
  unsigned char* adjm  = (unsigned char*)alloc((size_t)K_SEL * K_SEL);
  unsigned char* adjT  = (unsigned char*)alloc((size_t)K_SEL * K_SEL);  // contiguous after adjm
  unsigned char* maskA = (unsigned char*)alloc((size_t)K_SEL * K_SEL);
  unsigned char* maskAT= (unsigned char*)alloc((size_t)K_SEL * K_SEL);
  float* qbuf  = (float*)alloc((size_t)K_SEL * DA_DIM * 4);
  float* kbuf  = (float*)alloc((size_t)K_SEL * DA_DIM * 4);
  float* h_m   = (float*)alloc((size_t)K_SEL * DOUT_DIM * 4);
  float* pos_m = (float*)alloc((size_t)K_SEL * 3 * 4);
  float* hWn   = (float*)alloc((size_t)K_SEL * F_DIM * 4);
  float* upd_m = (float*)alloc((size_t)K_SEL * DOUT_DIM * 4);
  float* h_hier= (float*)alloc((size_t)K_SEL * DOUT_DIM * 4);
  u16*   Bth   = (u16*)alloc((size_t)DOUT_DIM * DOUT_DIM * 2);
  u16*   jlist = (u16*)alloc((size_t)K_SEL * K_SEL * 2);
  int*   njbuf = (int*)alloc((size_t)K_SEL * 4);
  u16*   updbm = (u16*)alloc((size_t)K_SEL * DOUT_DIM * 2);

  // ---- Phase 1: message passing (CSR, atomic-free)
  hipMemsetAsync(counts, 0, (size_t)N_NODES * 4, stream);
  transpose_bf16<<<dim3(DOUT_DIM / 32, DOUT_DIM / 32), 256, 0, stream>>>(
      W_prod_l, Btl, DOUT_DIM, DOUT_DIM);
  gemm64_f32<<<dim3(F_DIM / 64, N_NODES / 64, 1), 256, 0, stream>>>(
      h, F_DIM, W_node_l, F_DIM, hW, F_DIM, N_NODES, F_DIM, F_DIM, F_DIM, nullptr, 0, 0);
  count_kernel<<<E_EDGES / 256, 256, 0, stream>>>(eidx, counts);
  scan_kernel<<<1, 1024, 0, stream>>>(counts, offsets, cursor);
  fill_kernel<<<E_EDGES / 256, 256, 0, stream>>>(eidx, cursor, elist);
  gather_accum_kernel<<<N_NODES, 128, 0, stream>>>(
      hW, edge_sh, edge_feats, W_rad_l, eidx, offsets, counts, elist, upd,
      useB16 ? updb : nullptr);
  // hs (fp32-exact gate input) = upd @ W_prod_l[:, :128] + h, split-K=4 via psum
  hs_gemm_kernel<<<dim3(N_NODES / 128, 4), 256, 0, stream>>>(upd, W_prod_l, psum);
  hs_reduce_kernel<<<(N_NODES * F_DIM / 4) / 256, 256, 0, stream>>>(psum, h, hs);
  // h_local (MFMA bf16) into d_out region 0 (overwrites psum region)
  if (useB16) {
    gemm_mfma_b16<<<(DOUT_DIM / 128) * (N_NODES / 128), 256, 0, stream>>>(
        updb, Btl, out_hf, DOUT_DIM, DOUT_DIM, DOUT_DIM / 128,
        (DOUT_DIM / 128) * (N_NODES / 128), h, F_DIM, F_DIM);
  } else {
    gemm_mfma<<<dim3(DOUT_DIM / 128, N_NODES / 128), 256, 0, stream>>>(
        upd, Btl, out_hf, DOUT_DIM, N_NODES, DOUT_DIM, DOUT_DIM, h, F_DIM, F_DIM);
  }

  // ---- Phase 2
  hipMemsetAsync(adjm, 0, (size_t)2 * K_SEL * K_SEL, stream);     // adjm + adjT
  hipMemsetAsync(hist1, 0, (size_t)65536 * 4 * 2 + 256, stream);  // hist1+hist2+selb
  transpose_bf16<<<dim3(DOUT_DIM / 32, DOUT_DIM / 32), 256, 0, stream>>>(
      W_prod_h, Bth, DOUT_DIM, DOUT_DIM);
  gate_kernel<<<N_NODES / 4, 256, 0, stream>>>(hs, ms_W1, ms_b1, ms_W2, ms_b2,
                                               m_ws, out_m, hist1);
  // radix top-K selection (exact; ties broken by smaller index, matching top_k)
  radix_sel_kernel<<<1, 1024, 0, stream>>>(hist1, nullptr, 0, selb, 0);
  hist2_kernel<<<N_NODES / 256, 256, 0, stream>>>(m_ws, selb, hist2);
  radix_sel_kernel<<<1, 1024, 0, stream>>>(hist2, selb, 1, selb, 2);
  flag_kernel<<<N_NODES / 256, 256, 0, stream>>>(m_ws, selb, flags, cand);
  cand_kernel<<<1, 1024, 0, stream>>>(selb, cand, flags);
  compact_kernel<<<1, 1024, 0, stream>>>(flags, midx, rank, out_mi);
  adj_kernel<<<E_EDGES / 256, 256, 0, stream>>>(eidx, rank, adjm, adjT);
  gather_kernel<<<K_SEL, 128, 0, stream>>>(out_hf, pos, midx, h_m, pos_m);
  qk_kernel<<<K_SEL, 128, 0, stream>>>(hs, midx, vg_Wq, vg_Wk, qbuf, kbuf);
  attn_kernel<<<dim3(K_SEL / 16, K_SEL / 16), dim3(16, 16), 0, stream>>>(
      qbuf, kbuf, maskA, maskAT, out_Av);
  listbuild_kernel<<<K_SEL, 256, 0, stream>>>(adjT, maskAT, maskA, jlist, njbuf);
  hipMemsetAsync(hWn, 0, (size_t)K_SEL * F_DIM * 4, stream);
  gemm64_f32<<<dim3(F_DIM / 64, K_SEL / 64, 4), 256, 0, stream>>>(
      h_m, DOUT_DIM, W_node_h, F_DIM, hWn, F_DIM,
      K_SEL, F_DIM, DOUT_DIM, DOUT_DIM / 4, nullptr, 0, 0);
  hier2_kernel<<<K_SEL, 512, 0, stream>>>(hWn, pos_m, W_rad_h, jlist, njbuf, upd_m, updbm);
  gemm_mfma_b16<<<(DOUT_DIM / 128) * (K_SEL / 128), 256, 0, stream>>>(
      updbm, Bth, h_hier, DOUT_DIM, DOUT_DIM, DOUT_DIM / 128,
      (DOUT_DIM / 128) * (K_SEL / 128), h_m, DOUT_DIM, DOUT_DIM);
  combine_kernel<<<(N_NODES * DOUT_DIM / 4) / 256, 256, 0, stream>>>(out_hf, h_hier, m_ws, rank);
}

// Round 9
// 649.204 us; speedup vs baseline: 1.0445x; 1.0287x over previous
//
#include <hip/hip_runtime.h>
#include <hip/hip_bf16.h>
#include <stdint.h>

#define N_NODES 16384
#define E_EDGES 131072
#define F_DIM 128
#define L_DIM 9
#define R_DIM 8
#define DOUT_DIM 1152
#define K_SEL 1024
#define HID_DIM 64
#define DA_DIM 64

typedef unsigned short u16;
typedef __attribute__((ext_vector_type(8))) short bf16x8;
typedef __attribute__((ext_vector_type(4))) float f32x4;

static __device__ inline u16 f2bs(float x) {
  union { __hip_bfloat16 b; u16 s; } u;
  u.b = __float2bfloat16(x);
  return u.s;
}

// async global->LDS, 16B per lane. LDS dest must be waveBase + lane*16.
#define GLDS16(gsrc, ldst) __builtin_amdgcn_global_load_lds( \
    (__attribute__((address_space(1))) void*)(void*)(gsrc),  \
    (__attribute__((address_space(3))) void*)(ldst), 16, 0, 0)

// ================= MFMA GEMM (fallback): C = A(f32->bf16) * B^T(bf16) [+Add]
__global__ __launch_bounds__(256) void gemm_mfma(
    const float* __restrict__ A, const u16* __restrict__ Bt,
    float* __restrict__ C, int ldc, int M, int Nc, int Kc,
    const float* __restrict__ Add, int ldadd, int addW)
{
  __shared__ float Af[128 * 32];   // [m][oct ^ (m&7)]
  __shared__ u16  Bs[128 * 32];    // [n][q ^ ((n>>1)&3)]
  const int tid = threadIdx.x;
  const int wave = tid >> 6, lane = tid & 63;
  const int wm = wave >> 1, wn = wave & 1;
  const int l15 = lane & 15, quad = lane >> 4;
  const int bm = blockIdx.y * 128, bn = blockIdx.x * 128;

  f32x4 acc[4][4];
#pragma unroll
  for (int i = 0; i < 4; i++)
#pragma unroll
    for (int j = 0; j < 4; j++) acc[i][j] = (f32x4)(0.f);

  for (int k0 = 0; k0 < Kc; k0 += 32) {
    __syncthreads();
#pragma unroll
    for (int it = 0; it < 4; it++) {
      int c = it * 256 + tid;
      int row = c >> 3, op = c & 7;
      int oct = op ^ (row & 7);
      const float* g = A + (size_t)(bm + row) * Kc + k0 + oct * 4;
      GLDS16(g, &Af[c * 4]);
    }
#pragma unroll
    for (int it = 0; it < 2; it++) {
      int c = it * 256 + tid;
      int row = c >> 2, qp = c & 3;
      int q = qp ^ ((row >> 1) & 3);
      const u16* g = Bt + (size_t)(bn + row) * Kc + k0 + q * 8;
      GLDS16(g, &Bs[c * 8]);
    }
    __syncthreads();

    bf16x8 af[4], bfg[4];
#pragma unroll
    for (int mi = 0; mi < 4; mi++) {
      int m = wm * 64 + mi * 16 + l15;
      int o0 = (quad * 2) ^ (m & 7), o1 = (quad * 2 + 1) ^ (m & 7);
      float4 lo = *(const float4*)&Af[m * 32 + o0 * 4];
      float4 hi = *(const float4*)&Af[m * 32 + o1 * 4];
      bf16x8 r;
      r[0] = (short)f2bs(lo.x); r[1] = (short)f2bs(lo.y);
      r[2] = (short)f2bs(lo.z); r[3] = (short)f2bs(lo.w);
      r[4] = (short)f2bs(hi.x); r[5] = (short)f2bs(hi.y);
      r[6] = (short)f2bs(hi.z); r[7] = (short)f2bs(hi.w);
      af[mi] = r;
    }
#pragma unroll
    for (int ni = 0; ni < 4; ni++) {
      int n = wn * 64 + ni * 16 + l15;
      int q2 = quad ^ ((n >> 1) & 3);
      bfg[ni] = *(const bf16x8*)&Bs[n * 32 + q2 * 8];
    }
#pragma unroll
    for (int mi = 0; mi < 4; mi++)
#pragma unroll
      for (int ni = 0; ni < 4; ni++)
        acc[mi][ni] = __builtin_amdgcn_mfma_f32_16x16x32_bf16(af[mi], bfg[ni], acc[mi][ni], 0, 0, 0);
  }
#pragma unroll
  for (int mi = 0; mi < 4; mi++)
#pragma unroll
    for (int ni = 0; ni < 4; ni++)
#pragma unroll
      for (int r = 0; r < 4; r++) {
        int row = bm + wm * 64 + mi * 16 + quad * 4 + r;
        int col = bn + wn * 64 + ni * 16 + l15;
        float v = acc[mi][ni][r];
        if (Add != nullptr && col < addW) v += Add[(size_t)row * ldadd + col];
        C[(size_t)row * ldc + col] = v;
      }
}

// ================= MFMA GEMM, bf16 A, double-buffered prefetch (measured-best form:
// STAGE(next) issued before compute, single __syncthreads per k-step).
// 1D grid with XCD-chunked swizzle (nwg % 8 == 0).
__global__ __launch_bounds__(256) void gemm_mfma_b16(
    const u16* __restrict__ A, const u16* __restrict__ Bt,
    float* __restrict__ C, int ldc, int Kc, int nbx, int nwg,
    const float* __restrict__ Add, int ldadd, int addW)
{
  __shared__ u16 As[2][128 * 32];  // [buf][m][q ^ ((m>>1)&3)]
  __shared__ u16 Bs[2][128 * 32];  // [buf][n][q ^ ((n>>1)&3)]
  const int tid = threadIdx.x;
  const int wave = tid >> 6, lane = tid & 63;
  const int wm = wave >> 1, wn = wave & 1;
  const int l15 = lane & 15, quad = lane >> 4;
  const int lin = blockIdx.x;
  const int swz = (lin & 7) * (nwg >> 3) + (lin >> 3);  // XCD-chunked, bijective
  const int bm = (swz / nbx) * 128, bn = (swz % nbx) * 128;

  const int c0 = tid,      r0 = c0 >> 2, q0 = (c0 & 3) ^ ((r0 >> 1) & 3);
  const int c1 = 256 + tid, r1 = c1 >> 2, q1 = (c1 & 3) ^ ((r1 >> 1) & 3);
  const u16* gA0 = A + (size_t)(bm + r0) * Kc + q0 * 8;
  const u16* gA1 = A + (size_t)(bm + r1) * Kc + q1 * 8;
  const u16* gB0 = Bt + (size_t)(bn + r0) * Kc + q0 * 8;
  const u16* gB1 = Bt + (size_t)(bn + r1) * Kc + q1 * 8;

  f32x4 acc[4][4];
#pragma unroll
  for (int i = 0; i < 4; i++)
#pragma unroll
    for (int j = 0; j < 4; j++) acc[i][j] = (f32x4)(0.f);

#define STAGE_AB(s, k0) do {                      \
    GLDS16(gA0 + (k0), &As[s][c0 * 8]);           \
    GLDS16(gA1 + (k0), &As[s][c1 * 8]);           \
    GLDS16(gB0 + (k0), &Bs[s][c0 * 8]);           \
    GLDS16(gB1 + (k0), &Bs[s][c1 * 8]);           \
  } while (0)

  STAGE_AB(0, 0);
  __syncthreads();
  int cur = 0;
  const int nt = Kc / 32;
  for (int t = 0; t < nt; t++) {
    if (t + 1 < nt) STAGE_AB(cur ^ 1, (t + 1) * 32);
    bf16x8 af[4], bfg[4];
#pragma unroll
    for (int mi = 0; mi < 4; mi++) {
      int m = wm * 64 + mi * 16 + l15;
      af[mi] = *(const bf16x8*)&As[cur][m * 32 + (quad ^ ((m >> 1) & 3)) * 8];
    }
#pragma unroll
    for (int ni = 0; ni < 4; ni++) {
      int n = wn * 64 + ni * 16 + l15;
      bfg[ni] = *(const bf16x8*)&Bs[cur][n * 32 + (quad ^ ((n >> 1) & 3)) * 8];
    }
#pragma unroll
    for (int mi = 0; mi < 4; mi++)
#pragma unroll
      for (int ni = 0; ni < 4; ni++)
        acc[mi][ni] = __builtin_amdgcn_mfma_f32_16x16x32_bf16(af[mi], bfg[ni], acc[mi][ni], 0, 0, 0);
    __syncthreads();
    cur ^= 1;
  }
#undef STAGE_AB

#pragma unroll
  for (int mi = 0; mi < 4; mi++)
#pragma unroll
    for (int ni = 0; ni < 4; ni++)
#pragma unroll
      for (int r = 0; r < 4; r++) {
        int row = bm + wm * 64 + mi * 16 + quad * 4 + r;
        int col = bn + wn * 64 + ni * 16 + l15;
        float v = acc[mi][ni][r];
        if (Add != nullptr && col < addW) v += Add[(size_t)row * ldadd + col];
        C[(size_t)row * ldc + col] = v;
      }
}

// ================= transpose + bf16 cast
__global__ __launch_bounds__(256) void transpose_bf16(
    const float* __restrict__ W, u16* __restrict__ Bt, int K, int N)
{
  __shared__ float t[32][33];
  const int n0 = blockIdx.x * 32, k0 = blockIdx.y * 32;
  const int tx = threadIdx.x & 31, ty = threadIdx.x >> 5;
  for (int r = ty; r < 32; r += 8) t[r][tx] = W[(size_t)(k0 + r) * N + n0 + tx];
  __syncthreads();
  for (int r = ty; r < 32; r += 8) Bt[(size_t)(n0 + r) * K + k0 + tx] = f2bs(t[tx][r]);
}

// ================= hs GEMM: psum[z] = upd[:, z*288:(z+1)*288] @ W_prod_l[z-chunk, :128]
__global__ __launch_bounds__(256) void hs_gemm_kernel(
    const float* __restrict__ A,      // upd, lda = DOUT_DIM
    const float* __restrict__ B,      // W_prod_l, ldb = DOUT_DIM (cols 0..127)
    float* __restrict__ psum)         // [4][N_NODES][F_DIM]
{
  __shared__ float As[16][129];
  __shared__ float Bs[16][128];
  const int tid = threadIdx.x;
  const int tx = tid & 15, ty = tid >> 4;
  const int bm = blockIdx.x * 128;
  const int z = blockIdx.y;
  const int kb = z * (DOUT_DIM / 4);
  const int ke = kb + DOUT_DIM / 4;
  const int ac = tid & 15, ar0 = tid >> 4;
  const int bc = tid & 127, br0 = tid >> 7;
  float acc[8][8];
#pragma unroll
  for (int i = 0; i < 8; i++)
#pragma unroll
    for (int j = 0; j < 8; j++) acc[i][j] = 0.f;

  float ra[8], rb[8];
#define LOADREG(k0) do {                                                       \
    _Pragma("unroll")                                                          \
    for (int rr = 0; rr < 8; rr++)                                             \
      ra[rr] = A[(size_t)(bm + ar0 + rr * 16) * DOUT_DIM + (k0) + ac];         \
    _Pragma("unroll")                                                          \
    for (int rr = 0; rr < 8; rr++)                                             \
      rb[rr] = B[(size_t)((k0) + br0 + rr * 2) * DOUT_DIM + bc];               \
  } while (0)

  LOADREG(kb);
  for (int k0 = kb; k0 < ke; k0 += 16) {
#pragma unroll
    for (int rr = 0; rr < 8; rr++) As[ac][ar0 + rr * 16] = ra[rr];
#pragma unroll
    for (int rr = 0; rr < 8; rr++) Bs[br0 + rr * 2][bc] = rb[rr];
    __syncthreads();
    if (k0 + 16 < ke) LOADREG(k0 + 16);
#pragma unroll
    for (int kk = 0; kk < 16; kk++) {
      float a[8], b[8];
#pragma unroll
      for (int i = 0; i < 8; i++) a[i] = As[kk][ty * 8 + i];
#pragma unroll
      for (int j = 0; j < 8; j++) b[j] = Bs[kk][tx * 8 + j];
#pragma unroll
      for (int i = 0; i < 8; i++)
#pragma unroll
        for (int j = 0; j < 8; j++) acc[i][j] = fmaf(a[i], b[j], acc[i][j]);
    }
    __syncthreads();
  }
#undef LOADREG
#pragma unroll
  for (int i = 0; i < 8; i++) {
    size_t row = (size_t)z * N_NODES + bm + ty * 8 + i;
#pragma unroll
    for (int j = 0; j < 8; j++)
      psum[row * F_DIM + tx * 8 + j] = acc[i][j];
  }
}

// hs = psum[0]+psum[1]+psum[2]+psum[3] + h   (float4)
__global__ __launch_bounds__(256) void hs_reduce_kernel(
    const float* __restrict__ psum, const float* __restrict__ h, float* __restrict__ hs)
{
  size_t i4 = (size_t)blockIdx.x * 256 + threadIdx.x;
  const size_t stride = (size_t)N_NODES * F_DIM / 4;
  const float4* p = (const float4*)psum;
  float4 a = p[i4], b = p[i4 + stride], c = p[i4 + 2 * stride], d = p[i4 + 3 * stride];
  float4 hh = ((const float4*)h)[i4];
  float4 o;
  o.x = a.x + b.x + c.x + d.x + hh.x;
  o.y = a.y + b.y + c.y + d.y + hh.y;
  o.z = a.z + b.z + c.z + d.z + hh.z;
  o.w = a.w + b.w + c.w + d.w + hh.w;
  ((float4*)hs)[i4] = o;
}

// ================= fp32 GEMM 64x64, optional split-K
__global__ __launch_bounds__(256) void gemm64_f32(
    const float* __restrict__ A, int lda,
    const float* __restrict__ B, int ldb,
    float* __restrict__ C, int ldc,
    int M, int Nc, int Kc, int kPerSplit,
    const float* __restrict__ Add, int ldadd, int addW)
{
  __shared__ float As[16][65];
  __shared__ float Bs[16][64];
  const int tid = threadIdx.x;
  const int tx = tid & 15, ty = tid >> 4;
  const int bm = blockIdx.y * 64, bn = blockIdx.x * 64;
  const int kb = blockIdx.z * kPerSplit;
  const int ke = min(kb + kPerSplit, Kc);
  float acc[4][4];
#pragma unroll
  for (int i = 0; i < 4; i++)
#pragma unroll
    for (int j = 0; j < 4; j++) acc[i][j] = 0.f;
  for (int k0 = kb; k0 < ke; k0 += 16) {
    const int ac = tid & 15, ar = tid >> 4;
#pragma unroll
    for (int rr = 0; rr < 4; rr++) {
      int row = ar + rr * 16;
      As[ac][row] = A[(size_t)(bm + row) * lda + k0 + ac];
    }
    const int bc = tid & 63, br = tid >> 6;
#pragma unroll
    for (int rr = 0; rr < 4; rr++) {
      int kr = br + rr * 4;
      Bs[kr][bc] = B[(size_t)(k0 + kr) * ldb + bn + bc];
    }
    __syncthreads();
#pragma unroll
    for (int kk = 0; kk < 16; kk++) {
      float a[4], b[4];
#pragma unroll
      for (int i = 0; i < 4; i++) a[i] = As[kk][ty * 4 + i];
#pragma unroll
      for (int j = 0; j < 4; j++) b[j] = Bs[kk][tx * 4 + j];
#pragma unroll
      for (int i = 0; i < 4; i++)
#pragma unroll
        for (int j = 0; j < 4; j++) acc[i][j] = fmaf(a[i], b[j], acc[i][j]);
    }
    __syncthreads();
  }
#pragma unroll
  for (int i = 0; i < 4; i++) {
    int row = bm + ty * 4 + i;
#pragma unroll
    for (int j = 0; j < 4; j++) {
      int col = bn + tx * 4 + j;
      if (gridDim.z > 1) {
        atomicAdd(&C[(size_t)row * ldc + col], acc[i][j]);
      } else {
        float v = acc[i][j];
        if (Add != nullptr && col < addW) v += Add[(size_t)row * ldadd + col];
        C[(size_t)row * ldc + col] = v;
      }
    }
  }
}

// ================= CSR build: count / scan / fill
__global__ __launch_bounds__(256) void count_kernel(
    const int* __restrict__ ei, int* __restrict__ counts)
{
  int e = blockIdx.x * 256 + threadIdx.x;
  atomicAdd(&counts[ei[E_EDGES + e]], 1);
}

__global__ __launch_bounds__(1024) void scan_kernel(
    const int* __restrict__ counts, int* __restrict__ offsets, int* __restrict__ cursor)
{
  __shared__ int part[1024];
  const int t = threadIdx.x;
  const int base = t * 16;
  int loc[16];
  int s = 0;
#pragma unroll
  for (int k = 0; k < 16; k++) { loc[k] = counts[base + k]; s += loc[k]; }
  part[t] = s;
  __syncthreads();
  for (int d = 1; d < 1024; d <<= 1) {
    int v = (t >= d) ? part[t - d] : 0;
    __syncthreads();
    part[t] += v;
    __syncthreads();
  }
  int run = part[t] - s;  // exclusive prefix
#pragma unroll
  for (int k = 0; k < 16; k++) {
    offsets[base + k] = run;
    cursor[base + k] = run;
    run += loc[k];
  }
}

__global__ __launch_bounds__(256) void fill_kernel(
    const int* __restrict__ ei, int* __restrict__ cursor, int* __restrict__ elist)
{
  int e = blockIdx.x * 256 + threadIdx.x;
  int d = ei[E_EDGES + e];
  int p = atomicAdd(&cursor[d], 1);
  elist[p] = e;
}

// ================= atomic-free edge accumulation: block per dst node.
__global__ __launch_bounds__(128) void gather_accum_kernel(
    const float* __restrict__ hW, const float* __restrict__ edge_sh,
    const float* __restrict__ edge_feats, const float* __restrict__ W_rad_l,
    const int* __restrict__ ei, const int* __restrict__ offsets,
    const int* __restrict__ counts, const int* __restrict__ elist,
    float* __restrict__ upd, u16* __restrict__ updb)
{
  const int d = blockIdx.x, f = threadIdx.x;
  const float w0 = W_rad_l[0 * F_DIM + f], w1 = W_rad_l[1 * F_DIM + f];
  const float w2 = W_rad_l[2 * F_DIM + f], w3 = W_rad_l[3 * F_DIM + f];
  const float w4 = W_rad_l[4 * F_DIM + f], w5 = W_rad_l[5 * F_DIM + f];
  const float w6 = W_rad_l[6 * F_DIM + f], w7 = W_rad_l[7 * F_DIM + f];
  const int b = offsets[d], n = counts[d];
  float acc[L_DIM];
#pragma unroll
  for (int l = 0; l < L_DIM; l++) acc[l] = 0.f;
  for (int k = 0; k < n; k++) {
    const int e = elist[b + k];
    const int s = ei[e];
    const float4 ef0 = *(const float4*)&edge_feats[(size_t)e * R_DIM];
    const float4 ef1 = *(const float4*)&edge_feats[(size_t)e * R_DIM + 4];
    float rw = ef0.x * w0;
    rw = fmaf(ef0.y, w1, rw); rw = fmaf(ef0.z, w2, rw); rw = fmaf(ef0.w, w3, rw);
    rw = fmaf(ef1.x, w4, rw); rw = fmaf(ef1.y, w5, rw);
    rw = fmaf(ef1.z, w6, rw); rw = fmaf(ef1.w, w7, rw);
    const float tf = hW[(size_t)s * F_DIM + f] * rw;
#pragma unroll
    for (int l = 0; l < L_DIM; l++)
      acc[l] = fmaf(edge_sh[(size_t)e * L_DIM + l], tf, acc[l]);
  }
#pragma unroll
  for (int l = 0; l < L_DIM; l++)
    upd[(size_t)d * DOUT_DIM + l * F_DIM + f] = acc[l];
  if (updb != nullptr) {
#pragma unroll
    for (int l = 0; l < L_DIM; l++)
      updb[(size_t)d * DOUT_DIM + l * F_DIM + f] = f2bs(acc[l]);
  }
}

// ================= gating MLP on hs (fp32, ld=F_DIM) + fused 16-bit histogram
__global__ __launch_bounds__(256) void gate_kernel(
    const float* __restrict__ hs, const float* __restrict__ W1,
    const float* __restrict__ b1, const float* __restrict__ W2,
    const float* __restrict__ b2, float* __restrict__ m_ws, float* __restrict__ m_out,
    int* __restrict__ hist1)
{
  __shared__ float sW1[F_DIM * HID_DIM];
  __shared__ float srow[4][F_DIM];
  const int tid = threadIdx.x;
  for (int t = tid; t < F_DIM * HID_DIM; t += 256) sW1[t] = W1[t];
  const int wave = tid >> 6, lane = tid & 63;
  const int n = blockIdx.x * 4 + wave;
  srow[wave][lane] = hs[(size_t)n * F_DIM + lane];
  srow[wave][lane + 64] = hs[(size_t)n * F_DIM + lane + 64];
  __syncthreads();
  float hid = b1[lane];
#pragma unroll 8
  for (int c = 0; c < F_DIM; c++) hid = fmaf(srow[wave][c], sW1[c * HID_DIM + lane], hid);
  hid = fmaxf(hid, 0.f);
  float v = hid * W2[lane];
#pragma unroll
  for (int off = 32; off > 0; off >>= 1) v += __shfl_down(v, off);
  if (lane == 0) {
    float mm = 1.f / (1.f + expf(-(v + b2[0])));
    m_ws[n] = mm;
    m_out[n] = mm;
    unsigned mb = __float_as_uint(mm);
    atomicAdd(&hist1[mb >> 16], 1);
  }
}

// ================= radix top-K selection
__global__ __launch_bounds__(1024) void radix_sel_kernel(
    const int* __restrict__ hist, const int* __restrict__ kin, int kinIdx,
    int* __restrict__ outp, int outIdx)
{
  __shared__ int part[1024];
  const int t = threadIdx.x;
  const int Kv = kin ? kin[kinIdx] : K_SEL;
  const int base = t * 64;
  int s = 0;
  for (int k = 0; k < 64; k++) s += hist[base + k];
  part[t] = s;
  __syncthreads();
  for (int d = 1; d < 1024; d <<= 1) {
    int v = (t + d < 1024) ? part[t + d] : 0;
    __syncthreads();
    part[t] += v;
    __syncthreads();
  }
  int inc = part[t];
  if (inc >= Kv && inc - s < Kv) {
    int r = inc - s;
    for (int b = base + 63; b >= base; b--) {
      int hv = hist[b];
      if (r + hv >= Kv) { outp[outIdx] = b; outp[outIdx + 1] = Kv - r; break; }
      r += hv;
    }
  }
}

__global__ __launch_bounds__(256) void hist2_kernel(
    const float* __restrict__ m_ws, const int* __restrict__ selb, int* __restrict__ hist2)
{
  int i = blockIdx.x * 256 + threadIdx.x;
  unsigned mb = __float_as_uint(m_ws[i]);
  if ((int)(mb >> 16) == selb[0]) atomicAdd(&hist2[mb & 0xFFFFu], 1);
}

__global__ __launch_bounds__(256) void flag_kernel(
    const float* __restrict__ m_ws, int* __restrict__ selb,
    unsigned char* __restrict__ flags, int* __restrict__ cand)
{
  int i = blockIdx.x * 256 + threadIdx.x;
  unsigned mb = __float_as_uint(m_ws[i]);
  unsigned vb = ((unsigned)selb[0] << 16) | (unsigned)selb[2];
  unsigned char fl = 0;
  if (mb > vb) fl = 1;
  else if (mb == vb) { int p = atomicAdd(&selb[4], 1); cand[p] = i; }
  flags[i] = fl;
}

// fused: tie-break (pick selb[3] smallest candidate indices) + prefix-scan compaction
__global__ __launch_bounds__(1024) void compact_kernel(
    const int* __restrict__ selb, const int* __restrict__ cand,
    unsigned char* flags, int* __restrict__ midx,
    int* __restrict__ rank, float* __restrict__ mi_out)
{
  __shared__ int part[1024];
  const int t = threadIdx.x;
  const int nc = selb[4], need = selb[3];
  for (int c = t; c < nc; c += 1024) {
    const int idx = cand[c];
    int r = 0;
    for (int o = 0; o < nc; o++) r += (cand[o] < idx) ? 1 : 0;
    if (r < need) flags[idx] = 1;
  }
  __syncthreads();
  const int base = t * 16;
  int loc[16];
  int s = 0;
#pragma unroll
  for (int k = 0; k < 16; k++) { loc[k] = flags[base + k]; s += loc[k]; }
  part[t] = s;
  __syncthreads();
  for (int d = 1; d < 1024; d <<= 1) {
    int v = (t >= d) ? part[t - d] : 0;
    __syncthreads();
    part[t] += v;
    __syncthreads();
  }
  int run = part[t] - s;
#pragma unroll
  for (int k = 0; k < 16; k++) {
    int i = base + k;
    if (loc[k]) {
      midx[run] = i;
      mi_out[run] = (float)i;
      rank[i] = run;
      run++;
    } else {
      rank[i] = K_SEL;
    }
  }
}

// ================= induced adjacency (+ transposed copy for coalesced listbuild)
__global__ __launch_bounds__(256) void adj_kernel(
    const int* __restrict__ ei, const int* __restrict__ rank,
    unsigned char* __restrict__ adjm, unsigned char* __restrict__ adjT)
{
  int e = blockIdx.x * 256 + threadIdx.x;
  int rs = rank[ei[e]];
  int rd = rank[ei[E_EDGES + e]];
  if (rs < K_SEL && rd < K_SEL) {
    adjm[(size_t)rs * K_SEL + rd] = 1;
    adjT[(size_t)rd * K_SEL + rs] = 1;
  }
}

// ================= gather master rows + positions (float4)
__global__ __launch_bounds__(128) void gather_kernel(
    const float* __restrict__ hl, const float* __restrict__ pos,
    const int* __restrict__ midx, float* __restrict__ h_m, float* __restrict__ pos_m)
{
  const int rI = blockIdx.x, t = threadIdx.x;
  const int mi = midx[rI];
  const float4* src = (const float4*)(hl + (size_t)mi * DOUT_DIM);
  float4* dst = (float4*)(h_m + (size_t)rI * DOUT_DIM);
  for (int c = t; c < DOUT_DIM / 4; c += 128) dst[c] = src[c];
  if (t < 3) pos_m[rI * 3 + t] = pos[mi * 3 + t];
}

// ================= q/k projections from hs at master rows
__global__ __launch_bounds__(128) void qk_kernel(
    const float* __restrict__ hs, const int* __restrict__ midx,
    const float* __restrict__ Wq, const float* __restrict__ Wk,
    float* __restrict__ q, float* __restrict__ kk)
{
  __shared__ float row[F_DIM];
  const int i = blockIdx.x, t = threadIdx.x;
  const int mi = midx[i];
  row[t] = hs[(size_t)mi * F_DIM + t];
  __syncthreads();
  const int d = t & 63;
  const float* W = (t < 64) ? Wq : Wk;
  float acc = 0.f;
#pragma unroll 8
  for (int c = 0; c < F_DIM; c++) acc = fmaf(row[c], W[c * DA_DIM + d], acc);
  float* dst = (t < 64) ? q : kk;
  dst[(size_t)i * DA_DIM + d] = acc;
}

// ================= attention (padded LDS; also emits transposed mask)
__global__ __launch_bounds__(256) void attn_kernel(
    const float* __restrict__ q, const float* __restrict__ kk,
    unsigned char* __restrict__ maskA, unsigned char* __restrict__ maskAT,
    float* __restrict__ Av)
{
  __shared__ float qs[16][DA_DIM + 1], ks[16][DA_DIM + 1];
  const int tx = threadIdx.x, ty = threadIdx.y;
  const int tid = ty * 16 + tx;
  const int i0 = blockIdx.y * 16, j0 = blockIdx.x * 16;
  for (int t = tid; t < 16 * DA_DIM; t += 256) {
    int rr = t >> 6, cc = t & 63;
    qs[rr][cc] = q[(size_t)(i0 + rr) * DA_DIM + cc];
    ks[rr][cc] = kk[(size_t)(j0 + rr) * DA_DIM + cc];
  }
  __syncthreads();
  float acc = 0.f;
#pragma unroll
  for (int d2 = 0; d2 < DA_DIM; d2++) acc = fmaf(qs[ty][d2], ks[tx][d2], acc);
  float sgl = 1.f / (1.f + expf(-acc * 0.125f));
  size_t o = (size_t)(i0 + ty) * K_SEL + (j0 + tx);
  bool big = sgl > 0.5f;
  unsigned char bb = big ? 1 : 0;
  maskA[o] = bb;
  maskAT[(size_t)(j0 + tx) * K_SEL + (i0 + ty)] = bb;
  Av[o] = big ? sgl : 0.f;
}

// ================= per-i active-j list (coalesced row reads + wave-ballot)
__global__ __launch_bounds__(256) void listbuild_kernel(
    const unsigned char* __restrict__ adjT, const unsigned char* __restrict__ maskAT,
    const unsigned char* __restrict__ maskA, u16* __restrict__ list, int* __restrict__ nj)
{
  __shared__ int cnt;
  const int i = blockIdx.x, tid = threadIdx.x;
  const int lane = tid & 63;
  if (tid == 0) cnt = 0;
  __syncthreads();
  const int j0 = tid * 4;
  uchar4 a  = *(const uchar4*)&adjT  [(size_t)i * K_SEL + j0];
  uchar4 mt = *(const uchar4*)&maskAT[(size_t)i * K_SEL + j0];
  uchar4 ma = *(const uchar4*)&maskA [(size_t)i * K_SEL + j0];
  unsigned char av[4];
  av[0] = a.x | mt.x | ma.x; av[1] = a.y | mt.y | ma.y;
  av[2] = a.z | mt.z | ma.z; av[3] = a.w | mt.w | ma.w;
#pragma unroll
  for (int r = 0; r < 4; r++) {
    int j = j0 + r;
    bool e = (j != i) && av[r];
    unsigned long long m = __ballot(e);
    int nset = __popcll(m);
    int base = 0;
    if (lane == 0 && nset) base = atomicAdd(&cnt, nset);
    base = __shfl(base, 0);
    if (e) {
      int p = base + __popcll(m & ((1ull << lane) - 1ull));
      list[(size_t)i * K_SEL + p] = (u16)j;
    }
  }
  __syncthreads();
  if (tid == 0) nj[i] = cnt;
}

// ================= hier v6: 2 f per lane — 256 threads = 4 jsub x 64 lanes,
// lane covers f=lane and f=lane+64. Geometry LDS reads amortized over 2 f
// (5 DS reads feed 36 FMAs instead of 18). Only bf16 output (fp32 was dead).
__global__ __launch_bounds__(256) void hier2_kernel(
    const float* __restrict__ hWn, const float* __restrict__ pos_m,
    const float* __restrict__ W_rad_h, const u16* __restrict__ list,
    const int* __restrict__ nj, u16* __restrict__ updb_m)
{
  __shared__ float gsm[128][20];   // [pair][rd0..7, sh0..8, jbits, pad, pad]
  __shared__ float red[3][L_DIM][F_DIM];
  const int tid = threadIdx.x;
  const int i = blockIdx.x;
  const int lane = tid & 63, jsub = tid >> 6;
  const int f0 = lane, f1 = lane + 64;
  const float a0 = W_rad_h[0 * F_DIM + f0], a1 = W_rad_h[1 * F_DIM + f0];
  const float a2 = W_rad_h[2 * F_DIM + f0], a3 = W_rad_h[3 * F_DIM + f0];
  const float a4 = W_rad_h[4 * F_DIM + f0], a5 = W_rad_h[5 * F_DIM + f0];
  const float a6 = W_rad_h[6 * F_DIM + f0], a7 = W_rad_h[7 * F_DIM + f0];
  const float b0 = W_rad_h[0 * F_DIM + f1], b1 = W_rad_h[1 * F_DIM + f1];
  const float b2 = W_rad_h[2 * F_DIM + f1], b3 = W_rad_h[3 * F_DIM + f1];
  const float b4 = W_rad_h[4 * F_DIM + f1], b5 = W_rad_h[5 * F_DIM + f1];
  const float b6 = W_rad_h[6 * F_DIM + f1], b7 = W_rad_h[7 * F_DIM + f1];
  const float pix = pos_m[i * 3 + 0], piy = pos_m[i * 3 + 1], piz = pos_m[i * 3 + 2];
  float acc0[L_DIM], acc1[L_DIM];
#pragma unroll
  for (int l = 0; l < L_DIM; l++) { acc0[l] = 0.f; acc1[l] = 0.f; }
  const int n = nj[i];
  for (int c0 = 0; c0 < n; c0 += 128) {
    const int cnt = min(128, n - c0);
    __syncthreads();
    if (tid < cnt) {
      const int j = list[(size_t)i * K_SEL + c0 + tid];
      float vx = pos_m[j * 3 + 0] - pix;
      float vy = pos_m[j * 3 + 1] - piy;
      float vz = pos_m[j * 3 + 2] - piz;
      float r = sqrtf(vx * vx + vy * vy + vz * vz);
      float rm = fmaxf(r, 1e-9f);
      float inv = 1.f / rm;
      float ux = vx * inv, uy = vy * inv, uz = vz * inv;
      float theta = 0.62831853071795864769f * r;  // pi/R_CUT
      float s1 = sinf(theta), c1 = cosf(theta);
      float coef = 0.632455532033675866f * inv;   // sqrt(2/R_CUT)/max(r,eps)
      float snm2 = 0.f, snm1 = s1;
      gsm[tid][0] = s1 * coef;
#pragma unroll
      for (int nn = 2; nn <= R_DIM; nn++) {
        float sn = 2.f * c1 * snm1 - snm2;
        gsm[tid][nn - 1] = sn * coef;
        snm2 = snm1; snm1 = sn;
      }
      gsm[tid][8] = 1.f; gsm[tid][9] = ux; gsm[tid][10] = uy; gsm[tid][11] = uz;
      gsm[tid][12] = ux * uy; gsm[tid][13] = uy * uz;
      gsm[tid][14] = 3.f * uz * uz - 1.f;
      gsm[tid][15] = ux * uz; gsm[tid][16] = ux * ux - uy * uy;
      gsm[tid][17] = __int_as_float(j);
      gsm[tid][18] = 0.f; gsm[tid][19] = 0.f;
    }
    __syncthreads();
    for (int t = jsub; t < cnt; t += 4) {
      float2 s2 = *(const float2*)&gsm[t][16];   // sh8, jbits
      const int j = __float_as_int(s2.y);
      const float hw0 = hWn[(size_t)j * F_DIM + f0];
      const float hw1 = hWn[(size_t)j * F_DIM + f1];
      float4 r0 = *(const float4*)&gsm[t][0];    // rd0..3
      float4 r1 = *(const float4*)&gsm[t][4];    // rd4..7
      float4 s0 = *(const float4*)&gsm[t][8];    // sh0..3
      float4 s1g = *(const float4*)&gsm[t][12];  // sh4..7
      float rwa = r0.x * a0;
      rwa = fmaf(r0.y, a1, rwa); rwa = fmaf(r0.z, a2, rwa); rwa = fmaf(r0.w, a3, rwa);
      rwa = fmaf(r1.x, a4, rwa); rwa = fmaf(r1.y, a5, rwa);
      rwa = fmaf(r1.z, a6, rwa); rwa = fmaf(r1.w, a7, rwa);
      float rwb = r0.x * b0;
      rwb = fmaf(r0.y, b1, rwb); rwb = fmaf(r0.z, b2, rwb); rwb = fmaf(r0.w, b3, rwb);
      rwb = fmaf(r1.x, b4, rwb); rwb = fmaf(r1.y, b5, rwb);
      rwb = fmaf(r1.z, b6, rwb); rwb = fmaf(r1.w, b7, rwb);
      const float tm0 = hw0 * rwa;
      const float tm1 = hw1 * rwb;
      acc0[0] = fmaf(s0.x, tm0, acc0[0]); acc1[0] = fmaf(s0.x, tm1, acc1[0]);
      acc0[1] = fmaf(s0.y, tm0, acc0[1]); acc1[1] = fmaf(s0.y, tm1, acc1[1]);
      acc0[2] = fmaf(s0.z, tm0, acc0[2]); acc1[2] = fmaf(s0.z, tm1, acc1[2]);
      acc0[3] = fmaf(s0.w, tm0, acc0[3]); acc1[3] = fmaf(s0.w, tm1, acc1[3]);
      acc0[4] = fmaf(s1g.x, tm0, acc0[4]); acc1[4] = fmaf(s1g.x, tm1, acc1[4]);
      acc0[5] = fmaf(s1g.y, tm0, acc0[5]); acc1[5] = fmaf(s1g.y, tm1, acc1[5]);
      acc0[6] = fmaf(s1g.z, tm0, acc0[6]); acc1[6] = fmaf(s1g.z, tm1, acc1[6]);
      acc0[7] = fmaf(s1g.w, tm0, acc0[7]); acc1[7] = fmaf(s1g.w, tm1, acc1[7]);
      acc0[8] = fmaf(s2.x, tm0, acc0[8]); acc1[8] = fmaf(s2.x, tm1, acc1[8]);
    }
  }
  __syncthreads();
  if (jsub > 0) {
#pragma unroll
    for (int l = 0; l < L_DIM; l++) {
      red[jsub - 1][l][f0] = acc0[l];
      red[jsub - 1][l][f1] = acc1[l];
    }
  }
  __syncthreads();
  if (jsub == 0) {
#pragma unroll
    for (int l = 0; l < L_DIM; l++) {
      float v0 = acc0[l] + red[0][l][f0] + red[1][l][f0] + red[2][l][f0];
      float v1 = acc1[l] + red[0][l][f1] + red[1][l][f1] + red[2][l][f1];
      updb_m[(size_t)i * DOUT_DIM + l * F_DIM + f0] = f2bs(v0);
      updb_m[(size_t)i * DOUT_DIM + l * F_DIM + f1] = f2bs(v1);
    }
  }
}

// ================= final blend (float4; 1152 % 4 == 0, vector never spans rows)
__global__ __launch_bounds__(256) void combine_kernel(
    float* __restrict__ out0, const float* __restrict__ h_hier,
    const float* __restrict__ m_ws, const int* __restrict__ rank)
{
  size_t i4 = (size_t)blockIdx.x * 256 + threadIdx.x;
  int n = (int)(i4 / (DOUT_DIM / 4));
  int g4 = (int)(i4 % (DOUT_DIM / 4));
  float mv = m_ws[n];
  int r = rank[n];
  float4 hl = ((const float4*)out0)[i4];
  float4 he = make_float4(0.f, 0.f, 0.f, 0.f);
  if (r < K_SEL) he = ((const float4*)h_hier)[(size_t)r * (DOUT_DIM / 4) + g4];
  float4 o;
  o.x = (1.f - mv) * hl.x + mv * he.x;
  o.y = (1.f - mv) * hl.y + mv * he.y;
  o.z = (1.f - mv) * hl.z + mv * he.z;
  o.w = (1.f - mv) * hl.w + mv * he.w;
  ((float4*)out0)[i4] = o;
}

extern "C" void kernel_launch(void* const* d_in, const int* in_sizes, int n_in,
                              void* d_out, int out_size, void* d_ws, size_t ws_size,
                              hipStream_t stream)
{
  const float* h         = (const float*)d_in[0];
  const float* pos       = (const float*)d_in[1];
  const float* edge_sh   = (const float*)d_in[2];
  const float* edge_feats= (const float*)d_in[3];
  const float* W_node_l  = (const float*)d_in[4];
  const float* W_rad_l   = (const float*)d_in[5];
  const float* W_prod_l  = (const float*)d_in[6];
  const float* ms_W1     = (const float*)d_in[7];
  const float* ms_b1     = (const float*)d_in[8];
  const float* ms_W2     = (const float*)d_in[9];
  const float* ms_b2     = (const float*)d_in[10];
  const float* vg_Wq     = (const float*)d_in[11];
  const float* vg_Wk     = (const float*)d_in[12];
  const float* W_node_h  = (const float*)d_in[13];
  const float* W_rad_h   = (const float*)d_in[14];
  const float* W_prod_h  = (const float*)d_in[15];
  const int*   eidx      = (const int*)d_in[16];

  float* out    = (float*)d_out;
  float* out_hf = out;
  float* out_Av = out + (size_t)N_NODES * DOUT_DIM;
  float* out_m  = out_Av + (size_t)K_SEL * K_SEL;
  float* out_mi = out_m + N_NODES;

  char* ws = (char*)d_ws;
  // Phase 1: upd [0, 75.5MB); hW/hs [75.5, 83.9MB); optional updb [83.9, 121.6MB).
  float* upd = (float*)ws;
  float* hW  = (float*)(ws + (size_t)N_NODES * DOUT_DIM * 4);
  float* hs  = hW;  // hW dead after gather_accum; hs written after
  const size_t updbOff = (size_t)N_NODES * DOUT_DIM * 4 + (size_t)N_NODES * F_DIM * 4;
  const size_t updbNeed = updbOff + (size_t)N_NODES * DOUT_DIM * 2;
  const bool useB16 = (ws_size >= updbNeed);
  u16* updb = (u16*)(ws + updbOff);
  // hs split-K partials borrow out_hf (75.5MB, dead until gemm_mfma_b16 writes it).
  float* psum = out_hf;   // 4 * 16384 * 128 * 4B = 33.6 MB < 75.5 MB
  // Btl + CSR borrow the A_virtual out region (4MB, dead until attn writes it).
  u16* Btl = (u16*)out_Av;                                       // 2.65 MB
  char* csr = (char*)out_Av + (((size_t)DOUT_DIM * DOUT_DIM * 2 + 255) & ~(size_t)255);
  int* counts  = (int*)csr;                                      // 64 KB
  int* offsets = counts + N_NODES;                               // 64 KB
  int* cursor  = offsets + N_NODES;                              // 64 KB
  int* elist   = cursor + N_NODES;                               // 512 KB  (total 3.4MB < 4MB)
  // Phase 2 small pool aliases dead upd.
  size_t off = 0;
  auto alloc = [&](size_t bytes) -> void* {
    void* p = ws + off;
    off += (bytes + 255) & ~(size_t)255;
    return p;
  };
  float* m_ws  = (float*)alloc((size_t)N_NODES * 4);
  int*   rank  = (int*)alloc((size_t)N_NODES * 4);
  int*   midx  = (int*)alloc((size_t)K_SEL * 4);
  int*   hist1 = (int*)alloc((size_t)65536 * 4);
  int*   hist2 = (int*)alloc((size_t)65536 * 4);
  int*   selb  = (int*)alloc((size_t)64 * 4);   // [0]=b1 [1]=need1 [2]=b2 [3]=need2 [4]=ncand
  int*   cand  = (int*)alloc((size_t)N_NODES * 4);
  unsigned char* flags = (unsigned char*)alloc((size_t)N_NODES);
  unsigned char* adjm  = (unsigned char*)alloc((size_t)K_SEL * K_SEL);
  unsigned char* adjT  = (unsigned char*)alloc((size_t)K_SEL * K_SEL);  // contiguous after adjm
  unsigned char* maskA = (unsigned char*)alloc((size_t)K_SEL * K_SEL);
  unsigned char* maskAT= (unsigned char*)alloc((size_t)K_SEL * K_SEL);
  float* qbuf  = (float*)alloc((size_t)K_SEL * DA_DIM * 4);
  float* kbuf  = (float*)alloc((size_t)K_SEL * DA_DIM * 4);
  float* h_m   = (float*)alloc((size_t)K_SEL * DOUT_DIM * 4);
  float* pos_m = (float*)alloc((size_t)K_SEL * 3 * 4);
  float* hWn   = (float*)alloc((size_t)K_SEL * F_DIM * 4);
  float* upd_m = (float*)alloc((size_t)K_SEL * DOUT_DIM * 4);   // kept for layout stability
  float* h_hier= (float*)alloc((size_t)K_SEL * DOUT_DIM * 4);
  u16*   Bth   = (u16*)alloc((size_t)DOUT_DIM * DOUT_DIM * 2);
  u16*   jlist = (u16*)alloc((size_t)K_SEL * K_SEL * 2);
  int*   njbuf = (int*)alloc((size_t)K_SEL * 4);
  u16*   updbm = (u16*)alloc((size_t)K_SEL * DOUT_DIM * 2);
  (void)upd_m;

  // ---- Phase 1: message passing (CSR, atomic-free)
  hipMemsetAsync(counts, 0, (size_t)N_NODES * 4, stream);
  transpose_bf16<<<dim3(DOUT_DIM / 32, DOUT_DIM / 32), 256, 0, stream>>>(
      W_prod_l, Btl, DOUT_DIM, DOUT_DIM);
  gemm64_f32<<<dim3(F_DIM / 64, N_NODES / 64, 1), 256, 0, stream>>>(
      h, F_DIM, W_node_l, F_DIM, hW, F_DIM, N_NODES, F_DIM, F_DIM, F_DIM, nullptr, 0, 0);
  count_kernel<<<E_EDGES / 256, 256, 0, stream>>>(eidx, counts);
  scan_kernel<<<1, 1024, 0, stream>>>(counts, offsets, cursor);
  fill_kernel<<<E_EDGES / 256, 256, 0, stream>>>(eidx, cursor, elist);
  gather_accum_kernel<<<N_NODES, 128, 0, stream>>>(
      hW, edge_sh, edge_feats, W_rad_l, eidx, offsets, counts, elist, upd,
      useB16 ? updb : nullptr);
  // hs (fp32-exact gate input) = upd @ W_prod_l[:, :128] + h, split-K=4 via psum
  hs_gemm_kernel<<<dim3(N_NODES / 128, 4), 256, 0, stream>>>(upd, W_prod_l, psum);
  hs_reduce_kernel<<<(N_NODES * F_DIM / 4) / 256, 256, 0, stream>>>(psum, h, hs);
  // h_local (MFMA bf16) into d_out region 0 (overwrites psum region)
  if (useB16) {
    gemm_mfma_b16<<<(DOUT_DIM / 128) * (N_NODES / 128), 256, 0, stream>>>(
        updb, Btl, out_hf, DOUT_DIM, DOUT_DIM, DOUT_DIM / 128,
        (DOUT_DIM / 128) * (N_NODES / 128), h, F_DIM, F_DIM);
  } else {
    gemm_mfma<<<dim3(DOUT_DIM / 128, N_NODES / 128), 256, 0, stream>>>(
        upd, Btl, out_hf, DOUT_DIM, N_NODES, DOUT_DIM, DOUT_DIM, h, F_DIM, F_DIM);
  }

  // ---- Phase 2
  hipMemsetAsync(adjm, 0, (size_t)2 * K_SEL * K_SEL, stream);     // adjm + adjT
  hipMemsetAsync(hist1, 0, (size_t)65536 * 4 * 2 + 256, stream);  // hist1+hist2+selb
  transpose_bf16<<<dim3(DOUT_DIM / 32, DOUT_DIM / 32), 256, 0, stream>>>(
      W_prod_h, Bth, DOUT_DIM, DOUT_DIM);
  gate_kernel<<<N_NODES / 4, 256, 0, stream>>>(hs, ms_W1, ms_b1, ms_W2, ms_b2,
                                               m_ws, out_m, hist1);
  // radix top-K selection (exact; ties broken by smaller index, matching top_k)
  radix_sel_kernel<<<1, 1024, 0, stream>>>(hist1, nullptr, 0, selb, 0);
  hist2_kernel<<<N_NODES / 256, 256, 0, stream>>>(m_ws, selb, hist2);
  radix_sel_kernel<<<1, 1024, 0, stream>>>(hist2, selb, 1, selb, 2);
  flag_kernel<<<N_NODES / 256, 256, 0, stream>>>(m_ws, selb, flags, cand);
  compact_kernel<<<1, 1024, 0, stream>>>(selb, cand, flags, midx, rank, out_mi);
  adj_kernel<<<E_EDGES / 256, 256, 0, stream>>>(eidx, rank, adjm, adjT);
  gather_kernel<<<K_SEL, 128, 0, stream>>>(out_hf, pos, midx, h_m, pos_m);
  qk_kernel<<<K_SEL, 128, 0, stream>>>(hs, midx, vg_Wq, vg_Wk, qbuf, kbuf);
  attn_kernel<<<dim3(K_SEL / 16, K_SEL / 16), dim3(16, 16), 0, stream>>>(
      qbuf, kbuf, maskA, maskAT, out_Av);
  listbuild_kernel<<<K_SEL, 256, 0, stream>>>(adjT, maskAT, maskA, jlist, njbuf);
  hipMemsetAsync(hWn, 0, (size_t)K_SEL * F_DIM * 4, stream);
  gemm64_f32<<<dim3(F_DIM / 64, K_SEL / 64, 4), 256, 0, stream>>>(
      h_m, DOUT_DIM, W_node_h, F_DIM, hWn, F_DIM,
      K_SEL, F_DIM, DOUT_DIM, DOUT_DIM / 4, nullptr, 0, 0);
  hier2_kernel<<<K_SEL, 256, 0, stream>>>(hWn, pos_m, W_rad_h, jlist, njbuf, updbm);
  gemm_mfma_b16<<<(DOUT_DIM / 128) * (K_SEL / 128), 256, 0, stream>>>(
      updbm, Bth, h_hier, DOUT_DIM, DOUT_DIM, DOUT_DIM / 128,
      (DOUT_DIM / 128) * (K_SEL / 128), h_m, DOUT_DIM, DOUT_DIM);
  combine_kernel<<<(N_NODES * DOUT_DIM / 4) / 256, 256, 0, stream>>>(out_hf, h_hier, m_ws, rank);
}

// Round 10
// 642.674 us; speedup vs baseline: 1.0551x; 1.0102x over previous
//
#include <hip/hip_runtime.h>
#include <hip/hip_bf16.h>
#include <stdint.h>

#define N_NODES 16384
#define E_EDGES 131072
#define F_DIM 128
#define L_DIM 9
#define R_DIM 8
#define DOUT_DIM 1152
#define K_SEL 1024
#define HID_DIM 64
#define DA_DIM 64

typedef unsigned short u16;
typedef __attribute__((ext_vector_type(8))) short bf16x8;
typedef __attribute__((ext_vector_type(4))) float f32x4;

static __device__ inline u16 f2bs(float x) {
  union { __hip_bfloat16 b; u16 s; } u;
  u.b = __float2bfloat16(x);
  return u.s;
}

// async global->LDS, 16B per lane. LDS dest must be waveBase + lane*16.
#define GLDS16(gsrc, ldst) __builtin_amdgcn_global_load_lds( \
    (__attribute__((address_space(1))) void*)(void*)(gsrc),  \
    (__attribute__((address_space(3))) void*)(ldst), 16, 0, 0)

// ================= MFMA GEMM (fallback): C = A(f32->bf16) * B^T(bf16) [+Add]
__global__ __launch_bounds__(256) void gemm_mfma(
    const float* __restrict__ A, const u16* __restrict__ Bt,
    float* __restrict__ C, int ldc, int M, int Nc, int Kc,
    const float* __restrict__ Add, int ldadd, int addW)
{
  __shared__ float Af[128 * 32];   // [m][oct ^ (m&7)]
  __shared__ u16  Bs[128 * 32];    // [n][q ^ ((n>>1)&3)]
  const int tid = threadIdx.x;
  const int wave = tid >> 6, lane = tid & 63;
  const int wm = wave >> 1, wn = wave & 1;
  const int l15 = lane & 15, quad = lane >> 4;
  const int bm = blockIdx.y * 128, bn = blockIdx.x * 128;

  f32x4 acc[4][4];
#pragma unroll
  for (int i = 0; i < 4; i++)
#pragma unroll
    for (int j = 0; j < 4; j++) acc[i][j] = (f32x4)(0.f);

  for (int k0 = 0; k0 < Kc; k0 += 32) {
    __syncthreads();
#pragma unroll
    for (int it = 0; it < 4; it++) {
      int c = it * 256 + tid;
      int row = c >> 3, op = c & 7;
      int oct = op ^ (row & 7);
      const float* g = A + (size_t)(bm + row) * Kc + k0 + oct * 4;
      GLDS16(g, &Af[c * 4]);
    }
#pragma unroll
    for (int it = 0; it < 2; it++) {
      int c = it * 256 + tid;
      int row = c >> 2, qp = c & 3;
      int q = qp ^ ((row >> 1) & 3);
      const u16* g = Bt + (size_t)(bn + row) * Kc + k0 + q * 8;
      GLDS16(g, &Bs[c * 8]);
    }
    __syncthreads();

    bf16x8 af[4], bfg[4];
#pragma unroll
    for (int mi = 0; mi < 4; mi++) {
      int m = wm * 64 + mi * 16 + l15;
      int o0 = (quad * 2) ^ (m & 7), o1 = (quad * 2 + 1) ^ (m & 7);
      float4 lo = *(const float4*)&Af[m * 32 + o0 * 4];
      float4 hi = *(const float4*)&Af[m * 32 + o1 * 4];
      bf16x8 r;
      r[0] = (short)f2bs(lo.x); r[1] = (short)f2bs(lo.y);
      r[2] = (short)f2bs(lo.z); r[3] = (short)f2bs(lo.w);
      r[4] = (short)f2bs(hi.x); r[5] = (short)f2bs(hi.y);
      r[6] = (short)f2bs(hi.z); r[7] = (short)f2bs(hi.w);
      af[mi] = r;
    }
#pragma unroll
    for (int ni = 0; ni < 4; ni++) {
      int n = wn * 64 + ni * 16 + l15;
      int q2 = quad ^ ((n >> 1) & 3);
      bfg[ni] = *(const bf16x8*)&Bs[n * 32 + q2 * 8];
    }
#pragma unroll
    for (int mi = 0; mi < 4; mi++)
#pragma unroll
      for (int ni = 0; ni < 4; ni++)
        acc[mi][ni] = __builtin_amdgcn_mfma_f32_16x16x32_bf16(af[mi], bfg[ni], acc[mi][ni], 0, 0, 0);
  }
#pragma unroll
  for (int mi = 0; mi < 4; mi++)
#pragma unroll
    for (int ni = 0; ni < 4; ni++)
#pragma unroll
      for (int r = 0; r < 4; r++) {
        int row = bm + wm * 64 + mi * 16 + quad * 4 + r;
        int col = bn + wn * 64 + ni * 16 + l15;
        float v = acc[mi][ni][r];
        if (Add != nullptr && col < addW) v += Add[(size_t)row * ldadd + col];
        C[(size_t)row * ldc + col] = v;
      }
}

// ================= MFMA GEMM, bf16 A, 128x128, double-buffered (phase-2; nwg%8==0).
__global__ __launch_bounds__(256) void gemm_mfma_b16(
    const u16* __restrict__ A, const u16* __restrict__ Bt,
    float* __restrict__ C, int ldc, int Kc, int nbx, int nwg,
    const float* __restrict__ Add, int ldadd, int addW)
{
  __shared__ u16 As[2][128 * 32];  // [buf][m][q ^ ((m>>1)&3)]
  __shared__ u16 Bs[2][128 * 32];  // [buf][n][q ^ ((n>>1)&3)]
  const int tid = threadIdx.x;
  const int wave = tid >> 6, lane = tid & 63;
  const int wm = wave >> 1, wn = wave & 1;
  const int l15 = lane & 15, quad = lane >> 4;
  const int lin = blockIdx.x;
  const int swz = (lin & 7) * (nwg >> 3) + (lin >> 3);  // XCD-chunked, bijective
  const int bm = (swz / nbx) * 128, bn = (swz % nbx) * 128;

  const int c0 = tid,      r0 = c0 >> 2, q0 = (c0 & 3) ^ ((r0 >> 1) & 3);
  const int c1 = 256 + tid, r1 = c1 >> 2, q1 = (c1 & 3) ^ ((r1 >> 1) & 3);
  const u16* gA0 = A + (size_t)(bm + r0) * Kc + q0 * 8;
  const u16* gA1 = A + (size_t)(bm + r1) * Kc + q1 * 8;
  const u16* gB0 = Bt + (size_t)(bn + r0) * Kc + q0 * 8;
  const u16* gB1 = Bt + (size_t)(bn + r1) * Kc + q1 * 8;

  f32x4 acc[4][4];
#pragma unroll
  for (int i = 0; i < 4; i++)
#pragma unroll
    for (int j = 0; j < 4; j++) acc[i][j] = (f32x4)(0.f);

#define STAGE_AB(s, k0) do {                      \
    GLDS16(gA0 + (k0), &As[s][c0 * 8]);           \
    GLDS16(gA1 + (k0), &As[s][c1 * 8]);           \
    GLDS16(gB0 + (k0), &Bs[s][c0 * 8]);           \
    GLDS16(gB1 + (k0), &Bs[s][c1 * 8]);           \
  } while (0)

  STAGE_AB(0, 0);
  __syncthreads();
  int cur = 0;
  const int nt = Kc / 32;
  for (int t = 0; t < nt; t++) {
    if (t + 1 < nt) STAGE_AB(cur ^ 1, (t + 1) * 32);
    bf16x8 af[4], bfg[4];
#pragma unroll
    for (int mi = 0; mi < 4; mi++) {
      int m = wm * 64 + mi * 16 + l15;
      af[mi] = *(const bf16x8*)&As[cur][m * 32 + (quad ^ ((m >> 1) & 3)) * 8];
    }
#pragma unroll
    for (int ni = 0; ni < 4; ni++) {
      int n = wn * 64 + ni * 16 + l15;
      bfg[ni] = *(const bf16x8*)&Bs[cur][n * 32 + (quad ^ ((n >> 1) & 3)) * 8];
    }
#pragma unroll
    for (int mi = 0; mi < 4; mi++)
#pragma unroll
      for (int ni = 0; ni < 4; ni++)
        acc[mi][ni] = __builtin_amdgcn_mfma_f32_16x16x32_bf16(af[mi], bfg[ni], acc[mi][ni], 0, 0, 0);
    __syncthreads();
    cur ^= 1;
  }
#undef STAGE_AB

#pragma unroll
  for (int mi = 0; mi < 4; mi++)
#pragma unroll
    for (int ni = 0; ni < 4; ni++)
#pragma unroll
      for (int r = 0; r < 4; r++) {
        int row = bm + wm * 64 + mi * 16 + quad * 4 + r;
        int col = bn + wn * 64 + ni * 16 + l15;
        float v = acc[mi][ni][r];
        if (Add != nullptr && col < addW) v += Add[(size_t)row * ldadd + col];
        C[(size_t)row * ldc + col] = v;
      }
}

// ================= MFMA GEMM, bf16 A, 256x128 tile, 8 waves, double-buffered.
// 2x MFMA per staged tile vs 128^2 -> better latency hiding at same structure.
// 1D grid with XCD-chunked swizzle (nwg % 8 == 0).
__global__ __launch_bounds__(512) void gemm_mfma_b16_256(
    const u16* __restrict__ A, const u16* __restrict__ Bt,
    float* __restrict__ C, int ldc, int Kc, int nbx, int nwg,
    const float* __restrict__ Add, int ldadd, int addW)
{
  __shared__ u16 As[2][256 * 32];  // [buf][m][q ^ ((m>>1)&3)]  16 KB/buf
  __shared__ u16 Bs[2][128 * 32];  // [buf][n][q ^ ((n>>1)&3)]   8 KB/buf
  const int tid = threadIdx.x;
  const int wave = tid >> 6, lane = tid & 63;
  const int wm = wave >> 1, wn = wave & 1;      // wm 0..3 (256 rows), wn 0..1 (128 cols)
  const int l15 = lane & 15, quad = lane >> 4;
  const int lin = blockIdx.x;
  const int swz = (lin & 7) * (nwg >> 3) + (lin >> 3);  // XCD-chunked, bijective
  const int bm = (swz / nbx) * 256, bn = (swz % nbx) * 128;

  // A: 1024 16B-chunks, 2 per thread; B: 512 chunks, 1 per thread.
  const int ca0 = tid,       ra0 = ca0 >> 2, qa0 = (ca0 & 3) ^ ((ra0 >> 1) & 3);
  const int ca1 = 512 + tid, ra1 = ca1 >> 2, qa1 = (ca1 & 3) ^ ((ra1 >> 1) & 3);
  const int cb0 = tid,       rb0 = cb0 >> 2, qb0 = (cb0 & 3) ^ ((rb0 >> 1) & 3);
  const u16* gA0 = A + (size_t)(bm + ra0) * Kc + qa0 * 8;
  const u16* gA1 = A + (size_t)(bm + ra1) * Kc + qa1 * 8;
  const u16* gB0 = Bt + (size_t)(bn + rb0) * Kc + qb0 * 8;

  f32x4 acc[4][4];
#pragma unroll
  for (int i = 0; i < 4; i++)
#pragma unroll
    for (int j = 0; j < 4; j++) acc[i][j] = (f32x4)(0.f);

#define STAGE_AB(s, k0) do {                      \
    GLDS16(gA0 + (k0), &As[s][ca0 * 8]);          \
    GLDS16(gA1 + (k0), &As[s][ca1 * 8]);          \
    GLDS16(gB0 + (k0), &Bs[s][cb0 * 8]);          \
  } while (0)

  STAGE_AB(0, 0);
  __syncthreads();
  int cur = 0;
  const int nt = Kc / 32;
  for (int t = 0; t < nt; t++) {
    if (t + 1 < nt) STAGE_AB(cur ^ 1, (t + 1) * 32);
    bf16x8 af[4], bfg[4];
#pragma unroll
    for (int mi = 0; mi < 4; mi++) {
      int m = wm * 64 + mi * 16 + l15;
      af[mi] = *(const bf16x8*)&As[cur][m * 32 + (quad ^ ((m >> 1) & 3)) * 8];
    }
#pragma unroll
    for (int ni = 0; ni < 4; ni++) {
      int n = wn * 64 + ni * 16 + l15;
      bfg[ni] = *(const bf16x8*)&Bs[cur][n * 32 + (quad ^ ((n >> 1) & 3)) * 8];
    }
#pragma unroll
    for (int mi = 0; mi < 4; mi++)
#pragma unroll
      for (int ni = 0; ni < 4; ni++)
        acc[mi][ni] = __builtin_amdgcn_mfma_f32_16x16x32_bf16(af[mi], bfg[ni], acc[mi][ni], 0, 0, 0);
    __syncthreads();
    cur ^= 1;
  }
#undef STAGE_AB

#pragma unroll
  for (int mi = 0; mi < 4; mi++)
#pragma unroll
    for (int ni = 0; ni < 4; ni++)
#pragma unroll
      for (int r = 0; r < 4; r++) {
        int row = bm + wm * 64 + mi * 16 + quad * 4 + r;
        int col = bn + wn * 64 + ni * 16 + l15;
        float v = acc[mi][ni][r];
        if (Add != nullptr && col < addW) v += Add[(size_t)row * ldadd + col];
        C[(size_t)row * ldc + col] = v;
      }
}

// ================= transpose + bf16 cast
__global__ __launch_bounds__(256) void transpose_bf16(
    const float* __restrict__ W, u16* __restrict__ Bt, int K, int N)
{
  __shared__ float t[32][33];
  const int n0 = blockIdx.x * 32, k0 = blockIdx.y * 32;
  const int tx = threadIdx.x & 31, ty = threadIdx.x >> 5;
  for (int r = ty; r < 32; r += 8) t[r][tx] = W[(size_t)(k0 + r) * N + n0 + tx];
  __syncthreads();
  for (int r = ty; r < 32; r += 8) Bt[(size_t)(n0 + r) * K + k0 + tx] = f2bs(t[tx][r]);
}

// ================= hs GEMM: psum[z] = upd[:, z*288:(z+1)*288] @ W_prod_l[z-chunk, :128]
__global__ __launch_bounds__(256) void hs_gemm_kernel(
    const float* __restrict__ A,      // upd, lda = DOUT_DIM
    const float* __restrict__ B,      // W_prod_l, ldb = DOUT_DIM (cols 0..127)
    float* __restrict__ psum)         // [4][N_NODES][F_DIM]
{
  __shared__ float As[16][129];
  __shared__ float Bs[16][128];
  const int tid = threadIdx.x;
  const int tx = tid & 15, ty = tid >> 4;
  const int bm = blockIdx.x * 128;
  const int z = blockIdx.y;
  const int kb = z * (DOUT_DIM / 4);
  const int ke = kb + DOUT_DIM / 4;
  const int ac = tid & 15, ar0 = tid >> 4;
  const int bc = tid & 127, br0 = tid >> 7;
  float acc[8][8];
#pragma unroll
  for (int i = 0; i < 8; i++)
#pragma unroll
    for (int j = 0; j < 8; j++) acc[i][j] = 0.f;

  float ra[8], rb[8];
#define LOADREG(k0) do {                                                       \
    _Pragma("unroll")                                                          \
    for (int rr = 0; rr < 8; rr++)                                             \
      ra[rr] = A[(size_t)(bm + ar0 + rr * 16) * DOUT_DIM + (k0) + ac];         \
    _Pragma("unroll")                                                          \
    for (int rr = 0; rr < 8; rr++)                                             \
      rb[rr] = B[(size_t)((k0) + br0 + rr * 2) * DOUT_DIM + bc];               \
  } while (0)

  LOADREG(kb);
  for (int k0 = kb; k0 < ke; k0 += 16) {
#pragma unroll
    for (int rr = 0; rr < 8; rr++) As[ac][ar0 + rr * 16] = ra[rr];
#pragma unroll
    for (int rr = 0; rr < 8; rr++) Bs[br0 + rr * 2][bc] = rb[rr];
    __syncthreads();
    if (k0 + 16 < ke) LOADREG(k0 + 16);
#pragma unroll
    for (int kk = 0; kk < 16; kk++) {
      float a[8], b[8];
#pragma unroll
      for (int i = 0; i < 8; i++) a[i] = As[kk][ty * 8 + i];
#pragma unroll
      for (int j = 0; j < 8; j++) b[j] = Bs[kk][tx * 8 + j];
#pragma unroll
      for (int i = 0; i < 8; i++)
#pragma unroll
        for (int j = 0; j < 8; j++) acc[i][j] = fmaf(a[i], b[j], acc[i][j]);
    }
    __syncthreads();
  }
#undef LOADREG
#pragma unroll
  for (int i = 0; i < 8; i++) {
    size_t row = (size_t)z * N_NODES + bm + ty * 8 + i;
#pragma unroll
    for (int j = 0; j < 8; j++)
      psum[row * F_DIM + tx * 8 + j] = acc[i][j];
  }
}

// hs = psum[0]+psum[1]+psum[2]+psum[3] + h   (float4)
__global__ __launch_bounds__(256) void hs_reduce_kernel(
    const float* __restrict__ psum, const float* __restrict__ h, float* __restrict__ hs)
{
  size_t i4 = (size_t)blockIdx.x * 256 + threadIdx.x;
  const size_t stride = (size_t)N_NODES * F_DIM / 4;
  const float4* p = (const float4*)psum;
  float4 a = p[i4], b = p[i4 + stride], c = p[i4 + 2 * stride], d = p[i4 + 3 * stride];
  float4 hh = ((const float4*)h)[i4];
  float4 o;
  o.x = a.x + b.x + c.x + d.x + hh.x;
  o.y = a.y + b.y + c.y + d.y + hh.y;
  o.z = a.z + b.z + c.z + d.z + hh.z;
  o.w = a.w + b.w + c.w + d.w + hh.w;
  ((float4*)hs)[i4] = o;
}

// ================= fp32 GEMM 64x64, optional split-K
__global__ __launch_bounds__(256) void gemm64_f32(
    const float* __restrict__ A, int lda,
    const float* __restrict__ B, int ldb,
    float* __restrict__ C, int ldc,
    int M, int Nc, int Kc, int kPerSplit,
    const float* __restrict__ Add, int ldadd, int addW)
{
  __shared__ float As[16][65];
  __shared__ float Bs[16][64];
  const int tid = threadIdx.x;
  const int tx = tid & 15, ty = tid >> 4;
  const int bm = blockIdx.y * 64, bn = blockIdx.x * 64;
  const int kb = blockIdx.z * kPerSplit;
  const int ke = min(kb + kPerSplit, Kc);
  float acc[4][4];
#pragma unroll
  for (int i = 0; i < 4; i++)
#pragma unroll
    for (int j = 0; j < 4; j++) acc[i][j] = 0.f;
  for (int k0 = kb; k0 < ke; k0 += 16) {
    const int ac = tid & 15, ar = tid >> 4;
#pragma unroll
    for (int rr = 0; rr < 4; rr++) {
      int row = ar + rr * 16;
      As[ac][row] = A[(size_t)(bm + row) * lda + k0 + ac];
    }
    const int bc = tid & 63, br = tid >> 6;
#pragma unroll
    for (int rr = 0; rr < 4; rr++) {
      int kr = br + rr * 4;
      Bs[kr][bc] = B[(size_t)(k0 + kr) * ldb + bn + bc];
    }
    __syncthreads();
#pragma unroll
    for (int kk = 0; kk < 16; kk++) {
      float a[4], b[4];
#pragma unroll
      for (int i = 0; i < 4; i++) a[i] = As[kk][ty * 4 + i];
#pragma unroll
      for (int j = 0; j < 4; j++) b[j] = Bs[kk][tx * 4 + j];
#pragma unroll
      for (int i = 0; i < 4; i++)
#pragma unroll
        for (int j = 0; j < 4; j++) acc[i][j] = fmaf(a[i], b[j], acc[i][j]);
    }
    __syncthreads();
  }
#pragma unroll
  for (int i = 0; i < 4; i++) {
    int row = bm + ty * 4 + i;
#pragma unroll
    for (int j = 0; j < 4; j++) {
      int col = bn + tx * 4 + j;
      if (gridDim.z > 1) {
        atomicAdd(&C[(size_t)row * ldc + col], acc[i][j]);
      } else {
        float v = acc[i][j];
        if (Add != nullptr && col < addW) v += Add[(size_t)row * ldadd + col];
        C[(size_t)row * ldc + col] = v;
      }
    }
  }
}

// ================= CSR build: count / scan / fill
__global__ __launch_bounds__(256) void count_kernel(
    const int* __restrict__ ei, int* __restrict__ counts)
{
  int e = blockIdx.x * 256 + threadIdx.x;
  atomicAdd(&counts[ei[E_EDGES + e]], 1);
}

__global__ __launch_bounds__(1024) void scan_kernel(
    const int* __restrict__ counts, int* __restrict__ offsets, int* __restrict__ cursor)
{
  __shared__ int part[1024];
  const int t = threadIdx.x;
  const int base = t * 16;
  int loc[16];
  int s = 0;
#pragma unroll
  for (int k = 0; k < 16; k++) { loc[k] = counts[base + k]; s += loc[k]; }
  part[t] = s;
  __syncthreads();
  for (int d = 1; d < 1024; d <<= 1) {
    int v = (t >= d) ? part[t - d] : 0;
    __syncthreads();
    part[t] += v;
    __syncthreads();
  }
  int run = part[t] - s;  // exclusive prefix
#pragma unroll
  for (int k = 0; k < 16; k++) {
    offsets[base + k] = run;
    cursor[base + k] = run;
    run += loc[k];
  }
}

__global__ __launch_bounds__(256) void fill_kernel(
    const int* __restrict__ ei, int* __restrict__ cursor, int* __restrict__ elist)
{
  int e = blockIdx.x * 256 + threadIdx.x;
  int d = ei[E_EDGES + e];
  int p = atomicAdd(&cursor[d], 1);
  elist[p] = e;
}

// ================= atomic-free edge accumulation: block per dst node.
__global__ __launch_bounds__(128) void gather_accum_kernel(
    const float* __restrict__ hW, const float* __restrict__ edge_sh,
    const float* __restrict__ edge_feats, const float* __restrict__ W_rad_l,
    const int* __restrict__ ei, const int* __restrict__ offsets,
    const int* __restrict__ counts, const int* __restrict__ elist,
    float* __restrict__ upd, u16* __restrict__ updb)
{
  const int d = blockIdx.x, f = threadIdx.x;
  const float w0 = W_rad_l[0 * F_DIM + f], w1 = W_rad_l[1 * F_DIM + f];
  const float w2 = W_rad_l[2 * F_DIM + f], w3 = W_rad_l[3 * F_DIM + f];
  const float w4 = W_rad_l[4 * F_DIM + f], w5 = W_rad_l[5 * F_DIM + f];
  const float w6 = W_rad_l[6 * F_DIM + f], w7 = W_rad_l[7 * F_DIM + f];
  const int b = offsets[d], n = counts[d];
  float acc[L_DIM];
#pragma unroll
  for (int l = 0; l < L_DIM; l++) acc[l] = 0.f;
  for (int k = 0; k < n; k++) {
    const int e = elist[b + k];
    const int s = ei[e];
    const float4 ef0 = *(const float4*)&edge_feats[(size_t)e * R_DIM];
    const float4 ef1 = *(const float4*)&edge_feats[(size_t)e * R_DIM + 4];
    float rw = ef0.x * w0;
    rw = fmaf(ef0.y, w1, rw); rw = fmaf(ef0.z, w2, rw); rw = fmaf(ef0.w, w3, rw);
    rw = fmaf(ef1.x, w4, rw); rw = fmaf(ef1.y, w5, rw);
    rw = fmaf(ef1.z, w6, rw); rw = fmaf(ef1.w, w7, rw);
    const float tf = hW[(size_t)s * F_DIM + f] * rw;
#pragma unroll
    for (int l = 0; l < L_DIM; l++)
      acc[l] = fmaf(edge_sh[(size_t)e * L_DIM + l], tf, acc[l]);
  }
#pragma unroll
  for (int l = 0; l < L_DIM; l++)
    upd[(size_t)d * DOUT_DIM + l * F_DIM + f] = acc[l];
  if (updb != nullptr) {
#pragma unroll
    for (int l = 0; l < L_DIM; l++)
      updb[(size_t)d * DOUT_DIM + l * F_DIM + f] = f2bs(acc[l]);
  }
}

// ================= gating MLP on hs (fp32, ld=F_DIM) + fused 16-bit histogram
__global__ __launch_bounds__(256) void gate_kernel(
    const float* __restrict__ hs, const float* __restrict__ W1,
    const float* __restrict__ b1, const float* __restrict__ W2,
    const float* __restrict__ b2, float* __restrict__ m_ws, float* __restrict__ m_out,
    int* __restrict__ hist1)
{
  __shared__ float sW1[F_DIM * HID_DIM];
  __shared__ float srow[4][F_DIM];
  const int tid = threadIdx.x;
  for (int t = tid; t < F_DIM * HID_DIM; t += 256) sW1[t] = W1[t];
  const int wave = tid >> 6, lane = tid & 63;
  const int n = blockIdx.x * 4 + wave;
  srow[wave][lane] = hs[(size_t)n * F_DIM + lane];
  srow[wave][lane + 64] = hs[(size_t)n * F_DIM + lane + 64];
  __syncthreads();
  float hid = b1[lane];
#pragma unroll 8
  for (int c = 0; c < F_DIM; c++) hid = fmaf(srow[wave][c], sW1[c * HID_DIM + lane], hid);
  hid = fmaxf(hid, 0.f);
  float v = hid * W2[lane];
#pragma unroll
  for (int off = 32; off > 0; off >>= 1) v += __shfl_down(v, off);
  if (lane == 0) {
    float mm = 1.f / (1.f + expf(-(v + b2[0])));
    m_ws[n] = mm;
    m_out[n] = mm;
    unsigned mb = __float_as_uint(mm);
    atomicAdd(&hist1[mb >> 16], 1);
  }
}

// ================= radix top-K selection
__global__ __launch_bounds__(1024) void radix_sel_kernel(
    const int* __restrict__ hist, const int* __restrict__ kin, int kinIdx,
    int* __restrict__ outp, int outIdx)
{
  __shared__ int part[1024];
  const int t = threadIdx.x;
  const int Kv = kin ? kin[kinIdx] : K_SEL;
  const int base = t * 64;
  int s = 0;
  for (int k = 0; k < 64; k++) s += hist[base + k];
  part[t] = s;
  __syncthreads();
  for (int d = 1; d < 1024; d <<= 1) {
    int v = (t + d < 1024) ? part[t + d] : 0;
    __syncthreads();
    part[t] += v;
    __syncthreads();
  }
  int inc = part[t];
  if (inc >= Kv && inc - s < Kv) {
    int r = inc - s;
    for (int b = base + 63; b >= base; b--) {
      int hv = hist[b];
      if (r + hv >= Kv) { outp[outIdx] = b; outp[outIdx + 1] = Kv - r; break; }
      r += hv;
    }
  }
}

__global__ __launch_bounds__(256) void hist2_kernel(
    const float* __restrict__ m_ws, const int* __restrict__ selb, int* __restrict__ hist2)
{
  int i = blockIdx.x * 256 + threadIdx.x;
  unsigned mb = __float_as_uint(m_ws[i]);
  if ((int)(mb >> 16) == selb[0]) atomicAdd(&hist2[mb & 0xFFFFu], 1);
}

__global__ __launch_bounds__(256) void flag_kernel(
    const float* __restrict__ m_ws, int* __restrict__ selb,
    unsigned char* __restrict__ flags, int* __restrict__ cand)
{
  int i = blockIdx.x * 256 + threadIdx.x;
  unsigned mb = __float_as_uint(m_ws[i]);
  unsigned vb = ((unsigned)selb[0] << 16) | (unsigned)selb[2];
  unsigned char fl = 0;
  if (mb > vb) fl = 1;
  else if (mb == vb) { int p = atomicAdd(&selb[4], 1); cand[p] = i; }
  flags[i] = fl;
}

// fused: tie-break (pick selb[3] smallest candidate indices) + prefix-scan compaction
__global__ __launch_bounds__(1024) void compact_kernel(
    const int* __restrict__ selb, const int* __restrict__ cand,
    unsigned char* flags, int* __restrict__ midx,
    int* __restrict__ rank, float* __restrict__ mi_out)
{
  __shared__ int part[1024];
  const int t = threadIdx.x;
  const int nc = selb[4], need = selb[3];
  for (int c = t; c < nc; c += 1024) {
    const int idx = cand[c];
    int r = 0;
    for (int o = 0; o < nc; o++) r += (cand[o] < idx) ? 1 : 0;
    if (r < need) flags[idx] = 1;
  }
  __syncthreads();
  const int base = t * 16;
  int loc[16];
  int s = 0;
#pragma unroll
  for (int k = 0; k < 16; k++) { loc[k] = flags[base + k]; s += loc[k]; }
  part[t] = s;
  __syncthreads();
  for (int d = 1; d < 1024; d <<= 1) {
    int v = (t >= d) ? part[t - d] : 0;
    __syncthreads();
    part[t] += v;
    __syncthreads();
  }
  int run = part[t] - s;
#pragma unroll
  for (int k = 0; k < 16; k++) {
    int i = base + k;
    if (loc[k]) {
      midx[run] = i;
      mi_out[run] = (float)i;
      rank[i] = run;
      run++;
    } else {
      rank[i] = K_SEL;
    }
  }
}

// ================= induced adjacency (+ transposed copy for coalesced listbuild)
__global__ __launch_bounds__(256) void adj_kernel(
    const int* __restrict__ ei, const int* __restrict__ rank,
    unsigned char* __restrict__ adjm, unsigned char* __restrict__ adjT)
{
  int e = blockIdx.x * 256 + threadIdx.x;
  int rs = rank[ei[e]];
  int rd = rank[ei[E_EDGES + e]];
  if (rs < K_SEL && rd < K_SEL) {
    adjm[(size_t)rs * K_SEL + rd] = 1;
    adjT[(size_t)rd * K_SEL + rs] = 1;
  }
}

// ================= gather master rows + positions (float4)
__global__ __launch_bounds__(128) void gather_kernel(
    const float* __restrict__ hl, const float* __restrict__ pos,
    const int* __restrict__ midx, float* __restrict__ h_m, float* __restrict__ pos_m)
{
  const int rI = blockIdx.x, t = threadIdx.x;
  const int mi = midx[rI];
  const float4* src = (const float4*)(hl + (size_t)mi * DOUT_DIM);
  float4* dst = (float4*)(h_m + (size_t)rI * DOUT_DIM);
  for (int c = t; c < DOUT_DIM / 4; c += 128) dst[c] = src[c];
  if (t < 3) pos_m[rI * 3 + t] = pos[mi * 3 + t];
}

// ================= q/k projections from hs at master rows
__global__ __launch_bounds__(128) void qk_kernel(
    const float* __restrict__ hs, const int* __restrict__ midx,
    const float* __restrict__ Wq, const float* __restrict__ Wk,
    float* __restrict__ q, float* __restrict__ kk)
{
  __shared__ float row[F_DIM];
  const int i = blockIdx.x, t = threadIdx.x;
  const int mi = midx[i];
  row[t] = hs[(size_t)mi * F_DIM + t];
  __syncthreads();
  const int d = t & 63;
  const float* W = (t < 64) ? Wq : Wk;
  float acc = 0.f;
#pragma unroll 8
  for (int c = 0; c < F_DIM; c++) acc = fmaf(row[c], W[c * DA_DIM + d], acc);
  float* dst = (t < 64) ? q : kk;
  dst[(size_t)i * DA_DIM + d] = acc;
}

// ================= attention (padded LDS; also emits transposed mask)
__global__ __launch_bounds__(256) void attn_kernel(
    const float* __restrict__ q, const float* __restrict__ kk,
    unsigned char* __restrict__ maskA, unsigned char* __restrict__ maskAT,
    float* __restrict__ Av)
{
  __shared__ float qs[16][DA_DIM + 1], ks[16][DA_DIM + 1];
  const int tx = threadIdx.x, ty = threadIdx.y;
  const int tid = ty * 16 + tx;
  const int i0 = blockIdx.y * 16, j0 = blockIdx.x * 16;
  for (int t = tid; t < 16 * DA_DIM; t += 256) {
    int rr = t >> 6, cc = t & 63;
    qs[rr][cc] = q[(size_t)(i0 + rr) * DA_DIM + cc];
    ks[rr][cc] = kk[(size_t)(j0 + rr) * DA_DIM + cc];
  }
  __syncthreads();
  float acc = 0.f;
#pragma unroll
  for (int d2 = 0; d2 < DA_DIM; d2++) acc = fmaf(qs[ty][d2], ks[tx][d2], acc);
  float sgl = 1.f / (1.f + expf(-acc * 0.125f));
  size_t o = (size_t)(i0 + ty) * K_SEL + (j0 + tx);
  bool big = sgl > 0.5f;
  unsigned char bb = big ? 1 : 0;
  maskA[o] = bb;
  maskAT[(size_t)(j0 + tx) * K_SEL + (i0 + ty)] = bb;
  Av[o] = big ? sgl : 0.f;
}

// ================= per-i active-j list (coalesced row reads + wave-ballot)
__global__ __launch_bounds__(256) void listbuild_kernel(
    const unsigned char* __restrict__ adjT, const unsigned char* __restrict__ maskAT,
    const unsigned char* __restrict__ maskA, u16* __restrict__ list, int* __restrict__ nj)
{
  __shared__ int cnt;
  const int i = blockIdx.x, tid = threadIdx.x;
  const int lane = tid & 63;
  if (tid == 0) cnt = 0;
  __syncthreads();
  const int j0 = tid * 4;
  uchar4 a  = *(const uchar4*)&adjT  [(size_t)i * K_SEL + j0];
  uchar4 mt = *(const uchar4*)&maskAT[(size_t)i * K_SEL + j0];
  uchar4 ma = *(const uchar4*)&maskA [(size_t)i * K_SEL + j0];
  unsigned char av[4];
  av[0] = a.x | mt.x | ma.x; av[1] = a.y | mt.y | ma.y;
  av[2] = a.z | mt.z | ma.z; av[3] = a.w | mt.w | ma.w;
#pragma unroll
  for (int r = 0; r < 4; r++) {
    int j = j0 + r;
    bool e = (j != i) && av[r];
    unsigned long long m = __ballot(e);
    int nset = __popcll(m);
    int base = 0;
    if (lane == 0 && nset) base = atomicAdd(&cnt, nset);
    base = __shfl(base, 0);
    if (e) {
      int p = base + __popcll(m & ((1ull << lane) - 1ull));
      list[(size_t)i * K_SEL + p] = (u16)j;
    }
  }
  __syncthreads();
  if (tid == 0) nj[i] = cnt;
}

// ================= hier v6: 2 f per lane — 256 threads = 4 jsub x 64 lanes,
// lane covers f=lane and f=lane+64. Geometry LDS reads amortized over 2 f.
__global__ __launch_bounds__(256) void hier2_kernel(
    const float* __restrict__ hWn, const float* __restrict__ pos_m,
    const float* __restrict__ W_rad_h, const u16* __restrict__ list,
    const int* __restrict__ nj, u16* __restrict__ updb_m)
{
  __shared__ float gsm[128][20];   // [pair][rd0..7, sh0..8, jbits, pad, pad]
  __shared__ float red[3][L_DIM][F_DIM];
  const int tid = threadIdx.x;
  const int i = blockIdx.x;
  const int lane = tid & 63, jsub = tid >> 6;
  const int f0 = lane, f1 = lane + 64;
  const float a0 = W_rad_h[0 * F_DIM + f0], a1 = W_rad_h[1 * F_DIM + f0];
  const float a2 = W_rad_h[2 * F_DIM + f0], a3 = W_rad_h[3 * F_DIM + f0];
  const float a4 = W_rad_h[4 * F_DIM + f0], a5 = W_rad_h[5 * F_DIM + f0];
  const float a6 = W_rad_h[6 * F_DIM + f0], a7 = W_rad_h[7 * F_DIM + f0];
  const float b0 = W_rad_h[0 * F_DIM + f1], b1 = W_rad_h[1 * F_DIM + f1];
  const float b2 = W_rad_h[2 * F_DIM + f1], b3 = W_rad_h[3 * F_DIM + f1];
  const float b4 = W_rad_h[4 * F_DIM + f1], b5 = W_rad_h[5 * F_DIM + f1];
  const float b6 = W_rad_h[6 * F_DIM + f1], b7 = W_rad_h[7 * F_DIM + f1];
  const float pix = pos_m[i * 3 + 0], piy = pos_m[i * 3 + 1], piz = pos_m[i * 3 + 2];
  float acc0[L_DIM], acc1[L_DIM];
#pragma unroll
  for (int l = 0; l < L_DIM; l++) { acc0[l] = 0.f; acc1[l] = 0.f; }
  const int n = nj[i];
  for (int c0 = 0; c0 < n; c0 += 128) {
    const int cnt = min(128, n - c0);
    __syncthreads();
    if (tid < cnt) {
      const int j = list[(size_t)i * K_SEL + c0 + tid];
      float vx = pos_m[j * 3 + 0] - pix;
      float vy = pos_m[j * 3 + 1] - piy;
      float vz = pos_m[j * 3 + 2] - piz;
      float r = sqrtf(vx * vx + vy * vy + vz * vz);
      float rm = fmaxf(r, 1e-9f);
      float inv = 1.f / rm;
      float ux = vx * inv, uy = vy * inv, uz = vz * inv;
      float theta = 0.62831853071795864769f * r;  // pi/R_CUT
      float s1 = sinf(theta), c1 = cosf(theta);
      float coef = 0.632455532033675866f * inv;   // sqrt(2/R_CUT)/max(r,eps)
      float snm2 = 0.f, snm1 = s1;
      gsm[tid][0] = s1 * coef;
#pragma unroll
      for (int nn = 2; nn <= R_DIM; nn++) {
        float sn = 2.f * c1 * snm1 - snm2;
        gsm[tid][nn - 1] = sn * coef;
        snm2 = snm1; snm1 = sn;
      }
      gsm[tid][8] = 1.f; gsm[tid][9] = ux; gsm[tid][10] = uy; gsm[tid][11] = uz;
      gsm[tid][12] = ux * uy; gsm[tid][13] = uy * uz;
      gsm[tid][14] = 3.f * uz * uz - 1.f;
      gsm[tid][15] = ux * uz; gsm[tid][16] = ux * ux - uy * uy;
      gsm[tid][17] = __int_as_float(j);
      gsm[tid][18] = 0.f; gsm[tid][19] = 0.f;
    }
    __syncthreads();
    for (int t = jsub; t < cnt; t += 4) {
      float2 s2 = *(const float2*)&gsm[t][16];   // sh8, jbits
      const int j = __float_as_int(s2.y);
      const float hw0 = hWn[(size_t)j * F_DIM + f0];
      const float hw1 = hWn[(size_t)j * F_DIM + f1];
      float4 r0 = *(const float4*)&gsm[t][0];    // rd0..3
      float4 r1 = *(const float4*)&gsm[t][4];    // rd4..7
      float4 s0 = *(const float4*)&gsm[t][8];    // sh0..3
      float4 s1g = *(const float4*)&gsm[t][12];  // sh4..7
      float rwa = r0.x * a0;
      rwa = fmaf(r0.y, a1, rwa); rwa = fmaf(r0.z, a2, rwa); rwa = fmaf(r0.w, a3, rwa);
      rwa = fmaf(r1.x, a4, rwa); rwa = fmaf(r1.y, a5, rwa);
      rwa = fmaf(r1.z, a6, rwa); rwa = fmaf(r1.w, a7, rwa);
      float rwb = r0.x * b0;
      rwb = fmaf(r0.y, b1, rwb); rwb = fmaf(r0.z, b2, rwb); rwb = fmaf(r0.w, b3, rwb);
      rwb = fmaf(r1.x, b4, rwb); rwb = fmaf(r1.y, b5, rwb);
      rwb = fmaf(r1.z, b6, rwb); rwb = fmaf(r1.w, b7, rwb);
      const float tm0 = hw0 * rwa;
      const float tm1 = hw1 * rwb;
      acc0[0] = fmaf(s0.x, tm0, acc0[0]); acc1[0] = fmaf(s0.x, tm1, acc1[0]);
      acc0[1] = fmaf(s0.y, tm0, acc0[1]); acc1[1] = fmaf(s0.y, tm1, acc1[1]);
      acc0[2] = fmaf(s0.z, tm0, acc0[2]); acc1[2] = fmaf(s0.z, tm1, acc1[2]);
      acc0[3] = fmaf(s0.w, tm0, acc0[3]); acc1[3] = fmaf(s0.w, tm1, acc1[3]);
      acc0[4] = fmaf(s1g.x, tm0, acc0[4]); acc1[4] = fmaf(s1g.x, tm1, acc1[4]);
      acc0[5] = fmaf(s1g.y, tm0, acc0[5]); acc1[5] = fmaf(s1g.y, tm1, acc1[5]);
      acc0[6] = fmaf(s1g.z, tm0, acc0[6]); acc1[6] = fmaf(s1g.z, tm1, acc1[6]);
      acc0[7] = fmaf(s1g.w, tm0, acc0[7]); acc1[7] = fmaf(s1g.w, tm1, acc1[7]);
      acc0[8] = fmaf(s2.x, tm0, acc0[8]); acc1[8] = fmaf(s2.x, tm1, acc1[8]);
    }
  }
  __syncthreads();
  if (jsub > 0) {
#pragma unroll
    for (int l = 0; l < L_DIM; l++) {
      red[jsub - 1][l][f0] = acc0[l];
      red[jsub - 1][l][f1] = acc1[l];
    }
  }
  __syncthreads();
  if (jsub == 0) {
#pragma unroll
    for (int l = 0; l < L_DIM; l++) {
      float v0 = acc0[l] + red[0][l][f0] + red[1][l][f0] + red[2][l][f0];
      float v1 = acc1[l] + red[0][l][f1] + red[1][l][f1] + red[2][l][f1];
      updb_m[(size_t)i * DOUT_DIM + l * F_DIM + f0] = f2bs(v0);
      updb_m[(size_t)i * DOUT_DIM + l * F_DIM + f1] = f2bs(v1);
    }
  }
}

// ================= final blend (float4; 1152 % 4 == 0, vector never spans rows)
__global__ __launch_bounds__(256) void combine_kernel(
    float* __restrict__ out0, const float* __restrict__ h_hier,
    const float* __restrict__ m_ws, const int* __restrict__ rank)
{
  size_t i4 = (size_t)blockIdx.x * 256 + threadIdx.x;
  int n = (int)(i4 / (DOUT_DIM / 4));
  int g4 = (int)(i4 % (DOUT_DIM / 4));
  float mv = m_ws[n];
  int r = rank[n];
  float4 hl = ((const float4*)out0)[i4];
  float4 he = make_float4(0.f, 0.f, 0.f, 0.f);
  if (r < K_SEL) he = ((const float4*)h_hier)[(size_t)r * (DOUT_DIM / 4) + g4];
  float4 o;
  o.x = (1.f - mv) * hl.x + mv * he.x;
  o.y = (1.f - mv) * hl.y + mv * he.y;
  o.z = (1.f - mv) * hl.z + mv * he.z;
  o.w = (1.f - mv) * hl.w + mv * he.w;
  ((float4*)out0)[i4] = o;
}

extern "C" void kernel_launch(void* const* d_in, const int* in_sizes, int n_in,
                              void* d_out, int out_size, void* d_ws, size_t ws_size,
                              hipStream_t stream)
{
  const float* h         = (const float*)d_in[0];
  const float* pos       = (const float*)d_in[1];
  const float* edge_sh   = (const float*)d_in[2];
  const float* edge_feats= (const float*)d_in[3];
  const float* W_node_l  = (const float*)d_in[4];
  const float* W_rad_l   = (const float*)d_in[5];
  const float* W_prod_l  = (const float*)d_in[6];
  const float* ms_W1     = (const float*)d_in[7];
  const float* ms_b1     = (const float*)d_in[8];
  const float* ms_W2     = (const float*)d_in[9];
  const float* ms_b2     = (const float*)d_in[10];
  const float* vg_Wq     = (const float*)d_in[11];
  const float* vg_Wk     = (const float*)d_in[12];
  const float* W_node_h  = (const float*)d_in[13];
  const float* W_rad_h   = (const float*)d_in[14];
  const float* W_prod_h  = (const float*)d_in[15];
  const int*   eidx      = (const int*)d_in[16];

  float* out    = (float*)d_out;
  float* out_hf = out;
  float* out_Av = out + (size_t)N_NODES * DOUT_DIM;
  float* out_m  = out_Av + (size_t)K_SEL * K_SEL;
  float* out_mi = out_m + N_NODES;

  char* ws = (char*)d_ws;
  // Phase 1: upd [0, 75.5MB); hW/hs [75.5, 83.9MB); optional updb [83.9, 121.6MB).
  float* upd = (float*)ws;
  float* hW  = (float*)(ws + (size_t)N_NODES * DOUT_DIM * 4);
  float* hs  = hW;  // hW dead after gather_accum; hs written after
  const size_t updbOff = (size_t)N_NODES * DOUT_DIM * 4 + (size_t)N_NODES * F_DIM * 4;
  const size_t updbNeed = updbOff + (size_t)N_NODES * DOUT_DIM * 2;
  const bool useB16 = (ws_size >= updbNeed);
  u16* updb = (u16*)(ws + updbOff);
  // hs split-K partials borrow out_hf (75.5MB, dead until gemm_mfma_b16 writes it).
  float* psum = out_hf;   // 4 * 16384 * 128 * 4B = 33.6 MB < 75.5 MB
  // Btl + CSR borrow the A_virtual out region (4MB, dead until attn writes it).
  u16* Btl = (u16*)out_Av;                                       // 2.65 MB
  char* csr = (char*)out_Av + (((size_t)DOUT_DIM * DOUT_DIM * 2 + 255) & ~(size_t)255);
  int* counts  = (int*)csr;                                      // 64 KB
  int* offsets = counts + N_NODES;                               // 64 KB
  int* cursor  = offsets + N_NODES;                              // 64 KB
  int* elist   = cursor + N_NODES;                               // 512 KB  (total 3.4MB < 4MB)
  // Phase 2 small pool aliases dead upd.
  size_t off = 0;
  auto alloc = [&](size_t bytes) -> void* {
    void* p = ws + off;
    off += (bytes + 255) & ~(size_t)255;
    return p;
  };
  float* m_ws  = (float*)alloc((size_t)N_NODES * 4);
  int*   rank  = (int*)alloc((size_t)N_NODES * 4);
  int*   midx  = (int*)alloc((size_t)K_SEL * 4);
  int*   hist1 = (int*)alloc((size_t)65536 * 4);
  int*   hist2 = (int*)alloc((size_t)65536 * 4);
  int*   selb  = (int*)alloc((size_t)64 * 4);   // [0]=b1 [1]=need1 [2]=b2 [3]=need2 [4]=ncand
  int*   cand  = (int*)alloc((size_t)N_NODES * 4);
  unsigned char* flags = (unsigned char*)alloc((size_t)N_NODES);
  unsigned char* adjm  = (unsigned char*)alloc((size_t)K_SEL * K_SEL);
  unsigned char* adjT  = (unsigned char*)alloc((size_t)K_SEL * K_SEL);  // contiguous after adjm
  unsigned char* maskA = (unsigned char*)alloc((size_t)K_SEL * K_SEL);
  unsigned char* maskAT= (unsigned char*)alloc((size_t)K_SEL * K_SEL);
  float* qbuf  = (float*)alloc((size_t)K_SEL * DA_DIM * 4);
  float* kbuf  = (float*)alloc((size_t)K_SEL * DA_DIM * 4);
  float* h_m   = (float*)alloc((size_t)K_SEL * DOUT_DIM * 4);
  float* pos_m = (float*)alloc((size_t)K_SEL * 3 * 4);
  float* hWn   = (float*)alloc((size_t)K_SEL * F_DIM * 4);
  float* upd_m = (float*)alloc((size_t)K_SEL * DOUT_DIM * 4);   // kept for layout stability
  float* h_hier= (float*)alloc((size_t)K_SEL * DOUT_DIM * 4);
  u16*   Bth   = (u16*)alloc((size_t)DOUT_DIM * DOUT_DIM * 2);
  u16*   jlist = (u16*)alloc((size_t)K_SEL * K_SEL * 2);
  int*   njbuf = (int*)alloc((size_t)K_SEL * 4);
  u16*   updbm = (u16*)alloc((size_t)K_SEL * DOUT_DIM * 2);
  (void)upd_m;

  // ---- Phase 1: message passing (CSR, atomic-free)
  hipMemsetAsync(counts, 0, (size_t)N_NODES * 4, stream);
  transpose_bf16<<<dim3(DOUT_DIM / 32, DOUT_DIM / 32), 256, 0, stream>>>(
      W_prod_l, Btl, DOUT_DIM, DOUT_DIM);
  gemm64_f32<<<dim3(F_DIM / 64, N_NODES / 64, 1), 256, 0, stream>>>(
      h, F_DIM, W_node_l, F_DIM, hW, F_DIM, N_NODES, F_DIM, F_DIM, F_DIM, nullptr, 0, 0);
  count_kernel<<<E_EDGES / 256, 256, 0, stream>>>(eidx, counts);
  scan_kernel<<<1, 1024, 0, stream>>>(counts, offsets, cursor);
  fill_kernel<<<E_EDGES / 256, 256, 0, stream>>>(eidx, cursor, elist);
  gather_accum_kernel<<<N_NODES, 128, 0, stream>>>(
      hW, edge_sh, edge_feats, W_rad_l, eidx, offsets, counts, elist, upd,
      useB16 ? updb : nullptr);
  // hs (fp32-exact gate input) = upd @ W_prod_l[:, :128] + h, split-K=4 via psum
  hs_gemm_kernel<<<dim3(N_NODES / 128, 4), 256, 0, stream>>>(upd, W_prod_l, psum);
  hs_reduce_kernel<<<(N_NODES * F_DIM / 4) / 256, 256, 0, stream>>>(psum, h, hs);
  // h_local (MFMA bf16) into d_out region 0 (overwrites psum region)
  if (useB16) {
    gemm_mfma_b16_256<<<(DOUT_DIM / 128) * (N_NODES / 256), 512, 0, stream>>>(
        updb, Btl, out_hf, DOUT_DIM, DOUT_DIM, DOUT_DIM / 128,
        (DOUT_DIM / 128) * (N_NODES / 256), h, F_DIM, F_DIM);
  } else {
    gemm_mfma<<<dim3(DOUT_DIM / 128, N_NODES / 128), 256, 0, stream>>>(
        upd, Btl, out_hf, DOUT_DIM, N_NODES, DOUT_DIM, DOUT_DIM, h, F_DIM, F_DIM);
  }

  // ---- Phase 2
  hipMemsetAsync(adjm, 0, (size_t)2 * K_SEL * K_SEL, stream);     // adjm + adjT
  hipMemsetAsync(hist1, 0, (size_t)65536 * 4 * 2 + 256, stream);  // hist1+hist2+selb
  transpose_bf16<<<dim3(DOUT_DIM / 32, DOUT_DIM / 32), 256, 0, stream>>>(
      W_prod_h, Bth, DOUT_DIM, DOUT_DIM);
  gate_kernel<<<N_NODES / 4, 256, 0, stream>>>(hs, ms_W1, ms_b1, ms_W2, ms_b2,
                                               m_ws, out_m, hist1);
  // radix top-K selection (exact; ties broken by smaller index, matching top_k)
  radix_sel_kernel<<<1, 1024, 0, stream>>>(hist1, nullptr, 0, selb, 0);
  hist2_kernel<<<N_NODES / 256, 256, 0, stream>>>(m_ws, selb, hist2);
  radix_sel_kernel<<<1, 1024, 0, stream>>>(hist2, selb, 1, selb, 2);
  flag_kernel<<<N_NODES / 256, 256, 0, stream>>>(m_ws, selb, flags, cand);
  compact_kernel<<<1, 1024, 0, stream>>>(selb, cand, flags, midx, rank, out_mi);
  adj_kernel<<<E_EDGES / 256, 256, 0, stream>>>(eidx, rank, adjm, adjT);
  gather_kernel<<<K_SEL, 128, 0, stream>>>(out_hf, pos, midx, h_m, pos_m);
  qk_kernel<<<K_SEL, 128, 0, stream>>>(hs, midx, vg_Wq, vg_Wk, qbuf, kbuf);
  attn_kernel<<<dim3(K_SEL / 16, K_SEL / 16), dim3(16, 16), 0, stream>>>(
      qbuf, kbuf, maskA, maskAT, out_Av);
  listbuild_kernel<<<K_SEL, 256, 0, stream>>>(adjT, maskAT, maskA, jlist, njbuf);
  hipMemsetAsync(hWn, 0, (size_t)K_SEL * F_DIM * 4, stream);
  gemm64_f32<<<dim3(F_DIM / 64, K_SEL / 64, 4), 256, 0, stream>>>(
      h_m, DOUT_DIM, W_node_h, F_DIM, hWn, F_DIM,
      K_SEL, F_DIM, DOUT_DIM, DOUT_DIM / 4, nullptr, 0, 0);
  hier2_kernel<<<K_SEL, 256, 0, stream>>>(hWn, pos_m, W_rad_h, jlist, njbuf, updbm);
  gemm_mfma_b16<<<(DOUT_DIM / 128) * (K_SEL / 128), 256, 0, stream>>>(
      updbm, Bth, h_hier, DOUT_DIM, DOUT_DIM, DOUT_DIM / 128,
      (DOUT_DIM / 128) * (K_SEL / 128), h_m, DOUT_DIM, DOUT_DIM);
  combine_kernel<<<(N_NODES * DOUT_DIM / 4) / 256, 256, 0, stream>>>(out_hf, h_hier, m_ws, rank);
}

// Round 11
// 640.144 us; speedup vs baseline: 1.0592x; 1.0040x over previous
//
#include <hip/hip_runtime.h>
#include <hip/hip_bf16.h>
#include <stdint.h>

#define N_NODES 16384
#define E_EDGES 131072
#define F_DIM 128
#define L_DIM 9
#define R_DIM 8
#define DOUT_DIM 1152
#define K_SEL 1024
#define HID_DIM 64
#define DA_DIM 64

typedef unsigned short u16;
typedef __attribute__((ext_vector_type(8))) short bf16x8;
typedef __attribute__((ext_vector_type(4))) float f32x4;

static __device__ inline u16 f2bs(float x) {
  union { __hip_bfloat16 b; u16 s; } u;
  u.b = __float2bfloat16(x);
  return u.s;
}

// async global->LDS, 16B per lane. LDS dest must be waveBase + lane*16.
#define GLDS16(gsrc, ldst) __builtin_amdgcn_global_load_lds( \
    (__attribute__((address_space(1))) void*)(void*)(gsrc),  \
    (__attribute__((address_space(3))) void*)(ldst), 16, 0, 0)

// ================= MFMA GEMM (fallback): C = A(f32->bf16) * B^T(bf16) [+Add]
__global__ __launch_bounds__(256) void gemm_mfma(
    const float* __restrict__ A, const u16* __restrict__ Bt,
    float* __restrict__ C, int ldc, int M, int Nc, int Kc,
    const float* __restrict__ Add, int ldadd, int addW)
{
  __shared__ float Af[128 * 32];   // [m][oct ^ (m&7)]
  __shared__ u16  Bs[128 * 32];    // [n][q ^ ((n>>1)&3)]
  const int tid = threadIdx.x;
  const int wave = tid >> 6, lane = tid & 63;
  const int wm = wave >> 1, wn = wave & 1;
  const int l15 = lane & 15, quad = lane >> 4;
  const int bm = blockIdx.y * 128, bn = blockIdx.x * 128;

  f32x4 acc[4][4];
#pragma unroll
  for (int i = 0; i < 4; i++)
#pragma unroll
    for (int j = 0; j < 4; j++) acc[i][j] = (f32x4)(0.f);

  for (int k0 = 0; k0 < Kc; k0 += 32) {
    __syncthreads();
#pragma unroll
    for (int it = 0; it < 4; it++) {
      int c = it * 256 + tid;
      int row = c >> 3, op = c & 7;
      int oct = op ^ (row & 7);
      const float* g = A + (size_t)(bm + row) * Kc + k0 + oct * 4;
      GLDS16(g, &Af[c * 4]);
    }
#pragma unroll
    for (int it = 0; it < 2; it++) {
      int c = it * 256 + tid;
      int row = c >> 2, qp = c & 3;
      int q = qp ^ ((row >> 1) & 3);
      const u16* g = Bt + (size_t)(bn + row) * Kc + k0 + q * 8;
      GLDS16(g, &Bs[c * 8]);
    }
    __syncthreads();

    bf16x8 af[4], bfg[4];
#pragma unroll
    for (int mi = 0; mi < 4; mi++) {
      int m = wm * 64 + mi * 16 + l15;
      int o0 = (quad * 2) ^ (m & 7), o1 = (quad * 2 + 1) ^ (m & 7);
      float4 lo = *(const float4*)&Af[m * 32 + o0 * 4];
      float4 hi = *(const float4*)&Af[m * 32 + o1 * 4];
      bf16x8 r;
      r[0] = (short)f2bs(lo.x); r[1] = (short)f2bs(lo.y);
      r[2] = (short)f2bs(lo.z); r[3] = (short)f2bs(lo.w);
      r[4] = (short)f2bs(hi.x); r[5] = (short)f2bs(hi.y);
      r[6] = (short)f2bs(hi.z); r[7] = (short)f2bs(hi.w);
      af[mi] = r;
    }
#pragma unroll
    for (int ni = 0; ni < 4; ni++) {
      int n = wn * 64 + ni * 16 + l15;
      int q2 = quad ^ ((n >> 1) & 3);
      bfg[ni] = *(const bf16x8*)&Bs[n * 32 + q2 * 8];
    }
#pragma unroll
    for (int mi = 0; mi < 4; mi++)
#pragma unroll
      for (int ni = 0; ni < 4; ni++)
        acc[mi][ni] = __builtin_amdgcn_mfma_f32_16x16x32_bf16(af[mi], bfg[ni], acc[mi][ni], 0, 0, 0);
  }
#pragma unroll
  for (int mi = 0; mi < 4; mi++)
#pragma unroll
    for (int ni = 0; ni < 4; ni++)
#pragma unroll
      for (int r = 0; r < 4; r++) {
        int row = bm + wm * 64 + mi * 16 + quad * 4 + r;
        int col = bn + wn * 64 + ni * 16 + l15;
        float v = acc[mi][ni][r];
        if (Add != nullptr && col < addW) v += Add[(size_t)row * ldadd + col];
        C[(size_t)row * ldc + col] = v;
      }
}

// ================= MFMA GEMM, bf16 A, 128x128, double-buffered (phase-2; nwg%8==0).
__global__ __launch_bounds__(256) void gemm_mfma_b16(
    const u16* __restrict__ A, const u16* __restrict__ Bt,
    float* __restrict__ C, int ldc, int Kc, int nbx, int nwg,
    const float* __restrict__ Add, int ldadd, int addW)
{
  __shared__ u16 As[2][128 * 32];  // [buf][m][q ^ ((m>>1)&3)]
  __shared__ u16 Bs[2][128 * 32];  // [buf][n][q ^ ((n>>1)&3)]
  const int tid = threadIdx.x;
  const int wave = tid >> 6, lane = tid & 63;
  const int wm = wave >> 1, wn = wave & 1;
  const int l15 = lane & 15, quad = lane >> 4;
  const int lin = blockIdx.x;
  const int swz = (lin & 7) * (nwg >> 3) + (lin >> 3);  // XCD-chunked, bijective
  const int bm = (swz / nbx) * 128, bn = (swz % nbx) * 128;

  const int c0 = tid,      r0 = c0 >> 2, q0 = (c0 & 3) ^ ((r0 >> 1) & 3);
  const int c1 = 256 + tid, r1 = c1 >> 2, q1 = (c1 & 3) ^ ((r1 >> 1) & 3);
  const u16* gA0 = A + (size_t)(bm + r0) * Kc + q0 * 8;
  const u16* gA1 = A + (size_t)(bm + r1) * Kc + q1 * 8;
  const u16* gB0 = Bt + (size_t)(bn + r0) * Kc + q0 * 8;
  const u16* gB1 = Bt + (size_t)(bn + r1) * Kc + q1 * 8;

  f32x4 acc[4][4];
#pragma unroll
  for (int i = 0; i < 4; i++)
#pragma unroll
    for (int j = 0; j < 4; j++) acc[i][j] = (f32x4)(0.f);

#define STAGE_AB(s, k0) do {                      \
    GLDS16(gA0 + (k0), &As[s][c0 * 8]);           \
    GLDS16(gA1 + (k0), &As[s][c1 * 8]);           \
    GLDS16(gB0 + (k0), &Bs[s][c0 * 8]);           \
    GLDS16(gB1 + (k0), &Bs[s][c1 * 8]);           \
  } while (0)

  STAGE_AB(0, 0);
  __syncthreads();
  int cur = 0;
  const int nt = Kc / 32;
  for (int t = 0; t < nt; t++) {
    if (t + 1 < nt) STAGE_AB(cur ^ 1, (t + 1) * 32);
    bf16x8 af[4], bfg[4];
#pragma unroll
    for (int mi = 0; mi < 4; mi++) {
      int m = wm * 64 + mi * 16 + l15;
      af[mi] = *(const bf16x8*)&As[cur][m * 32 + (quad ^ ((m >> 1) & 3)) * 8];
    }
#pragma unroll
    for (int ni = 0; ni < 4; ni++) {
      int n = wn * 64 + ni * 16 + l15;
      bfg[ni] = *(const bf16x8*)&Bs[cur][n * 32 + (quad ^ ((n >> 1) & 3)) * 8];
    }
#pragma unroll
    for (int mi = 0; mi < 4; mi++)
#pragma unroll
      for (int ni = 0; ni < 4; ni++)
        acc[mi][ni] = __builtin_amdgcn_mfma_f32_16x16x32_bf16(af[mi], bfg[ni], acc[mi][ni], 0, 0, 0);
    __syncthreads();
    cur ^= 1;
  }
#undef STAGE_AB

#pragma unroll
  for (int mi = 0; mi < 4; mi++)
#pragma unroll
    for (int ni = 0; ni < 4; ni++)
#pragma unroll
      for (int r = 0; r < 4; r++) {
        int row = bm + wm * 64 + mi * 16 + quad * 4 + r;
        int col = bn + wn * 64 + ni * 16 + l15;
        float v = acc[mi][ni][r];
        if (Add != nullptr && col < addW) v += Add[(size_t)row * ldadd + col];
        C[(size_t)row * ldc + col] = v;
      }
}

// ================= MFMA GEMM, bf16 A, 256x128 tile, 8 waves, double-buffered.
// 1D grid with XCD-chunked swizzle (nwg % 8 == 0).
__global__ __launch_bounds__(512) void gemm_mfma_b16_256(
    const u16* __restrict__ A, const u16* __restrict__ Bt,
    float* __restrict__ C, int ldc, int Kc, int nbx, int nwg,
    const float* __restrict__ Add, int ldadd, int addW)
{
  __shared__ u16 As[2][256 * 32];  // [buf][m][q ^ ((m>>1)&3)]  16 KB/buf
  __shared__ u16 Bs[2][128 * 32];  // [buf][n][q ^ ((n>>1)&3)]   8 KB/buf
  const int tid = threadIdx.x;
  const int wave = tid >> 6, lane = tid & 63;
  const int wm = wave >> 1, wn = wave & 1;      // wm 0..3 (256 rows), wn 0..1 (128 cols)
  const int l15 = lane & 15, quad = lane >> 4;
  const int lin = blockIdx.x;
  const int swz = (lin & 7) * (nwg >> 3) + (lin >> 3);  // XCD-chunked, bijective
  const int bm = (swz / nbx) * 256, bn = (swz % nbx) * 128;

  const int ca0 = tid,       ra0 = ca0 >> 2, qa0 = (ca0 & 3) ^ ((ra0 >> 1) & 3);
  const int ca1 = 512 + tid, ra1 = ca1 >> 2, qa1 = (ca1 & 3) ^ ((ra1 >> 1) & 3);
  const int cb0 = tid,       rb0 = cb0 >> 2, qb0 = (cb0 & 3) ^ ((rb0 >> 1) & 3);
  const u16* gA0 = A + (size_t)(bm + ra0) * Kc + qa0 * 8;
  const u16* gA1 = A + (size_t)(bm + ra1) * Kc + qa1 * 8;
  const u16* gB0 = Bt + (size_t)(bn + rb0) * Kc + qb0 * 8;

  f32x4 acc[4][4];
#pragma unroll
  for (int i = 0; i < 4; i++)
#pragma unroll
    for (int j = 0; j < 4; j++) acc[i][j] = (f32x4)(0.f);

#define STAGE_AB(s, k0) do {                      \
    GLDS16(gA0 + (k0), &As[s][ca0 * 8]);          \
    GLDS16(gA1 + (k0), &As[s][ca1 * 8]);          \
    GLDS16(gB0 + (k0), &Bs[s][cb0 * 8]);          \
  } while (0)

  STAGE_AB(0, 0);
  __syncthreads();
  int cur = 0;
  const int nt = Kc / 32;
  for (int t = 0; t < nt; t++) {
    if (t + 1 < nt) STAGE_AB(cur ^ 1, (t + 1) * 32);
    bf16x8 af[4], bfg[4];
#pragma unroll
    for (int mi = 0; mi < 4; mi++) {
      int m = wm * 64 + mi * 16 + l15;
      af[mi] = *(const bf16x8*)&As[cur][m * 32 + (quad ^ ((m >> 1) & 3)) * 8];
    }
#pragma unroll
    for (int ni = 0; ni < 4; ni++) {
      int n = wn * 64 + ni * 16 + l15;
      bfg[ni] = *(const bf16x8*)&Bs[cur][n * 32 + (quad ^ ((n >> 1) & 3)) * 8];
    }
#pragma unroll
    for (int mi = 0; mi < 4; mi++)
#pragma unroll
      for (int ni = 0; ni < 4; ni++)
        acc[mi][ni] = __builtin_amdgcn_mfma_f32_16x16x32_bf16(af[mi], bfg[ni], acc[mi][ni], 0, 0, 0);
    __syncthreads();
    cur ^= 1;
  }
#undef STAGE_AB

#pragma unroll
  for (int mi = 0; mi < 4; mi++)
#pragma unroll
    for (int ni = 0; ni < 4; ni++)
#pragma unroll
      for (int r = 0; r < 4; r++) {
        int row = bm + wm * 64 + mi * 16 + quad * 4 + r;
        int col = bn + wn * 64 + ni * 16 + l15;
        float v = acc[mi][ni][r];
        if (Add != nullptr && col < addW) v += Add[(size_t)row * ldadd + col];
        C[(size_t)row * ldc + col] = v;
      }
}

// ================= transpose + bf16 cast
__global__ __launch_bounds__(256) void transpose_bf16(
    const float* __restrict__ W, u16* __restrict__ Bt, int K, int N)
{
  __shared__ float t[32][33];
  const int n0 = blockIdx.x * 32, k0 = blockIdx.y * 32;
  const int tx = threadIdx.x & 31, ty = threadIdx.x >> 5;
  for (int r = ty; r < 32; r += 8) t[r][tx] = W[(size_t)(k0 + r) * N + n0 + tx];
  __syncthreads();
  for (int r = ty; r < 32; r += 8) Bt[(size_t)(n0 + r) * K + k0 + tx] = f2bs(t[tx][r]);
}

// ================= hs GEMM: psum[z] = upd[:, z*288:(z+1)*288] @ W_prod_l[z-chunk, :128]
__global__ __launch_bounds__(256) void hs_gemm_kernel(
    const float* __restrict__ A,      // upd, lda = DOUT_DIM
    const float* __restrict__ B,      // W_prod_l, ldb = DOUT_DIM (cols 0..127)
    float* __restrict__ psum)         // [4][N_NODES][F_DIM]
{
  __shared__ float As[16][129];
  __shared__ float Bs[16][128];
  const int tid = threadIdx.x;
  const int tx = tid & 15, ty = tid >> 4;
  const int bm = blockIdx.x * 128;
  const int z = blockIdx.y;
  const int kb = z * (DOUT_DIM / 4);
  const int ke = kb + DOUT_DIM / 4;
  const int ac = tid & 15, ar0 = tid >> 4;
  const int bc = tid & 127, br0 = tid >> 7;
  float acc[8][8];
#pragma unroll
  for (int i = 0; i < 8; i++)
#pragma unroll
    for (int j = 0; j < 8; j++) acc[i][j] = 0.f;

  float ra[8], rb[8];
#define LOADREG(k0) do {                                                       \
    _Pragma("unroll")                                                          \
    for (int rr = 0; rr < 8; rr++)                                             \
      ra[rr] = A[(size_t)(bm + ar0 + rr * 16) * DOUT_DIM + (k0) + ac];         \
    _Pragma("unroll")                                                          \
    for (int rr = 0; rr < 8; rr++)                                             \
      rb[rr] = B[(size_t)((k0) + br0 + rr * 2) * DOUT_DIM + bc];               \
  } while (0)

  LOADREG(kb);
  for (int k0 = kb; k0 < ke; k0 += 16) {
#pragma unroll
    for (int rr = 0; rr < 8; rr++) As[ac][ar0 + rr * 16] = ra[rr];
#pragma unroll
    for (int rr = 0; rr < 8; rr++) Bs[br0 + rr * 2][bc] = rb[rr];
    __syncthreads();
    if (k0 + 16 < ke) LOADREG(k0 + 16);
#pragma unroll
    for (int kk = 0; kk < 16; kk++) {
      float a[8], b[8];
#pragma unroll
      for (int i = 0; i < 8; i++) a[i] = As[kk][ty * 8 + i];
#pragma unroll
      for (int j = 0; j < 8; j++) b[j] = Bs[kk][tx * 8 + j];
#pragma unroll
      for (int i = 0; i < 8; i++)
#pragma unroll
        for (int j = 0; j < 8; j++) acc[i][j] = fmaf(a[i], b[j], acc[i][j]);
    }
    __syncthreads();
  }
#undef LOADREG
#pragma unroll
  for (int i = 0; i < 8; i++) {
    size_t row = (size_t)z * N_NODES + bm + ty * 8 + i;
#pragma unroll
    for (int j = 0; j < 8; j++)
      psum[row * F_DIM + tx * 8 + j] = acc[i][j];
  }
}

// hs = psum[0]+psum[1]+psum[2]+psum[3] + h   (float4)
__global__ __launch_bounds__(256) void hs_reduce_kernel(
    const float* __restrict__ psum, const float* __restrict__ h, float* __restrict__ hs)
{
  size_t i4 = (size_t)blockIdx.x * 256 + threadIdx.x;
  const size_t stride = (size_t)N_NODES * F_DIM / 4;
  const float4* p = (const float4*)psum;
  float4 a = p[i4], b = p[i4 + stride], c = p[i4 + 2 * stride], d = p[i4 + 3 * stride];
  float4 hh = ((const float4*)h)[i4];
  float4 o;
  o.x = a.x + b.x + c.x + d.x + hh.x;
  o.y = a.y + b.y + c.y + d.y + hh.y;
  o.z = a.z + b.z + c.z + d.z + hh.z;
  o.w = a.w + b.w + c.w + d.w + hh.w;
  ((float4*)hs)[i4] = o;
}

// ================= fp32 GEMM 64x64, optional split-K
__global__ __launch_bounds__(256) void gemm64_f32(
    const float* __restrict__ A, int lda,
    const float* __restrict__ B, int ldb,
    float* __restrict__ C, int ldc,
    int M, int Nc, int Kc, int kPerSplit,
    const float* __restrict__ Add, int ldadd, int addW)
{
  __shared__ float As[16][65];
  __shared__ float Bs[16][64];
  const int tid = threadIdx.x;
  const int tx = tid & 15, ty = tid >> 4;
  const int bm = blockIdx.y * 64, bn = blockIdx.x * 64;
  const int kb = blockIdx.z * kPerSplit;
  const int ke = min(kb + kPerSplit, Kc);
  float acc[4][4];
#pragma unroll
  for (int i = 0; i < 4; i++)
#pragma unroll
    for (int j = 0; j < 4; j++) acc[i][j] = 0.f;
  for (int k0 = kb; k0 < ke; k0 += 16) {
    const int ac = tid & 15, ar = tid >> 4;
#pragma unroll
    for (int rr = 0; rr < 4; rr++) {
      int row = ar + rr * 16;
      As[ac][row] = A[(size_t)(bm + row) * lda + k0 + ac];
    }
    const int bc = tid & 63, br = tid >> 6;
#pragma unroll
    for (int rr = 0; rr < 4; rr++) {
      int kr = br + rr * 4;
      Bs[kr][bc] = B[(size_t)(k0 + kr) * ldb + bn + bc];
    }
    __syncthreads();
#pragma unroll
    for (int kk = 0; kk < 16; kk++) {
      float a[4], b[4];
#pragma unroll
      for (int i = 0; i < 4; i++) a[i] = As[kk][ty * 4 + i];
#pragma unroll
      for (int j = 0; j < 4; j++) b[j] = Bs[kk][tx * 4 + j];
#pragma unroll
      for (int i = 0; i < 4; i++)
#pragma unroll
        for (int j = 0; j < 4; j++) acc[i][j] = fmaf(a[i], b[j], acc[i][j]);
    }
    __syncthreads();
  }
#pragma unroll
  for (int i = 0; i < 4; i++) {
    int row = bm + ty * 4 + i;
#pragma unroll
    for (int j = 0; j < 4; j++) {
      int col = bn + tx * 4 + j;
      if (gridDim.z > 1) {
        atomicAdd(&C[(size_t)row * ldc + col], acc[i][j]);
      } else {
        float v = acc[i][j];
        if (Add != nullptr && col < addW) v += Add[(size_t)row * ldadd + col];
        C[(size_t)row * ldc + col] = v;
      }
    }
  }
}

// ================= CSR build: count / scan / fill
__global__ __launch_bounds__(256) void count_kernel(
    const int* __restrict__ ei, int* __restrict__ counts)
{
  int e = blockIdx.x * 256 + threadIdx.x;
  atomicAdd(&counts[ei[E_EDGES + e]], 1);
}

__global__ __launch_bounds__(1024) void scan_kernel(
    const int* __restrict__ counts, int* __restrict__ offsets, int* __restrict__ cursor)
{
  __shared__ int part[1024];
  const int t = threadIdx.x;
  const int base = t * 16;
  int loc[16];
  int s = 0;
#pragma unroll
  for (int k = 0; k < 16; k++) { loc[k] = counts[base + k]; s += loc[k]; }
  part[t] = s;
  __syncthreads();
  for (int d = 1; d < 1024; d <<= 1) {
    int v = (t >= d) ? part[t - d] : 0;
    __syncthreads();
    part[t] += v;
    __syncthreads();
  }
  int run = part[t] - s;  // exclusive prefix
#pragma unroll
  for (int k = 0; k < 16; k++) {
    offsets[base + k] = run;
    cursor[base + k] = run;
    run += loc[k];
  }
}

__global__ __launch_bounds__(256) void fill_kernel(
    const int* __restrict__ ei, int* __restrict__ cursor, int* __restrict__ elist)
{
  int e = blockIdx.x * 256 + threadIdx.x;
  int d = ei[E_EDGES + e];
  int p = atomicAdd(&cursor[d], 1);
  elist[p] = e;
}

// ================= atomic-free edge accumulation: block per dst node.
__global__ __launch_bounds__(128) void gather_accum_kernel(
    const float* __restrict__ hW, const float* __restrict__ edge_sh,
    const float* __restrict__ edge_feats, const float* __restrict__ W_rad_l,
    const int* __restrict__ ei, const int* __restrict__ offsets,
    const int* __restrict__ counts, const int* __restrict__ elist,
    float* __restrict__ upd, u16* __restrict__ updb)
{
  const int d = blockIdx.x, f = threadIdx.x;
  const float w0 = W_rad_l[0 * F_DIM + f], w1 = W_rad_l[1 * F_DIM + f];
  const float w2 = W_rad_l[2 * F_DIM + f], w3 = W_rad_l[3 * F_DIM + f];
  const float w4 = W_rad_l[4 * F_DIM + f], w5 = W_rad_l[5 * F_DIM + f];
  const float w6 = W_rad_l[6 * F_DIM + f], w7 = W_rad_l[7 * F_DIM + f];
  const int b = offsets[d], n = counts[d];
  float acc[L_DIM];
#pragma unroll
  for (int l = 0; l < L_DIM; l++) acc[l] = 0.f;
  for (int k = 0; k < n; k++) {
    const int e = elist[b + k];
    const int s = ei[e];
    const float4 ef0 = *(const float4*)&edge_feats[(size_t)e * R_DIM];
    const float4 ef1 = *(const float4*)&edge_feats[(size_t)e * R_DIM + 4];
    float rw = ef0.x * w0;
    rw = fmaf(ef0.y, w1, rw); rw = fmaf(ef0.z, w2, rw); rw = fmaf(ef0.w, w3, rw);
    rw = fmaf(ef1.x, w4, rw); rw = fmaf(ef1.y, w5, rw);
    rw = fmaf(ef1.z, w6, rw); rw = fmaf(ef1.w, w7, rw);
    const float tf = hW[(size_t)s * F_DIM + f] * rw;
#pragma unroll
    for (int l = 0; l < L_DIM; l++)
      acc[l] = fmaf(edge_sh[(size_t)e * L_DIM + l], tf, acc[l]);
  }
#pragma unroll
  for (int l = 0; l < L_DIM; l++)
    upd[(size_t)d * DOUT_DIM + l * F_DIM + f] = acc[l];
  if (updb != nullptr) {
#pragma unroll
    for (int l = 0; l < L_DIM; l++)
      updb[(size_t)d * DOUT_DIM + l * F_DIM + f] = f2bs(acc[l]);
  }
}

// ================= gating MLP on hs (fp32, ld=F_DIM) + fused 16-bit histogram
__global__ __launch_bounds__(256) void gate_kernel(
    const float* __restrict__ hs, const float* __restrict__ W1,
    const float* __restrict__ b1, const float* __restrict__ W2,
    const float* __restrict__ b2, float* __restrict__ m_ws, float* __restrict__ m_out,
    int* __restrict__ hist1)
{
  __shared__ float sW1[F_DIM * HID_DIM];
  __shared__ float srow[4][F_DIM];
  const int tid = threadIdx.x;
  for (int t = tid; t < F_DIM * HID_DIM; t += 256) sW1[t] = W1[t];
  const int wave = tid >> 6, lane = tid & 63;
  const int n = blockIdx.x * 4 + wave;
  srow[wave][lane] = hs[(size_t)n * F_DIM + lane];
  srow[wave][lane + 64] = hs[(size_t)n * F_DIM + lane + 64];
  __syncthreads();
  float hid = b1[lane];
#pragma unroll 8
  for (int c = 0; c < F_DIM; c++) hid = fmaf(srow[wave][c], sW1[c * HID_DIM + lane], hid);
  hid = fmaxf(hid, 0.f);
  float v = hid * W2[lane];
#pragma unroll
  for (int off = 32; off > 0; off >>= 1) v += __shfl_down(v, off);
  if (lane == 0) {
    float mm = 1.f / (1.f + expf(-(v + b2[0])));
    m_ws[n] = mm;
    m_out[n] = mm;
    unsigned mb = __float_as_uint(mm);
    atomicAdd(&hist1[mb >> 16], 1);
  }
}

// ================= radix top-K selection
__global__ __launch_bounds__(1024) void radix_sel_kernel(
    const int* __restrict__ hist, const int* __restrict__ kin, int kinIdx,
    int* __restrict__ outp, int outIdx)
{
  __shared__ int part[1024];
  const int t = threadIdx.x;
  const int Kv = kin ? kin[kinIdx] : K_SEL;
  const int base = t * 64;
  int s = 0;
  for (int k = 0; k < 64; k++) s += hist[base + k];
  part[t] = s;
  __syncthreads();
  for (int d = 1; d < 1024; d <<= 1) {
    int v = (t + d < 1024) ? part[t + d] : 0;
    __syncthreads();
    part[t] += v;
    __syncthreads();
  }
  int inc = part[t];
  if (inc >= Kv && inc - s < Kv) {
    int r = inc - s;
    for (int b = base + 63; b >= base; b--) {
      int hv = hist[b];
      if (r + hv >= Kv) { outp[outIdx] = b; outp[outIdx + 1] = Kv - r; break; }
      r += hv;
    }
  }
}

__global__ __launch_bounds__(256) void hist2_kernel(
    const float* __restrict__ m_ws, const int* __restrict__ selb, int* __restrict__ hist2)
{
  int i = blockIdx.x * 256 + threadIdx.x;
  unsigned mb = __float_as_uint(m_ws[i]);
  if ((int)(mb >> 16) == selb[0]) atomicAdd(&hist2[mb & 0xFFFFu], 1);
}

__global__ __launch_bounds__(256) void flag_kernel(
    const float* __restrict__ m_ws, int* __restrict__ selb,
    unsigned char* __restrict__ flags, int* __restrict__ cand)
{
  int i = blockIdx.x * 256 + threadIdx.x;
  unsigned mb = __float_as_uint(m_ws[i]);
  unsigned vb = ((unsigned)selb[0] << 16) | (unsigned)selb[2];
  unsigned char fl = 0;
  if (mb > vb) fl = 1;
  else if (mb == vb) { int p = atomicAdd(&selb[4], 1); cand[p] = i; }
  flags[i] = fl;
}

// fused: tie-break (pick selb[3] smallest candidate indices) + prefix-scan compaction
__global__ __launch_bounds__(1024) void compact_kernel(
    const int* __restrict__ selb, const int* __restrict__ cand,
    unsigned char* flags, int* __restrict__ midx,
    int* __restrict__ rank, float* __restrict__ mi_out)
{
  __shared__ int part[1024];
  const int t = threadIdx.x;
  const int nc = selb[4], need = selb[3];
  for (int c = t; c < nc; c += 1024) {
    const int idx = cand[c];
    int r = 0;
    for (int o = 0; o < nc; o++) r += (cand[o] < idx) ? 1 : 0;
    if (r < need) flags[idx] = 1;
  }
  __syncthreads();
  const int base = t * 16;
  int loc[16];
  int s = 0;
#pragma unroll
  for (int k = 0; k < 16; k++) { loc[k] = flags[base + k]; s += loc[k]; }
  part[t] = s;
  __syncthreads();
  for (int d = 1; d < 1024; d <<= 1) {
    int v = (t >= d) ? part[t - d] : 0;
    __syncthreads();
    part[t] += v;
    __syncthreads();
  }
  int run = part[t] - s;
#pragma unroll
  for (int k = 0; k < 16; k++) {
    int i = base + k;
    if (loc[k]) {
      midx[run] = i;
      mi_out[run] = (float)i;
      rank[i] = run;
      run++;
    } else {
      rank[i] = K_SEL;
    }
  }
}

// ================= induced adjacency (+ transposed copy for coalesced listbuild)
__global__ __launch_bounds__(256) void adj_kernel(
    const int* __restrict__ ei, const int* __restrict__ rank,
    unsigned char* __restrict__ adjm, unsigned char* __restrict__ adjT)
{
  int e = blockIdx.x * 256 + threadIdx.x;
  int rs = rank[ei[e]];
  int rd = rank[ei[E_EDGES + e]];
  if (rs < K_SEL && rd < K_SEL) {
    adjm[(size_t)rs * K_SEL + rd] = 1;
    adjT[(size_t)rd * K_SEL + rs] = 1;
  }
}

// ================= gather master rows + positions (float4)
__global__ __launch_bounds__(128) void gather_kernel(
    const float* __restrict__ hl, const float* __restrict__ pos,
    const int* __restrict__ midx, float* __restrict__ h_m, float* __restrict__ pos_m)
{
  const int rI = blockIdx.x, t = threadIdx.x;
  const int mi = midx[rI];
  const float4* src = (const float4*)(hl + (size_t)mi * DOUT_DIM);
  float4* dst = (float4*)(h_m + (size_t)rI * DOUT_DIM);
  for (int c = t; c < DOUT_DIM / 4; c += 128) dst[c] = src[c];
  if (t < 3) pos_m[rI * 3 + t] = pos[mi * 3 + t];
}

// ================= q/k projections from hs at master rows
__global__ __launch_bounds__(128) void qk_kernel(
    const float* __restrict__ hs, const int* __restrict__ midx,
    const float* __restrict__ Wq, const float* __restrict__ Wk,
    float* __restrict__ q, float* __restrict__ kk)
{
  __shared__ float row[F_DIM];
  const int i = blockIdx.x, t = threadIdx.x;
  const int mi = midx[i];
  row[t] = hs[(size_t)mi * F_DIM + t];
  __syncthreads();
  const int d = t & 63;
  const float* W = (t < 64) ? Wq : Wk;
  float acc = 0.f;
#pragma unroll 8
  for (int c = 0; c < F_DIM; c++) acc = fmaf(row[c], W[c * DA_DIM + d], acc);
  float* dst = (t < 64) ? q : kk;
  dst[(size_t)i * DA_DIM + d] = acc;
}

// ================= attention (padded LDS; also emits transposed mask)
__global__ __launch_bounds__(256) void attn_kernel(
    const float* __restrict__ q, const float* __restrict__ kk,
    unsigned char* __restrict__ maskA, unsigned char* __restrict__ maskAT,
    float* __restrict__ Av)
{
  __shared__ float qs[16][DA_DIM + 1], ks[16][DA_DIM + 1];
  const int tx = threadIdx.x, ty = threadIdx.y;
  const int tid = ty * 16 + tx;
  const int i0 = blockIdx.y * 16, j0 = blockIdx.x * 16;
  for (int t = tid; t < 16 * DA_DIM; t += 256) {
    int rr = t >> 6, cc = t & 63;
    qs[rr][cc] = q[(size_t)(i0 + rr) * DA_DIM + cc];
    ks[rr][cc] = kk[(size_t)(j0 + rr) * DA_DIM + cc];
  }
  __syncthreads();
  float acc = 0.f;
#pragma unroll
  for (int d2 = 0; d2 < DA_DIM; d2++) acc = fmaf(qs[ty][d2], ks[tx][d2], acc);
  float sgl = 1.f / (1.f + expf(-acc * 0.125f));
  size_t o = (size_t)(i0 + ty) * K_SEL + (j0 + tx);
  bool big = sgl > 0.5f;
  unsigned char bb = big ? 1 : 0;
  maskA[o] = bb;
  maskAT[(size_t)(j0 + tx) * K_SEL + (i0 + ty)] = bb;
  Av[o] = big ? sgl : 0.f;
}

// ================= per-i active-j list (coalesced row reads + wave-ballot)
__global__ __launch_bounds__(256) void listbuild_kernel(
    const unsigned char* __restrict__ adjT, const unsigned char* __restrict__ maskAT,
    const unsigned char* __restrict__ maskA, u16* __restrict__ list, int* __restrict__ nj)
{
  __shared__ int cnt;
  const int i = blockIdx.x, tid = threadIdx.x;
  const int lane = tid & 63;
  if (tid == 0) cnt = 0;
  __syncthreads();
  const int j0 = tid * 4;
  uchar4 a  = *(const uchar4*)&adjT  [(size_t)i * K_SEL + j0];
  uchar4 mt = *(const uchar4*)&maskAT[(size_t)i * K_SEL + j0];
  uchar4 ma = *(const uchar4*)&maskA [(size_t)i * K_SEL + j0];
  unsigned char av[4];
  av[0] = a.x | mt.x | ma.x; av[1] = a.y | mt.y | ma.y;
  av[2] = a.z | mt.z | ma.z; av[3] = a.w | mt.w | ma.w;
#pragma unroll
  for (int r = 0; r < 4; r++) {
    int j = j0 + r;
    bool e = (j != i) && av[r];
    unsigned long long m = __ballot(e);
    int nset = __popcll(m);
    int base = 0;
    if (lane == 0 && nset) base = atomicAdd(&cnt, nset);
    base = __shfl(base, 0);
    if (e) {
      int p = base + __popcll(m & ((1ull << lane) - 1ull));
      list[(size_t)i * K_SEL + p] = (u16)j;
    }
  }
  __syncthreads();
  if (tid == 0) nj[i] = cnt;
}

// ================= hier v7: 512 thr = 8 jsub x 64 lanes, 2 f per lane.
// Per-block serial path halves vs v6; staged 8->4->2->1 LDS reduction keeps
// the buffer at 4 planes (28.7 KB total) so all 1024 blocks stay co-resident
// (4 blocks/CU, wave-limited).
__global__ __launch_bounds__(512) void hier2_kernel(
    const float* __restrict__ hWn, const float* __restrict__ pos_m,
    const float* __restrict__ W_rad_h, const u16* __restrict__ list,
    const int* __restrict__ nj, u16* __restrict__ updb_m)
{
  __shared__ float gsm[128][20];          // [pair][rd0..7, sh0..8, jbits, pad, pad]
  __shared__ float red[4][L_DIM][F_DIM];  // staged reduction buffer
  const int tid = threadIdx.x;
  const int i = blockIdx.x;
  const int lane = tid & 63, jsub = tid >> 6;   // 8 j-subgroups
  const int f0 = lane, f1 = lane + 64;
  const float a0 = W_rad_h[0 * F_DIM + f0], a1 = W_rad_h[1 * F_DIM + f0];
  const float a2 = W_rad_h[2 * F_DIM + f0], a3 = W_rad_h[3 * F_DIM + f0];
  const float a4 = W_rad_h[4 * F_DIM + f0], a5 = W_rad_h[5 * F_DIM + f0];
  const float a6 = W_rad_h[6 * F_DIM + f0], a7 = W_rad_h[7 * F_DIM + f0];
  const float b0 = W_rad_h[0 * F_DIM + f1], b1 = W_rad_h[1 * F_DIM + f1];
  const float b2 = W_rad_h[2 * F_DIM + f1], b3 = W_rad_h[3 * F_DIM + f1];
  const float b4 = W_rad_h[4 * F_DIM + f1], b5 = W_rad_h[5 * F_DIM + f1];
  const float b6 = W_rad_h[6 * F_DIM + f1], b7 = W_rad_h[7 * F_DIM + f1];
  const float pix = pos_m[i * 3 + 0], piy = pos_m[i * 3 + 1], piz = pos_m[i * 3 + 2];
  float acc0[L_DIM], acc1[L_DIM];
#pragma unroll
  for (int l = 0; l < L_DIM; l++) { acc0[l] = 0.f; acc1[l] = 0.f; }
  const int n = nj[i];
  for (int c0 = 0; c0 < n; c0 += 128) {
    const int cnt = min(128, n - c0);
    __syncthreads();
    if (tid < cnt) {
      const int j = list[(size_t)i * K_SEL + c0 + tid];
      float vx = pos_m[j * 3 + 0] - pix;
      float vy = pos_m[j * 3 + 1] - piy;
      float vz = pos_m[j * 3 + 2] - piz;
      float r = sqrtf(vx * vx + vy * vy + vz * vz);
      float rm = fmaxf(r, 1e-9f);
      float inv = 1.f / rm;
      float ux = vx * inv, uy = vy * inv, uz = vz * inv;
      float theta = 0.62831853071795864769f * r;  // pi/R_CUT
      float s1 = sinf(theta), c1 = cosf(theta);
      float coef = 0.632455532033675866f * inv;   // sqrt(2/R_CUT)/max(r,eps)
      float snm2 = 0.f, snm1 = s1;
      gsm[tid][0] = s1 * coef;
#pragma unroll
      for (int nn = 2; nn <= R_DIM; nn++) {
        float sn = 2.f * c1 * snm1 - snm2;
        gsm[tid][nn - 1] = sn * coef;
        snm2 = snm1; snm1 = sn;
      }
      gsm[tid][8] = 1.f; gsm[tid][9] = ux; gsm[tid][10] = uy; gsm[tid][11] = uz;
      gsm[tid][12] = ux * uy; gsm[tid][13] = uy * uz;
      gsm[tid][14] = 3.f * uz * uz - 1.f;
      gsm[tid][15] = ux * uz; gsm[tid][16] = ux * ux - uy * uy;
      gsm[tid][17] = __int_as_float(j);
      gsm[tid][18] = 0.f; gsm[tid][19] = 0.f;
    }
    __syncthreads();
    for (int t = jsub; t < cnt; t += 8) {
      float2 s2 = *(const float2*)&gsm[t][16];   // sh8, jbits
      const int j = __float_as_int(s2.y);
      const float hw0 = hWn[(size_t)j * F_DIM + f0];
      const float hw1 = hWn[(size_t)j * F_DIM + f1];
      float4 r0 = *(const float4*)&gsm[t][0];    // rd0..3
      float4 r1 = *(const float4*)&gsm[t][4];    // rd4..7
      float4 s0 = *(const float4*)&gsm[t][8];    // sh0..3
      float4 s1g = *(const float4*)&gsm[t][12];  // sh4..7
      float rwa = r0.x * a0;
      rwa = fmaf(r0.y, a1, rwa); rwa = fmaf(r0.z, a2, rwa); rwa = fmaf(r0.w, a3, rwa);
      rwa = fmaf(r1.x, a4, rwa); rwa = fmaf(r1.y, a5, rwa);
      rwa = fmaf(r1.z, a6, rwa); rwa = fmaf(r1.w, a7, rwa);
      float rwb = r0.x * b0;
      rwb = fmaf(r0.y, b1, rwb); rwb = fmaf(r0.z, b2, rwb); rwb = fmaf(r0.w, b3, rwb);
      rwb = fmaf(r1.x, b4, rwb); rwb = fmaf(r1.y, b5, rwb);
      rwb = fmaf(r1.z, b6, rwb); rwb = fmaf(r1.w, b7, rwb);
      const float tm0 = hw0 * rwa;
      const float tm1 = hw1 * rwb;
      acc0[0] = fmaf(s0.x, tm0, acc0[0]); acc1[0] = fmaf(s0.x, tm1, acc1[0]);
      acc0[1] = fmaf(s0.y, tm0, acc0[1]); acc1[1] = fmaf(s0.y, tm1, acc1[1]);
      acc0[2] = fmaf(s0.z, tm0, acc0[2]); acc1[2] = fmaf(s0.z, tm1, acc1[2]);
      acc0[3] = fmaf(s0.w, tm0, acc0[3]); acc1[3] = fmaf(s0.w, tm1, acc1[3]);
      acc0[4] = fmaf(s1g.x, tm0, acc0[4]); acc1[4] = fmaf(s1g.x, tm1, acc1[4]);
      acc0[5] = fmaf(s1g.y, tm0, acc0[5]); acc1[5] = fmaf(s1g.y, tm1, acc1[5]);
      acc0[6] = fmaf(s1g.z, tm0, acc0[6]); acc1[6] = fmaf(s1g.z, tm1, acc1[6]);
      acc0[7] = fmaf(s1g.w, tm0, acc0[7]); acc1[7] = fmaf(s1g.w, tm1, acc1[7]);
      acc0[8] = fmaf(s2.x, tm0, acc0[8]); acc1[8] = fmaf(s2.x, tm1, acc1[8]);
    }
  }
  // staged reduction 8 -> 4 -> 2 -> 1 (buffer: 4 planes, reused)
  __syncthreads();
  if (jsub >= 4) {
#pragma unroll
    for (int l = 0; l < L_DIM; l++) {
      red[jsub - 4][l][f0] = acc0[l];
      red[jsub - 4][l][f1] = acc1[l];
    }
  }
  __syncthreads();
  if (jsub < 4) {
#pragma unroll
    for (int l = 0; l < L_DIM; l++) {
      acc0[l] += red[jsub][l][f0];
      acc1[l] += red[jsub][l][f1];
    }
  }
  __syncthreads();
  if (jsub == 2 || jsub == 3) {
#pragma unroll
    for (int l = 0; l < L_DIM; l++) {
      red[jsub - 2][l][f0] = acc0[l];
      red[jsub - 2][l][f1] = acc1[l];
    }
  }
  __syncthreads();
  if (jsub < 2) {
#pragma unroll
    for (int l = 0; l < L_DIM; l++) {
      acc0[l] += red[jsub][l][f0];
      acc1[l] += red[jsub][l][f1];
    }
  }
  __syncthreads();
  if (jsub == 1) {
#pragma unroll
    for (int l = 0; l < L_DIM; l++) {
      red[0][l][f0] = acc0[l];
      red[0][l][f1] = acc1[l];
    }
  }
  __syncthreads();
  if (jsub == 0) {
#pragma unroll
    for (int l = 0; l < L_DIM; l++) {
      float v0 = acc0[l] + red[0][l][f0];
      float v1 = acc1[l] + red[0][l][f1];
      updb_m[(size_t)i * DOUT_DIM + l * F_DIM + f0] = f2bs(v0);
      updb_m[(size_t)i * DOUT_DIM + l * F_DIM + f1] = f2bs(v1);
    }
  }
}

// ================= final blend (float4; 1152 % 4 == 0, vector never spans rows)
__global__ __launch_bounds__(256) void combine_kernel(
    float* __restrict__ out0, const float* __restrict__ h_hier,
    const float* __restrict__ m_ws, const int* __restrict__ rank)
{
  size_t i4 = (size_t)blockIdx.x * 256 + threadIdx.x;
  int n = (int)(i4 / (DOUT_DIM / 4));
  int g4 = (int)(i4 % (DOUT_DIM / 4));
  float mv = m_ws[n];
  int r = rank[n];
  float4 hl = ((const float4*)out0)[i4];
  float4 he = make_float4(0.f, 0.f, 0.f, 0.f);
  if (r < K_SEL) he = ((const float4*)h_hier)[(size_t)r * (DOUT_DIM / 4) + g4];
  float4 o;
  o.x = (1.f - mv) * hl.x + mv * he.x;
  o.y = (1.f - mv) * hl.y + mv * he.y;
  o.z = (1.f - mv) * hl.z + mv * he.z;
  o.w = (1.f - mv) * hl.w + mv * he.w;
  ((float4*)out0)[i4] = o;
}

extern "C" void kernel_launch(void* const* d_in, const int* in_sizes, int n_in,
                              void* d_out, int out_size, void* d_ws, size_t ws_size,
                              hipStream_t stream)
{
  const float* h         = (const float*)d_in[0];
  const float* pos       = (const float*)d_in[1];
  const float* edge_sh   = (const float*)d_in[2];
  const float* edge_feats= (const float*)d_in[3];
  const float* W_node_l  = (const float*)d_in[4];
  const float* W_rad_l   = (const float*)d_in[5];
  const float* W_prod_l  = (const float*)d_in[6];
  const float* ms_W1     = (const float*)d_in[7];
  const float* ms_b1     = (const float*)d_in[8];
  const float* ms_W2     = (const float*)d_in[9];
  const float* ms_b2     = (const float*)d_in[10];
  const float* vg_Wq     = (const float*)d_in[11];
  const float* vg_Wk     = (const float*)d_in[12];
  const float* W_node_h  = (const float*)d_in[13];
  const float* W_rad_h   = (const float*)d_in[14];
  const float* W_prod_h  = (const float*)d_in[15];
  const int*   eidx      = (const int*)d_in[16];

  float* out    = (float*)d_out;
  float* out_hf = out;
  float* out_Av = out + (size_t)N_NODES * DOUT_DIM;
  float* out_m  = out_Av + (size_t)K_SEL * K_SEL;
  float* out_mi = out_m + N_NODES;

  char* ws = (char*)d_ws;
  // Phase 1: upd [0, 75.5MB); hW/hs [75.5, 83.9MB); optional updb [83.9, 121.6MB).
  float* upd = (float*)ws;
  float* hW  = (float*)(ws + (size_t)N_NODES * DOUT_DIM * 4);
  float* hs  = hW;  // hW dead after gather_accum; hs written after
  const size_t updbOff = (size_t)N_NODES * DOUT_DIM * 4 + (size_t)N_NODES * F_DIM * 4;
  const size_t updbNeed = updbOff + (size_t)N_NODES * DOUT_DIM * 2;
  const bool useB16 = (ws_size >= updbNeed);
  u16* updb = (u16*)(ws + updbOff);
  // hs split-K partials borrow out_hf (75.5MB, dead until gemm writes it).
  float* psum = out_hf;   // 4 * 16384 * 128 * 4B = 33.6 MB < 75.5 MB
  // Btl + CSR borrow the A_virtual out region (4MB, dead until attn writes it).
  u16* Btl = (u16*)out_Av;                                       // 2.65 MB
  char* csr = (char*)out_Av + (((size_t)DOUT_DIM * DOUT_DIM * 2 + 255) & ~(size_t)255);
  int* counts  = (int*)csr;                                      // 64 KB
  int* offsets = counts + N_NODES;                               // 64 KB
  int* cursor  = offsets + N_NODES;                              // 64 KB
  int* elist   = cursor + N_NODES;                               // 512 KB  (total 3.4MB < 4MB)
  // Phase 2 small pool aliases dead upd.
  size_t off = 0;
  auto alloc = [&](size_t bytes) -> void* {
    void* p = ws + off;
    off += (bytes + 255) & ~(size_t)255;
    return p;
  };
  float* m_ws  = (float*)alloc((size_t)N_NODES * 4);
  int*   rank  = (int*)alloc((size_t)N_NODES * 4);
  int*   midx  = (int*)alloc((size_t)K_SEL * 4);
  int*   hist1 = (int*)alloc((size_t)65536 * 4);
  int*   hist2 = (int*)alloc((size_t)65536 * 4);
  int*   selb  = (int*)alloc((size_t)64 * 4);   // [0]=b1 [1]=need1 [2]=b2 [3]=need2 [4]=ncand
  int*   cand  = (int*)alloc((size_t)N_NODES * 4);
  unsigned char* flags = (unsigned char*)alloc((size_t)N_NODES);
  unsigned char* adjm  = (unsigned char*)alloc((size_t)K_SEL * K_SEL);
  unsigned char* adjT  = (unsigned char*)alloc((size_t)K_SEL * K_SEL);  // contiguous after adjm
  unsigned char* maskA = (unsigned char*)alloc((size_t)K_SEL * K_SEL);
  unsigned char* maskAT= (unsigned char*)alloc((size_t)K_SEL * K_SEL);
  float* qbuf  = (float*)alloc((size_t)K_SEL * DA_DIM * 4);
  float* kbuf  = (float*)alloc((size_t)K_SEL * DA_DIM * 4);
  float* h_m   = (float*)alloc((size_t)K_SEL * DOUT_DIM * 4);
  float* pos_m = (float*)alloc((size_t)K_SEL * 3 * 4);
  float* hWn   = (float*)alloc((size_t)K_SEL * F_DIM * 4);
  float* upd_m = (float*)alloc((size_t)K_SEL * DOUT_DIM * 4);   // kept for layout stability
  float* h_hier= (float*)alloc((size_t)K_SEL * DOUT_DIM * 4);
  u16*   Bth   = (u16*)alloc((size_t)DOUT_DIM * DOUT_DIM * 2);
  u16*   jlist = (u16*)alloc((size_t)K_SEL * K_SEL * 2);
  int*   njbuf = (int*)alloc((size_t)K_SEL * 4);
  u16*   updbm = (u16*)alloc((size_t)K_SEL * DOUT_DIM * 2);
  (void)upd_m;

  // ---- Phase 1: message passing (CSR, atomic-free)
  hipMemsetAsync(counts, 0, (size_t)N_NODES * 4, stream);
  transpose_bf16<<<dim3(DOUT_DIM / 32, DOUT_DIM / 32), 256, 0, stream>>>(
      W_prod_l, Btl, DOUT_DIM, DOUT_DIM);
  gemm64_f32<<<dim3(F_DIM / 64, N_NODES / 64, 1), 256, 0, stream>>>(
      h, F_DIM, W_node_l, F_DIM, hW, F_DIM, N_NODES, F_DIM, F_DIM, F_DIM, nullptr, 0, 0);
  count_kernel<<<E_EDGES / 256, 256, 0, stream>>>(eidx, counts);
  scan_kernel<<<1, 1024, 0, stream>>>(counts, offsets, cursor);
  fill_kernel<<<E_EDGES / 256, 256, 0, stream>>>(eidx, cursor, elist);
  gather_accum_kernel<<<N_NODES, 128, 0, stream>>>(
      hW, edge_sh, edge_feats, W_rad_l, eidx, offsets, counts, elist, upd,
      useB16 ? updb : nullptr);
  // hs (fp32-exact gate input) = upd @ W_prod_l[:, :128] + h, split-K=4 via psum
  hs_gemm_kernel<<<dim3(N_NODES / 128, 4), 256, 0, stream>>>(upd, W_prod_l, psum);
  hs_reduce_kernel<<<(N_NODES * F_DIM / 4) / 256, 256, 0, stream>>>(psum, h, hs);
  // h_local (MFMA bf16) into d_out region 0 (overwrites psum region)
  if (useB16) {
    gemm_mfma_b16_256<<<(DOUT_DIM / 128) * (N_NODES / 256), 512, 0, stream>>>(
        updb, Btl, out_hf, DOUT_DIM, DOUT_DIM, DOUT_DIM / 128,
        (DOUT_DIM / 128) * (N_NODES / 256), h, F_DIM, F_DIM);
  } else {
    gemm_mfma<<<dim3(DOUT_DIM / 128, N_NODES / 128), 256, 0, stream>>>(
        upd, Btl, out_hf, DOUT_DIM, N_NODES, DOUT_DIM, DOUT_DIM, h, F_DIM, F_DIM);
  }

  // ---- Phase 2
  hipMemsetAsync(adjm, 0, (size_t)2 * K_SEL * K_SEL, stream);     // adjm + adjT
  hipMemsetAsync(hist1, 0, (size_t)65536 * 4 * 2 + 256, stream);  // hist1+hist2+selb
  transpose_bf16<<<dim3(DOUT_DIM / 32, DOUT_DIM / 32), 256, 0, stream>>>(
      W_prod_h, Bth, DOUT_DIM, DOUT_DIM);
  gate_kernel<<<N_NODES / 4, 256, 0, stream>>>(hs, ms_W1, ms_b1, ms_W2, ms_b2,
                                               m_ws, out_m, hist1);
  // radix top-K selection (exact; ties broken by smaller index, matching top_k)
  radix_sel_kernel<<<1, 1024, 0, stream>>>(hist1, nullptr, 0, selb, 0);
  hist2_kernel<<<N_NODES / 256, 256, 0, stream>>>(m_ws, selb, hist2);
  radix_sel_kernel<<<1, 1024, 0, stream>>>(hist2, selb, 1, selb, 2);
  flag_kernel<<<N_NODES / 256, 256, 0, stream>>>(m_ws, selb, flags, cand);
  compact_kernel<<<1, 1024, 0, stream>>>(selb, cand, flags, midx, rank, out_mi);
  adj_kernel<<<E_EDGES / 256, 256, 0, stream>>>(eidx, rank, adjm, adjT);
  gather_kernel<<<K_SEL, 128, 0, stream>>>(out_hf, pos, midx, h_m, pos_m);
  qk_kernel<<<K_SEL, 128, 0, stream>>>(hs, midx, vg_Wq, vg_Wk, qbuf, kbuf);
  attn_kernel<<<dim3(K_SEL / 16, K_SEL / 16), dim3(16, 16), 0, stream>>>(
      qbuf, kbuf, maskA, maskAT, out_Av);
  listbuild_kernel<<<K_SEL, 256, 0, stream>>>(adjT, maskAT, maskA, jlist, njbuf);
  hipMemsetAsync(hWn, 0, (size_t)K_SEL * F_DIM * 4, stream);
  gemm64_f32<<<dim3(F_DIM / 64, K_SEL / 64, 4), 256, 0, stream>>>(
      h_m, DOUT_DIM, W_node_h, F_DIM, hWn, F_DIM,
      K_SEL, F_DIM, DOUT_DIM, DOUT_DIM / 4, nullptr, 0, 0);
  hier2_kernel<<<K_SEL, 512, 0, stream>>>(hWn, pos_m, W_rad_h, jlist, njbuf, updbm);
  gemm_mfma_b16<<<(DOUT_DIM / 128) * (K_SEL / 128), 256, 0, stream>>>(
      updbm, Bth, h_hier, DOUT_DIM, DOUT_DIM, DOUT_DIM / 128,
      (DOUT_DIM / 128) * (K_SEL / 128), h_m, DOUT_DIM, DOUT_DIM);
  combine_kernel<<<(N_NODES * DOUT_DIM / 4) / 256, 256, 0, stream>>>(out_hf, h_hier, m_ws, rank);
}